// Round 1
// baseline (2030.928 us; speedup 1.0000x reference)
//
#include <hip/hip_runtime.h>
#include <math.h>

// ---------------------------------------------------------------------------
// SimGNN forward on MI355X.  All f32.  Structure:
//   per graph: CSR-by-tgt build -> 3x (GEMM + CSR gather aggregation)
//   attention pool (colmean trick), NTN, 2-pass tiled similarity histogram,
//   tiny MLP head.
// ---------------------------------------------------------------------------

// ---------------- CSR build ----------------
__global__ void count_tgt(const int* __restrict__ tgt, int* __restrict__ cnt, int E) {
    int g = blockIdx.x * blockDim.x + threadIdx.x;
    if (g < E) atomicAdd(&cnt[tgt[g]], 1);
}

__global__ __launch_bounds__(1024) void scan_offsets(const int* __restrict__ cnt,
                                                     int* __restrict__ offs,
                                                     int* __restrict__ cursor, int N) {
    __shared__ int part[1024];
    int tid = threadIdx.x;
    int chunk = (N + 1023) >> 10;
    int base = tid * chunk;
    int s = 0;
    for (int i = 0; i < chunk; ++i) {
        int idx = base + i;
        if (idx < N) s += cnt[idx];
    }
    part[tid] = s;
    __syncthreads();
    for (int d = 1; d < 1024; d <<= 1) {
        int v = (tid >= d) ? part[tid - d] : 0;
        __syncthreads();
        part[tid] += v;
        __syncthreads();
    }
    int run = (tid > 0) ? part[tid - 1] : 0;
    for (int i = 0; i < chunk; ++i) {
        int idx = base + i;
        if (idx < N) {
            offs[idx] = run;
            cursor[idx] = run;
            run += cnt[idx];
        }
    }
    if (tid == 1023) offs[N] = part[1023];
}

__global__ void scatter_src(const int* __restrict__ src, const int* __restrict__ tgt,
                            int* __restrict__ cursor, int* __restrict__ esrc, int E) {
    int g = blockIdx.x * blockDim.x + threadIdx.x;
    if (g < E) {
        int t = tgt[g];
        int pos = atomicAdd(&cursor[t], 1);
        esrc[pos] = src[g];
    }
}

__global__ void make_dinv(const int* __restrict__ cnt, float* __restrict__ dinv, int N) {
    int i = blockIdx.x * blockDim.x + threadIdx.x;
    if (i < N) {
        float d = (float)(cnt[i] + 1);  // +1 self loop
        dinv[i] = 1.0f / sqrtf(d);
    }
}

// ---------------- GEMM: out[N,FOUT] = x[N,FIN] @ W[FIN,FOUT] ----------------
template <int FIN, int FOUT>
__global__ __launch_bounds__(256) void gemm_lds(const float* __restrict__ x,
                                                const float* __restrict__ W,
                                                float* __restrict__ out, int N) {
    constexpr int RPB = 256 / FOUT;
    __shared__ float Wl[FIN * FOUT];
    for (int t = threadIdx.x; t < FIN * FOUT; t += 256) Wl[t] = W[t];
    __syncthreads();
    int fx = threadIdx.x % FOUT;
    int r = blockIdx.x * RPB + threadIdx.x / FOUT;
    if (r >= N) return;
    const float* xr = x + (size_t)r * FIN;
    float acc = 0.f;
#pragma unroll
    for (int k = 0; k < FIN; ++k) acc = fmaf(xr[k], Wl[k * FOUT + fx], acc);
    out[(size_t)r * FOUT + fx] = acc;
}

// ------------- GCN aggregation: out[t] = relu?(dt*(dt*h[t] + sum ds*h[s]) + b) -------------
template <int F, bool RELU>
__global__ __launch_bounds__(256) void agg_csr(const float* __restrict__ h,
                                               const int* __restrict__ offs,
                                               const int* __restrict__ esrc,
                                               const float* __restrict__ dinv,
                                               const float* __restrict__ b,
                                               float* __restrict__ out, int N) {
    constexpr int RPB = 256 / F;
    int fx = threadIdx.x % F;
    int t = blockIdx.x * RPB + threadIdx.x / F;
    if (t >= N) return;
    float dt = dinv[t];
    float acc = dt * h[(size_t)t * F + fx];  // self loop term (dt^2 * h[t]) / dt
    int e1 = offs[t + 1];
    for (int e = offs[t]; e < e1; ++e) {
        int s = esrc[e];
        acc = fmaf(dinv[s], h[(size_t)s * F + fx], acc);
    }
    float v = fmaf(dt, acc, b[fx]);
    if (RELU) v = fmaxf(v, 0.f);
    out[(size_t)t * F + fx] = v;
}

// ---------------- attention pool ----------------
__global__ __launch_bounds__(256) void colmean_ctx(const float* __restrict__ af,
                                                   const float* __restrict__ Wa,
                                                   float* __restrict__ ctx, int N) {
    __shared__ float red[32 * 256];
    __shared__ float mean[32];
    int tid = threadIdx.x;
    float acc[32];
#pragma unroll
    for (int f = 0; f < 32; ++f) acc[f] = 0.f;
    for (int r = tid; r < N; r += 256) {
        const float4* row = (const float4*)(af + (size_t)r * 32);
#pragma unroll
        for (int q = 0; q < 8; ++q) {
            float4 v = row[q];
            acc[q * 4 + 0] += v.x;
            acc[q * 4 + 1] += v.y;
            acc[q * 4 + 2] += v.z;
            acc[q * 4 + 3] += v.w;
        }
    }
#pragma unroll
    for (int f = 0; f < 32; ++f) red[f * 256 + tid] = acc[f];
    __syncthreads();
    if (tid < 32) {
        float s = 0.f;
        for (int j = 0; j < 256; ++j) s += red[tid * 256 + j];
        mean[tid] = s / (float)N;
    }
    __syncthreads();
    if (tid < 32) {
        float s = 0.f;
        for (int d = 0; d < 32; ++d) s = fmaf(mean[d], Wa[d * 32 + tid], s);
        ctx[tid] = tanhf(s);
    }
}

__global__ __launch_bounds__(256) void att_pool(const float* __restrict__ af,
                                                const float* __restrict__ ctx,
                                                float* __restrict__ p, int N) {
    __shared__ float red[32 * 256];
    __shared__ float ctxl[32];
    int tid = threadIdx.x;
    if (tid < 32) ctxl[tid] = ctx[tid];
    __syncthreads();
    float acc[32];
#pragma unroll
    for (int f = 0; f < 32; ++f) acc[f] = 0.f;
    for (int r = tid; r < N; r += 256) {
        float rowv[32];
        const float4* row = (const float4*)(af + (size_t)r * 32);
#pragma unroll
        for (int q = 0; q < 8; ++q) {
            float4 v = row[q];
            rowv[q * 4 + 0] = v.x;
            rowv[q * 4 + 1] = v.y;
            rowv[q * 4 + 2] = v.z;
            rowv[q * 4 + 3] = v.w;
        }
        float dot = 0.f;
#pragma unroll
        for (int f = 0; f < 32; ++f) dot = fmaf(rowv[f], ctxl[f], dot);
        float att = 1.f / (1.f + expf(-dot));
#pragma unroll
        for (int f = 0; f < 32; ++f) acc[f] = fmaf(att, rowv[f], acc[f]);
    }
#pragma unroll
    for (int f = 0; f < 32; ++f) red[f * 256 + tid] = acc[f];
    __syncthreads();
    if (tid < 32) {
        float s = 0.f;
        for (int j = 0; j < 256; ++j) s += red[tid * 256 + j];
        p[tid] = s;
    }
}

// ---------------- NTN ----------------
__global__ void ntn_kernel(const float* __restrict__ p1, const float* __restrict__ p2,
                           const float* __restrict__ Wt, const float* __restrict__ V,
                           const float* __restrict__ bt, float* __restrict__ outk) {
    int k = threadIdx.x;
    if (k >= 16) return;
    float sc = 0.f;
    for (int d = 0; d < 32; ++d) {
        float a = p1[d];
        for (int e = 0; e < 32; ++e) sc = fmaf(a * p2[e], Wt[(d * 32 + e) * 16 + k], sc);
    }
    float bl = 0.f;
    for (int m = 0; m < 32; ++m) bl = fmaf(V[k * 64 + m], p1[m], bl);
    for (int m = 0; m < 32; ++m) bl = fmaf(V[k * 64 + 32 + m], p2[m], bl);
    outk[k] = fmaxf(sc + bl + bt[k], 0.f);
}

// ---------------- similarity histogram (2-pass, s never materialized) ----------------
__device__ __forceinline__ unsigned fkey(float f) {
    unsigned u = __float_as_uint(f);
    return (u & 0x80000000u) ? ~u : (u | 0x80000000u);
}
__device__ __forceinline__ float funkey(unsigned k) {
    unsigned u = (k & 0x80000000u) ? (k & 0x7fffffffu) : ~k;
    return __uint_as_float(u);
}

__global__ __launch_bounds__(256) void sim_minmax(const float* __restrict__ af1,
                                                  const float* __restrict__ af2, int N,
                                                  unsigned* __restrict__ mm) {
    __shared__ float A[64 * 33];
    __shared__ float B[64 * 33];
    __shared__ float rmin[256], rmax[256];
    int nb = N >> 6;
    int by = blockIdx.x / nb;
    int bx = blockIdx.x % nb;
    const float* a0 = af1 + ((size_t)by * 64) * 32;
    const float* b0 = af2 + ((size_t)bx * 64) * 32;
    for (int t = threadIdx.x; t < 512; t += 256) {
        int row = t >> 3, c = (t & 7) << 2;
        float4 v = *(const float4*)(a0 + row * 32 + c);
        A[row * 33 + c] = v.x; A[row * 33 + c + 1] = v.y;
        A[row * 33 + c + 2] = v.z; A[row * 33 + c + 3] = v.w;
        float4 u = *(const float4*)(b0 + row * 32 + c);
        B[row * 33 + c] = u.x; B[row * 33 + c + 1] = u.y;
        B[row * 33 + c + 2] = u.z; B[row * 33 + c + 3] = u.w;
    }
    __syncthreads();
    int tx = threadIdx.x & 15, ty = threadIdx.x >> 4;
    float acc[4][4];
#pragma unroll
    for (int i = 0; i < 4; ++i)
#pragma unroll
        for (int j = 0; j < 4; ++j) acc[i][j] = 0.f;
#pragma unroll
    for (int k = 0; k < 32; ++k) {
        float a[4], b[4];
#pragma unroll
        for (int i = 0; i < 4; ++i) a[i] = A[(ty * 4 + i) * 33 + k];
#pragma unroll
        for (int j = 0; j < 4; ++j) b[j] = B[(tx * 4 + j) * 33 + k];
#pragma unroll
        for (int i = 0; i < 4; ++i)
#pragma unroll
            for (int j = 0; j < 4; ++j) acc[i][j] = fmaf(a[i], b[j], acc[i][j]);
    }
    float mn = acc[0][0], mx = acc[0][0];
#pragma unroll
    for (int i = 0; i < 4; ++i)
#pragma unroll
        for (int j = 0; j < 4; ++j) {
            mn = fminf(mn, acc[i][j]);
            mx = fmaxf(mx, acc[i][j]);
        }
    rmin[threadIdx.x] = mn;
    rmax[threadIdx.x] = mx;
    __syncthreads();
    for (int s2 = 128; s2 > 0; s2 >>= 1) {
        if (threadIdx.x < s2) {
            rmin[threadIdx.x] = fminf(rmin[threadIdx.x], rmin[threadIdx.x + s2]);
            rmax[threadIdx.x] = fmaxf(rmax[threadIdx.x], rmax[threadIdx.x + s2]);
        }
        __syncthreads();
    }
    if (threadIdx.x == 0) {
        atomicMin(&mm[0], fkey(rmin[0]));
        atomicMax(&mm[1], fkey(rmax[0]));
    }
}

__global__ __launch_bounds__(256) void sim_hist(const float* __restrict__ af1,
                                                const float* __restrict__ af2, int N,
                                                const unsigned* __restrict__ mm,
                                                unsigned* __restrict__ hist) {
    __shared__ float A[64 * 33];
    __shared__ float B[64 * 33];
    __shared__ unsigned hs[16];
    if (threadIdx.x < 16) hs[threadIdx.x] = 0;
    int nb = N >> 6;
    int by = blockIdx.x / nb;
    int bx = blockIdx.x % nb;
    const float* a0 = af1 + ((size_t)by * 64) * 32;
    const float* b0 = af2 + ((size_t)bx * 64) * 32;
    for (int t = threadIdx.x; t < 512; t += 256) {
        int row = t >> 3, c = (t & 7) << 2;
        float4 v = *(const float4*)(a0 + row * 32 + c);
        A[row * 33 + c] = v.x; A[row * 33 + c + 1] = v.y;
        A[row * 33 + c + 2] = v.z; A[row * 33 + c + 3] = v.w;
        float4 u = *(const float4*)(b0 + row * 32 + c);
        B[row * 33 + c] = u.x; B[row * 33 + c + 1] = u.y;
        B[row * 33 + c + 2] = u.z; B[row * 33 + c + 3] = u.w;
    }
    __syncthreads();
    int tx = threadIdx.x & 15, ty = threadIdx.x >> 4;
    float acc[4][4];
#pragma unroll
    for (int i = 0; i < 4; ++i)
#pragma unroll
        for (int j = 0; j < 4; ++j) acc[i][j] = 0.f;
#pragma unroll
    for (int k = 0; k < 32; ++k) {
        float a[4], b[4];
#pragma unroll
        for (int i = 0; i < 4; ++i) a[i] = A[(ty * 4 + i) * 33 + k];
#pragma unroll
        for (int j = 0; j < 4; ++j) b[j] = B[(tx * 4 + j) * 33 + k];
#pragma unroll
        for (int i = 0; i < 4; ++i)
#pragma unroll
            for (int j = 0; j < 4; ++j) acc[i][j] = fmaf(a[i], b[j], acc[i][j]);
    }
    float mn = funkey(mm[0]);
    float mx = funkey(mm[1]);
    float width = (mx > mn) ? (mx - mn) : 1.0f;
    float scale = 16.0f / width;
    int lane = threadIdx.x & 63;
    // ballot-aggregated binning: one LDS atomic per (wave, bin) instead of per lane.
#pragma unroll
    for (int i = 0; i < 4; ++i)
#pragma unroll
        for (int j = 0; j < 4; ++j) {
            float v = acc[i][j];
            int bin = (int)((v - mn) * scale);
            bin = bin < 0 ? 0 : (bin > 15 ? 15 : bin);
            for (int bb = 0; bb < 16; ++bb) {
                unsigned long long m = __ballot(bin == bb);
                if (m) {
                    if ((int)__builtin_ctzll(m) == lane)
                        atomicAdd(&hs[bb], (unsigned)__builtin_popcountll(m));
                }
            }
        }
    __syncthreads();
    if (threadIdx.x < 16 && hs[threadIdx.x]) atomicAdd(&hist[threadIdx.x], hs[threadIdx.x]);
}

// ---------------- final MLP head ----------------
__global__ void final_mlp(const float* __restrict__ ntn_out, const unsigned* __restrict__ hist,
                          const float* __restrict__ fc1W, const float* __restrict__ fc1b,
                          const float* __restrict__ fc2W, const float* __restrict__ fc2b,
                          const float* __restrict__ fc3W, const float* __restrict__ fc3b,
                          const float* __restrict__ scW, const float* __restrict__ scb,
                          const float* __restrict__ avg_v, float* __restrict__ out) {
    if (threadIdx.x != 0 || blockIdx.x != 0) return;
    float s[32];
    for (int k = 0; k < 16; ++k) s[k] = ntn_out[k];
    unsigned tot = 0;
    for (int b = 0; b < 16; ++b) tot += hist[b];
    float ftot = (float)tot;
    for (int b = 0; b < 16; ++b) s[16 + b] = (float)hist[b] / ftot;
    float h1[16];
    for (int r = 0; r < 16; ++r) {
        float a = fc1b[r];
        for (int m = 0; m < 32; ++m) a = fmaf(s[m], fc1W[m * 16 + r], a);
        h1[r] = fmaxf(a, 0.f);
    }
    float h2[8];
    for (int r = 0; r < 8; ++r) {
        float a = fc2b[r];
        for (int m = 0; m < 16; ++m) a = fmaf(h1[m], fc2W[m * 8 + r], a);
        h2[r] = fmaxf(a, 0.f);
    }
    float h3[4];
    for (int r = 0; r < 4; ++r) {
        float a = fc3b[r];
        for (int m = 0; m < 8; ++m) a = fmaf(h2[m], fc3W[m * 4 + r], a);
        h3[r] = fmaxf(a, 0.f);
    }
    float z = scb[0];
    for (int m = 0; m < 4; ++m) z = fmaf(h3[m], scW[m], z);
    float sig = 1.f / (1.f + expf(-z));
    out[0] = sig;
    out[1] = -logf(sig) * avg_v[0];
}

// ---------------------------------------------------------------------------
extern "C" void kernel_launch(void* const* d_in, const int* in_sizes, int n_in,
                              void* d_out, int out_size, void* d_ws, size_t ws_size,
                              hipStream_t stream) {
    (void)n_in; (void)out_size; (void)ws_size;
    const int* ei1 = (const int*)d_in[0];
    const int* ei2 = (const int*)d_in[1];
    const float* feat1 = (const float*)d_in[2];
    const float* feat2 = (const float*)d_in[3];
    const float* avg_v = (const float*)d_in[4];
    const float* W1 = (const float*)d_in[5];
    const float* b1 = (const float*)d_in[6];
    const float* W2 = (const float*)d_in[7];
    const float* b2 = (const float*)d_in[8];
    const float* W3 = (const float*)d_in[9];
    const float* b3 = (const float*)d_in[10];
    const float* Wa = (const float*)d_in[11];
    const float* Wt = (const float*)d_in[12];
    const float* V = (const float*)d_in[13];
    const float* bt = (const float*)d_in[14];
    const float* fc1W = (const float*)d_in[15];
    const float* fc1b = (const float*)d_in[16];
    const float* fc2W = (const float*)d_in[17];
    const float* fc2b = (const float*)d_in[18];
    const float* fc3W = (const float*)d_in[19];
    const float* fc3b = (const float*)d_in[20];
    const float* scW = (const float*)d_in[21];
    const float* scb = (const float*)d_in[22];

    const int E = in_sizes[0] / 2;
    const int N = in_sizes[2] / 64;

    // ---- workspace layout ----
    char* w = (char*)d_ws;
    size_t off = 0;
    auto take = [&](size_t bytes) -> void* {
        void* p = w + off;
        off = (off + bytes + 255) & ~(size_t)255;
        return p;
    };
    float* dinv = (float*)take((size_t)N * 4);
    int* cnt = (int*)take((size_t)N * 4);
    int* offs = (int*)take((size_t)(N + 1) * 4);
    int* cursor = (int*)take((size_t)N * 4);
    int* esrc = (int*)take((size_t)E * 4);
    float* bufA = (float*)take((size_t)N * 128 * 4);
    float* bufB = (float*)take((size_t)N * 128 * 4);
    float* af0 = (float*)take((size_t)N * 32 * 4);
    float* af1p = (float*)take((size_t)N * 32 * 4);
    float* ctx = (float*)take(2 * 32 * 4);
    float* p12 = (float*)take(2 * 32 * 4);
    float* ntn_out = (float*)take(16 * 4);
    unsigned* mm = (unsigned*)take(2 * 4);
    unsigned* hist = (unsigned*)take(16 * 4);

    float* afg[2] = {af0, af1p};

    for (int g = 0; g < 2; ++g) {
        const int* ei = g ? ei2 : ei1;
        const float* x = g ? feat2 : feat1;
        const int* src = ei;
        const int* tgt = ei + E;

        hipMemsetAsync(cnt, 0, (size_t)N * 4, stream);
        count_tgt<<<(E + 255) / 256, 256, 0, stream>>>(tgt, cnt, E);
        scan_offsets<<<1, 1024, 0, stream>>>(cnt, offs, cursor, N);
        scatter_src<<<(E + 255) / 256, 256, 0, stream>>>(src, tgt, cursor, esrc, E);
        make_dinv<<<(N + 255) / 256, 256, 0, stream>>>(cnt, dinv, N);

        gemm_lds<64, 128><<<N / 2, 256, 0, stream>>>(x, W1, bufA, N);
        agg_csr<128, true><<<N / 2, 256, 0, stream>>>(bufA, offs, esrc, dinv, b1, bufB, N);
        gemm_lds<128, 64><<<N / 4, 256, 0, stream>>>(bufB, W2, bufA, N);
        agg_csr<64, true><<<N / 4, 256, 0, stream>>>(bufA, offs, esrc, dinv, b2, bufB, N);
        gemm_lds<64, 32><<<N / 8, 256, 0, stream>>>(bufB, W3, bufA, N);
        agg_csr<32, false><<<N / 8, 256, 0, stream>>>(bufA, offs, esrc, dinv, b3, afg[g], N);

        colmean_ctx<<<1, 256, 0, stream>>>(afg[g], Wa, ctx + g * 32, N);
        att_pool<<<1, 256, 0, stream>>>(afg[g], ctx + g * 32, p12 + g * 32, N);
    }

    ntn_kernel<<<1, 64, 0, stream>>>(p12, p12 + 32, Wt, V, bt, ntn_out);

    hipMemsetAsync(mm, 0xFF, 4, stream);       // min key = 0xFFFFFFFF
    hipMemsetAsync(mm + 1, 0, 4, stream);      // max key = 0
    hipMemsetAsync(hist, 0, 16 * 4, stream);

    int nb = N / 64;
    sim_minmax<<<nb * nb, 256, 0, stream>>>(afg[0], afg[1], N, mm);
    sim_hist<<<nb * nb, 256, 0, stream>>>(afg[0], afg[1], N, mm, hist);

    final_mlp<<<1, 64, 0, stream>>>(ntn_out, hist, fc1W, fc1b, fc2W, fc2b, fc3W, fc3b,
                                    scW, scb, avg_v, (float*)d_out);
}

// Round 2
// 700.222 us; speedup vs baseline: 2.9004x; 2.9004x over previous
//
#include <hip/hip_runtime.h>
#include <math.h>

// ---------------------------------------------------------------------------
// SimGNN forward on MI355X.  All f32.
//   per graph: CSR-by-tgt build -> 3x (GEMM + CSR gather aggregation)
//   attention pool (colmean trick), NTN, 2-pass tiled similarity histogram
//   (128x128 tiles, register-packed histogram, no ballots), tiny MLP head.
// ---------------------------------------------------------------------------

// ---------------- CSR build ----------------
__global__ void count_tgt(const int* __restrict__ tgt, int* __restrict__ cnt, int E) {
    int g = blockIdx.x * blockDim.x + threadIdx.x;
    if (g < E) atomicAdd(&cnt[tgt[g]], 1);
}

__global__ __launch_bounds__(1024) void scan_offsets(const int* __restrict__ cnt,
                                                     int* __restrict__ offs,
                                                     int* __restrict__ cursor, int N) {
    __shared__ int part[1024];
    int tid = threadIdx.x;
    int chunk = (N + 1023) >> 10;
    int base = tid * chunk;
    int s = 0;
    for (int i = 0; i < chunk; ++i) {
        int idx = base + i;
        if (idx < N) s += cnt[idx];
    }
    part[tid] = s;
    __syncthreads();
    for (int d = 1; d < 1024; d <<= 1) {
        int v = (tid >= d) ? part[tid - d] : 0;
        __syncthreads();
        part[tid] += v;
        __syncthreads();
    }
    int run = (tid > 0) ? part[tid - 1] : 0;
    for (int i = 0; i < chunk; ++i) {
        int idx = base + i;
        if (idx < N) {
            offs[idx] = run;
            cursor[idx] = run;
            run += cnt[idx];
        }
    }
    if (tid == 1023) offs[N] = part[1023];
}

__global__ void scatter_src(const int* __restrict__ src, const int* __restrict__ tgt,
                            int* __restrict__ cursor, int* __restrict__ esrc, int E) {
    int g = blockIdx.x * blockDim.x + threadIdx.x;
    if (g < E) {
        int t = tgt[g];
        int pos = atomicAdd(&cursor[t], 1);
        esrc[pos] = src[g];
    }
}

__global__ void make_dinv(const int* __restrict__ cnt, float* __restrict__ dinv, int N) {
    int i = blockIdx.x * blockDim.x + threadIdx.x;
    if (i < N) {
        float d = (float)(cnt[i] + 1);  // +1 self loop
        dinv[i] = 1.0f / sqrtf(d);
    }
}

// ---------------- GEMM: out[N,FOUT] = x[N,FIN] @ W[FIN,FOUT] ----------------
template <int FIN, int FOUT>
__global__ __launch_bounds__(256) void gemm_lds(const float* __restrict__ x,
                                                const float* __restrict__ W,
                                                float* __restrict__ out, int N) {
    constexpr int RPB = 256 / FOUT;
    __shared__ float Wl[FIN * FOUT];
    for (int t = threadIdx.x; t < FIN * FOUT; t += 256) Wl[t] = W[t];
    __syncthreads();
    int fx = threadIdx.x % FOUT;
    int r = blockIdx.x * RPB + threadIdx.x / FOUT;
    if (r >= N) return;
    const float* xr = x + (size_t)r * FIN;
    float acc = 0.f;
#pragma unroll
    for (int k = 0; k < FIN; ++k) acc = fmaf(xr[k], Wl[k * FOUT + fx], acc);
    out[(size_t)r * FOUT + fx] = acc;
}

// ------------- GCN aggregation: out[t] = relu?(dt*(dt*h[t] + sum ds*h[s]) + b) -------------
template <int F, bool RELU>
__global__ __launch_bounds__(256) void agg_csr(const float* __restrict__ h,
                                               const int* __restrict__ offs,
                                               const int* __restrict__ esrc,
                                               const float* __restrict__ dinv,
                                               const float* __restrict__ b,
                                               float* __restrict__ out, int N) {
    constexpr int RPB = 256 / F;
    int fx = threadIdx.x % F;
    int t = blockIdx.x * RPB + threadIdx.x / F;
    if (t >= N) return;
    float dt = dinv[t];
    float acc = dt * h[(size_t)t * F + fx];  // self loop term (dt^2 * h[t]) / dt
    int e1 = offs[t + 1];
    for (int e = offs[t]; e < e1; ++e) {
        int s = esrc[e];
        acc = fmaf(dinv[s], h[(size_t)s * F + fx], acc);
    }
    float v = fmaf(dt, acc, b[fx]);
    if (RELU) v = fmaxf(v, 0.f);
    out[(size_t)t * F + fx] = v;
}

// ---------------- attention pool ----------------
__global__ __launch_bounds__(256) void colmean_ctx(const float* __restrict__ af,
                                                   const float* __restrict__ Wa,
                                                   float* __restrict__ ctx, int N) {
    __shared__ float red[32 * 256];
    __shared__ float mean[32];
    int tid = threadIdx.x;
    float acc[32];
#pragma unroll
    for (int f = 0; f < 32; ++f) acc[f] = 0.f;
    for (int r = tid; r < N; r += 256) {
        const float4* row = (const float4*)(af + (size_t)r * 32);
#pragma unroll
        for (int q = 0; q < 8; ++q) {
            float4 v = row[q];
            acc[q * 4 + 0] += v.x;
            acc[q * 4 + 1] += v.y;
            acc[q * 4 + 2] += v.z;
            acc[q * 4 + 3] += v.w;
        }
    }
#pragma unroll
    for (int f = 0; f < 32; ++f) red[f * 256 + tid] = acc[f];
    __syncthreads();
    if (tid < 32) {
        float s = 0.f;
        for (int j = 0; j < 256; ++j) s += red[tid * 256 + j];
        mean[tid] = s / (float)N;
    }
    __syncthreads();
    if (tid < 32) {
        float s = 0.f;
        for (int d = 0; d < 32; ++d) s = fmaf(mean[d], Wa[d * 32 + tid], s);
        ctx[tid] = tanhf(s);
    }
}

__global__ __launch_bounds__(256) void att_pool(const float* __restrict__ af,
                                                const float* __restrict__ ctx,
                                                float* __restrict__ p, int N) {
    __shared__ float red[32 * 256];
    __shared__ float ctxl[32];
    int tid = threadIdx.x;
    if (tid < 32) ctxl[tid] = ctx[tid];
    __syncthreads();
    float acc[32];
#pragma unroll
    for (int f = 0; f < 32; ++f) acc[f] = 0.f;
    for (int r = tid; r < N; r += 256) {
        float rowv[32];
        const float4* row = (const float4*)(af + (size_t)r * 32);
#pragma unroll
        for (int q = 0; q < 8; ++q) {
            float4 v = row[q];
            rowv[q * 4 + 0] = v.x;
            rowv[q * 4 + 1] = v.y;
            rowv[q * 4 + 2] = v.z;
            rowv[q * 4 + 3] = v.w;
        }
        float dot = 0.f;
#pragma unroll
        for (int f = 0; f < 32; ++f) dot = fmaf(rowv[f], ctxl[f], dot);
        float att = 1.f / (1.f + expf(-dot));
#pragma unroll
        for (int f = 0; f < 32; ++f) acc[f] = fmaf(att, rowv[f], acc[f]);
    }
#pragma unroll
    for (int f = 0; f < 32; ++f) red[f * 256 + tid] = acc[f];
    __syncthreads();
    if (tid < 32) {
        float s = 0.f;
        for (int j = 0; j < 256; ++j) s += red[tid * 256 + j];
        p[tid] = s;
    }
}

// ---------------- NTN ----------------
__global__ void ntn_kernel(const float* __restrict__ p1, const float* __restrict__ p2,
                           const float* __restrict__ Wt, const float* __restrict__ V,
                           const float* __restrict__ bt, float* __restrict__ outk) {
    int k = threadIdx.x;
    if (k >= 16) return;
    float sc = 0.f;
    for (int d = 0; d < 32; ++d) {
        float a = p1[d];
        for (int e = 0; e < 32; ++e) sc = fmaf(a * p2[e], Wt[(d * 32 + e) * 16 + k], sc);
    }
    float bl = 0.f;
    for (int m = 0; m < 32; ++m) bl = fmaf(V[k * 64 + m], p1[m], bl);
    for (int m = 0; m < 32; ++m) bl = fmaf(V[k * 64 + 32 + m], p2[m], bl);
    outk[k] = fmaxf(sc + bl + bt[k], 0.f);
}

// ---------------- similarity pass (s never materialized) ----------------
// 128x128 tile per 256-thread block, 8x8 values per thread, K=32.
// A/B staged k-major in LDS (pad 132) so fragment loads are ds_read_b128.
// HIST=false: block min/max -> ordered-uint global atomics.
// HIST=true : packed register histogram (16x 8-bit fields in 4 u32),
//             shfl reduce (1 level @8bit, unpack, 5 levels @16bit),
//             LDS merge, 16 padded global atomics per block.

#define GH_STRIDE 32  // pad hist bins to separate cachelines

__device__ __forceinline__ unsigned fkey(float f) {
    unsigned u = __float_as_uint(f);
    return (u & 0x80000000u) ? ~u : (u | 0x80000000u);
}
__device__ __forceinline__ float funkey(unsigned k) {
    unsigned u = (k & 0x80000000u) ? (k & 0x7fffffffu) : ~k;
    return __uint_as_float(u);
}

template <bool HIST>
__global__ __launch_bounds__(256) void sim_pass(const float* __restrict__ af1,
                                                const float* __restrict__ af2, int N,
                                                unsigned* __restrict__ mm,
                                                unsigned* __restrict__ ghist) {
    __shared__ float At[32][132];
    __shared__ float Bt[32][132];
    int nb = N >> 7;
    int by = blockIdx.x / nb;
    int bx = blockIdx.x % nb;
    const float* a0 = af1 + ((size_t)by * 128) * 32;
    const float* b0 = af2 + ((size_t)bx * 128) * 32;
    // stage k-major: 1024 float4 chunks per matrix, 4 per thread
    for (int c = threadIdx.x; c < 1024; c += 256) {
        int row = c >> 3, kq = (c & 7) << 2;
        float4 va = *(const float4*)(a0 + row * 32 + kq);
        At[kq + 0][row] = va.x; At[kq + 1][row] = va.y;
        At[kq + 2][row] = va.z; At[kq + 3][row] = va.w;
        float4 vb = *(const float4*)(b0 + row * 32 + kq);
        Bt[kq + 0][row] = vb.x; Bt[kq + 1][row] = vb.y;
        Bt[kq + 2][row] = vb.z; Bt[kq + 3][row] = vb.w;
    }
    __syncthreads();

    int tx = threadIdx.x & 15, ty = threadIdx.x >> 4;
    int ar = ty * 8, bc = tx * 8;
    float acc[8][8];
#pragma unroll
    for (int i = 0; i < 8; ++i)
#pragma unroll
        for (int j = 0; j < 8; ++j) acc[i][j] = 0.f;

#pragma unroll 4
    for (int k = 0; k < 32; ++k) {
        float4 av0 = *(const float4*)&At[k][ar];
        float4 av1 = *(const float4*)&At[k][ar + 4];
        float4 bv0 = *(const float4*)&Bt[k][bc];
        float4 bv1 = *(const float4*)&Bt[k][bc + 4];
        float a[8] = {av0.x, av0.y, av0.z, av0.w, av1.x, av1.y, av1.z, av1.w};
        float b[8] = {bv0.x, bv0.y, bv0.z, bv0.w, bv1.x, bv1.y, bv1.z, bv1.w};
#pragma unroll
        for (int i = 0; i < 8; ++i)
#pragma unroll
            for (int j = 0; j < 8; ++j) acc[i][j] = fmaf(a[i], b[j], acc[i][j]);
    }

    if (!HIST) {
        float mn = acc[0][0], mx = acc[0][0];
#pragma unroll
        for (int i = 0; i < 8; ++i)
#pragma unroll
            for (int j = 0; j < 8; ++j) {
                mn = fminf(mn, acc[i][j]);
                mx = fmaxf(mx, acc[i][j]);
            }
#pragma unroll
        for (int off = 1; off < 64; off <<= 1) {
            mn = fminf(mn, __shfl_xor(mn, off));
            mx = fmaxf(mx, __shfl_xor(mx, off));
        }
        __shared__ float wmn[4], wmx[4];
        int lane = threadIdx.x & 63, wid = threadIdx.x >> 6;
        if (lane == 0) { wmn[wid] = mn; wmx[wid] = mx; }
        __syncthreads();
        if (threadIdx.x == 0) {
            float bmn = fminf(fminf(wmn[0], wmn[1]), fminf(wmn[2], wmn[3]));
            float bmx = fmaxf(fmaxf(wmx[0], wmx[1]), fmaxf(wmx[2], wmx[3]));
            atomicMin(&mm[0], fkey(bmn));
            atomicMax(&mm[1], fkey(bmx));
        }
    } else {
        float mnv = funkey(mm[0]);
        float mxv = funkey(mm[1]);
        float width = (mxv > mnv) ? (mxv - mnv) : 1.0f;
        float scale = 16.0f / width;
        unsigned h4_0 = 0, h4_1 = 0, h4_2 = 0, h4_3 = 0;
#pragma unroll
        for (int i = 0; i < 8; ++i)
#pragma unroll
            for (int j = 0; j < 8; ++j) {
                float v = acc[i][j];
                int bin = (int)((v - mnv) * scale);
                bin = bin < 0 ? 0 : (bin > 15 ? 15 : bin);
                unsigned w = 1u << ((bin & 3) << 3);
                int hi = bin >> 2;
                h4_0 += (hi == 0) ? w : 0u;
                h4_1 += (hi == 1) ? w : 0u;
                h4_2 += (hi == 2) ? w : 0u;
                h4_3 += (hi == 3) ? w : 0u;
            }
        // lane-pair reduce at 8-bit fields (max 128 <= 255)
        h4_0 += (unsigned)__shfl_xor((int)h4_0, 1);
        h4_1 += (unsigned)__shfl_xor((int)h4_1, 1);
        h4_2 += (unsigned)__shfl_xor((int)h4_2, 1);
        h4_3 += (unsigned)__shfl_xor((int)h4_3, 1);
        // unpack to 16-bit fields: hh[2q] = bins {4q, 4q+2}, hh[2q+1] = {4q+1, 4q+3}
        unsigned hh[8];
        hh[0] = h4_0 & 0x00FF00FFu; hh[1] = (h4_0 >> 8) & 0x00FF00FFu;
        hh[2] = h4_1 & 0x00FF00FFu; hh[3] = (h4_1 >> 8) & 0x00FF00FFu;
        hh[4] = h4_2 & 0x00FF00FFu; hh[5] = (h4_2 >> 8) & 0x00FF00FFu;
        hh[6] = h4_3 & 0x00FF00FFu; hh[7] = (h4_3 >> 8) & 0x00FF00FFu;
#pragma unroll
        for (int off = 2; off < 64; off <<= 1) {
#pragma unroll
            for (int q = 0; q < 8; ++q) hh[q] += (unsigned)__shfl_xor((int)hh[q], off);
        }
        __shared__ unsigned hs[16];
        if (threadIdx.x < 16) hs[threadIdx.x] = 0;
        __syncthreads();
        int lane = threadIdx.x & 63;
        if (lane == 0) {
#pragma unroll
            for (int q = 0; q < 4; ++q) {
                atomicAdd(&hs[4 * q + 0], hh[2 * q] & 0xFFFFu);
                atomicAdd(&hs[4 * q + 1], hh[2 * q + 1] & 0xFFFFu);
                atomicAdd(&hs[4 * q + 2], hh[2 * q] >> 16);
                atomicAdd(&hs[4 * q + 3], hh[2 * q + 1] >> 16);
            }
        }
        __syncthreads();
        if (threadIdx.x < 16) atomicAdd(&ghist[threadIdx.x * GH_STRIDE], hs[threadIdx.x]);
    }
}

// ---------------- final MLP head ----------------
__global__ void final_mlp(const float* __restrict__ ntn_out, const unsigned* __restrict__ hist,
                          const float* __restrict__ fc1W, const float* __restrict__ fc1b,
                          const float* __restrict__ fc2W, const float* __restrict__ fc2b,
                          const float* __restrict__ fc3W, const float* __restrict__ fc3b,
                          const float* __restrict__ scW, const float* __restrict__ scb,
                          const float* __restrict__ avg_v, float* __restrict__ out) {
    if (threadIdx.x != 0 || blockIdx.x != 0) return;
    float s[32];
    for (int k = 0; k < 16; ++k) s[k] = ntn_out[k];
    unsigned tot = 0;
    for (int b = 0; b < 16; ++b) tot += hist[b * GH_STRIDE];
    float ftot = (float)tot;
    for (int b = 0; b < 16; ++b) s[16 + b] = (float)hist[b * GH_STRIDE] / ftot;
    float h1[16];
    for (int r = 0; r < 16; ++r) {
        float a = fc1b[r];
        for (int m = 0; m < 32; ++m) a = fmaf(s[m], fc1W[m * 16 + r], a);
        h1[r] = fmaxf(a, 0.f);
    }
    float h2[8];
    for (int r = 0; r < 8; ++r) {
        float a = fc2b[r];
        for (int m = 0; m < 16; ++m) a = fmaf(h1[m], fc2W[m * 8 + r], a);
        h2[r] = fmaxf(a, 0.f);
    }
    float h3[4];
    for (int r = 0; r < 4; ++r) {
        float a = fc3b[r];
        for (int m = 0; m < 8; ++m) a = fmaf(h2[m], fc3W[m * 4 + r], a);
        h3[r] = fmaxf(a, 0.f);
    }
    float z = scb[0];
    for (int m = 0; m < 4; ++m) z = fmaf(h3[m], scW[m], z);
    float sig = 1.f / (1.f + expf(-z));
    out[0] = sig;
    out[1] = -logf(sig) * avg_v[0];
}

// ---------------------------------------------------------------------------
extern "C" void kernel_launch(void* const* d_in, const int* in_sizes, int n_in,
                              void* d_out, int out_size, void* d_ws, size_t ws_size,
                              hipStream_t stream) {
    (void)n_in; (void)out_size; (void)ws_size;
    const int* ei1 = (const int*)d_in[0];
    const int* ei2 = (const int*)d_in[1];
    const float* feat1 = (const float*)d_in[2];
    const float* feat2 = (const float*)d_in[3];
    const float* avg_v = (const float*)d_in[4];
    const float* W1 = (const float*)d_in[5];
    const float* b1 = (const float*)d_in[6];
    const float* W2 = (const float*)d_in[7];
    const float* b2 = (const float*)d_in[8];
    const float* W3 = (const float*)d_in[9];
    const float* b3 = (const float*)d_in[10];
    const float* Wa = (const float*)d_in[11];
    const float* Wt = (const float*)d_in[12];
    const float* V = (const float*)d_in[13];
    const float* bt = (const float*)d_in[14];
    const float* fc1W = (const float*)d_in[15];
    const float* fc1b = (const float*)d_in[16];
    const float* fc2W = (const float*)d_in[17];
    const float* fc2b = (const float*)d_in[18];
    const float* fc3W = (const float*)d_in[19];
    const float* fc3b = (const float*)d_in[20];
    const float* scW = (const float*)d_in[21];
    const float* scb = (const float*)d_in[22];

    const int E = in_sizes[0] / 2;
    const int N = in_sizes[2] / 64;

    // ---- workspace layout ----
    char* w = (char*)d_ws;
    size_t off = 0;
    auto take = [&](size_t bytes) -> void* {
        void* p = w + off;
        off = (off + bytes + 255) & ~(size_t)255;
        return p;
    };
    float* dinv = (float*)take((size_t)N * 4);
    int* cnt = (int*)take((size_t)N * 4);
    int* offs = (int*)take((size_t)(N + 1) * 4);
    int* cursor = (int*)take((size_t)N * 4);
    int* esrc = (int*)take((size_t)E * 4);
    float* bufA = (float*)take((size_t)N * 128 * 4);
    float* bufB = (float*)take((size_t)N * 128 * 4);
    float* af0 = (float*)take((size_t)N * 32 * 4);
    float* af1p = (float*)take((size_t)N * 32 * 4);
    float* ctx = (float*)take(2 * 32 * 4);
    float* p12 = (float*)take(2 * 32 * 4);
    float* ntn_out = (float*)take(16 * 4);
    unsigned* mm = (unsigned*)take(2 * 4);
    unsigned* hist = (unsigned*)take(16 * GH_STRIDE * 4);

    float* afg[2] = {af0, af1p};

    for (int g = 0; g < 2; ++g) {
        const int* ei = g ? ei2 : ei1;
        const float* x = g ? feat2 : feat1;
        const int* src = ei;
        const int* tgt = ei + E;

        hipMemsetAsync(cnt, 0, (size_t)N * 4, stream);
        count_tgt<<<(E + 255) / 256, 256, 0, stream>>>(tgt, cnt, E);
        scan_offsets<<<1, 1024, 0, stream>>>(cnt, offs, cursor, N);
        scatter_src<<<(E + 255) / 256, 256, 0, stream>>>(src, tgt, cursor, esrc, E);
        make_dinv<<<(N + 255) / 256, 256, 0, stream>>>(cnt, dinv, N);

        gemm_lds<64, 128><<<N / 2, 256, 0, stream>>>(x, W1, bufA, N);
        agg_csr<128, true><<<N / 2, 256, 0, stream>>>(bufA, offs, esrc, dinv, b1, bufB, N);
        gemm_lds<128, 64><<<N / 4, 256, 0, stream>>>(bufB, W2, bufA, N);
        agg_csr<64, true><<<N / 4, 256, 0, stream>>>(bufA, offs, esrc, dinv, b2, bufB, N);
        gemm_lds<64, 32><<<N / 8, 256, 0, stream>>>(bufB, W3, bufA, N);
        agg_csr<32, false><<<N / 8, 256, 0, stream>>>(bufA, offs, esrc, dinv, b3, afg[g], N);

        colmean_ctx<<<1, 256, 0, stream>>>(afg[g], Wa, ctx + g * 32, N);
        att_pool<<<1, 256, 0, stream>>>(afg[g], ctx + g * 32, p12 + g * 32, N);
    }

    ntn_kernel<<<1, 64, 0, stream>>>(p12, p12 + 32, Wt, V, bt, ntn_out);

    hipMemsetAsync(mm, 0xFF, 4, stream);       // min key = 0xFFFFFFFF
    hipMemsetAsync(mm + 1, 0, 4, stream);      // max key = 0
    hipMemsetAsync(hist, 0, 16 * GH_STRIDE * 4, stream);

    int nb = N / 128;
    sim_pass<false><<<nb * nb, 256, 0, stream>>>(afg[0], afg[1], N, mm, hist);
    sim_pass<true><<<nb * nb, 256, 0, stream>>>(afg[0], afg[1], N, mm, hist);

    final_mlp<<<1, 64, 0, stream>>>(ntn_out, hist, fc1W, fc1b, fc2W, fc2b, fc3W, fc3b,
                                    scW, scb, avg_v, (float*)d_out);
}

// Round 3
// 511.595 us; speedup vs baseline: 3.9698x; 1.3687x over previous
//
#include <hip/hip_runtime.h>
#include <math.h>

// ---------------------------------------------------------------------------
// SimGNN forward on MI355X (gfx950).  f32 GCN pipeline, bf16-MFMA similarity
// histogram.  Both graphs batched via blockIdx.y (sequential fallback if ws
// is tight).
// ---------------------------------------------------------------------------

#define GH_STRIDE 32  // pad hist bins to separate cachelines

using bf16x8 = __attribute__((ext_vector_type(8))) short;
using f32x4  = __attribute__((ext_vector_type(4))) float;

__device__ __forceinline__ unsigned fkey(float f) {
    unsigned u = __float_as_uint(f);
    return (u & 0x80000000u) ? ~u : (u | 0x80000000u);
}
__device__ __forceinline__ float funkey(unsigned k) {
    unsigned u = (k & 0x80000000u) ? (k & 0x7fffffffu) : ~k;
    return __uint_as_float(u);
}
__device__ __forceinline__ unsigned short f2bf(float f) {  // RNE
    unsigned u = __float_as_uint(f);
    unsigned r = ((u >> 16) & 1u) + 0x7FFFu;
    return (unsigned short)((u + r) >> 16);
}

// ---------------- CSR build (batched: blockIdx.y = graph) ----------------
__global__ void count_tgt(const int* __restrict__ t0, const int* __restrict__ t1,
                          int* __restrict__ cnt, int N, int E) {
    int g = blockIdx.y;
    const int* t = g ? t1 : t0;
    int i = blockIdx.x * 256 + threadIdx.x;
    if (i < E) atomicAdd(&cnt[g * N + t[i]], 1);
}

__global__ __launch_bounds__(1024) void scan_offsets(const int* __restrict__ cnt_,
                                                     int* __restrict__ offs_,
                                                     int* __restrict__ cursor_,
                                                     float* __restrict__ dinv_, int N) {
    int g = blockIdx.x;
    const int* cnt = cnt_ + g * N;
    int* offs = offs_ + g * (N + 1);
    int* cursor = cursor_ + g * N;
    float* dinv = dinv_ + g * N;
    __shared__ int part[1024];
    int tid = threadIdx.x;
    int chunk = (N + 1023) >> 10;
    int base = tid * chunk;
    int s = 0;
    for (int i = 0; i < chunk; ++i) {
        int idx = base + i;
        if (idx < N) s += cnt[idx];
    }
    part[tid] = s;
    __syncthreads();
    for (int d = 1; d < 1024; d <<= 1) {
        int v = (tid >= d) ? part[tid - d] : 0;
        __syncthreads();
        part[tid] += v;
        __syncthreads();
    }
    int run = (tid > 0) ? part[tid - 1] : 0;
    for (int i = 0; i < chunk; ++i) {
        int idx = base + i;
        if (idx < N) {
            int c = cnt[idx];
            offs[idx] = run;
            cursor[idx] = run;
            dinv[idx] = 1.0f / sqrtf((float)(c + 1));
            run += c;
        }
    }
    if (tid == 1023) offs[N] = part[1023];
}

__global__ void scatter_src(const int* __restrict__ s0, const int* __restrict__ s1,
                            const int* __restrict__ t0, const int* __restrict__ t1,
                            int* __restrict__ cursor, int* __restrict__ esrc, int N, int E) {
    int g = blockIdx.y;
    const int* src = g ? s1 : s0;
    const int* tgt = g ? t1 : t0;
    int i = blockIdx.x * 256 + threadIdx.x;
    if (i < E) {
        int t = tgt[i];
        int pos = atomicAdd(&cursor[g * N + t], 1);
        esrc[g * E + pos] = src[i];
    }
}

// ---------------- GEMM: out[N,FOUT] = x[N,FIN] @ W[FIN,FOUT] ----------------
template <int FIN, int FOUT>
__global__ __launch_bounds__(256) void gemm_lds(const float* __restrict__ x0,
                                                const float* __restrict__ x1,
                                                const float* __restrict__ W,
                                                float* __restrict__ out, size_t ostride,
                                                int N) {
    int g = blockIdx.y;
    const float* x = g ? x1 : x0;
    out += (size_t)g * ostride;
    constexpr int RPB = 256 / FOUT;
    __shared__ float Wl[FIN * FOUT];
    for (int t = threadIdx.x; t < FIN * FOUT; t += 256) Wl[t] = W[t];
    __syncthreads();
    int fx = threadIdx.x % FOUT;
    int r = blockIdx.x * RPB + threadIdx.x / FOUT;
    if (r >= N) return;
    const float* xr = x + (size_t)r * FIN;
    float acc = 0.f;
#pragma unroll
    for (int k = 0; k < FIN; ++k) acc = fmaf(xr[k], Wl[k * FOUT + fx], acc);
    out[(size_t)r * FOUT + fx] = acc;
}

// ------------- GCN aggregation; optional column-sum pool epilogue -------------
template <int F, bool RELU, bool POOL>
__global__ __launch_bounds__(256) void agg_csr(const float* __restrict__ h0,
                                               const float* __restrict__ h1,
                                               const int* __restrict__ offs_,
                                               const int* __restrict__ esrc_,
                                               const float* __restrict__ dinv_,
                                               const float* __restrict__ b,
                                               float* __restrict__ out, size_t ostride,
                                               float* __restrict__ gsum, int N, int E) {
    int g = blockIdx.y;
    const float* h = g ? h1 : h0;
    const int* offs = offs_ + g * (N + 1);
    const int* esrc = esrc_ + g * E;
    const float* dinv = dinv_ + g * N;
    out += (size_t)g * ostride;
    constexpr int RPB = 256 / F;
    int fx = threadIdx.x % F;
    int t = blockIdx.x * RPB + threadIdx.x / F;
    float v = 0.f;
    if (t < N) {
        float dt = dinv[t];
        float acc = dt * h[(size_t)t * F + fx];  // self-loop / dt
        int e1 = offs[t + 1];
        for (int e = offs[t]; e < e1; ++e) {
            int s = esrc[e];
            acc = fmaf(dinv[s], h[(size_t)s * F + fx], acc);
        }
        v = fmaf(dt, acc, b[fx]);
        if (RELU) v = fmaxf(v, 0.f);
        out[(size_t)t * F + fx] = v;
    }
    if (POOL) {
        __shared__ float ls[F];
        if (threadIdx.x < F) ls[threadIdx.x] = 0.f;
        __syncthreads();
        atomicAdd(&ls[fx], v);
        __syncthreads();
        if (threadIdx.x < F) atomicAdd(&gsum[g * 32 + threadIdx.x], ls[threadIdx.x]);
    }
}

// ---------------- af (f32, both graphs contiguous) -> bf16 ----------------
__global__ void to_bf16(const float* __restrict__ in, unsigned short* __restrict__ out,
                        int n8) {
    int i = blockIdx.x * 256 + threadIdx.x;
    if (i >= n8) return;
    const float4* p = (const float4*)in + (size_t)i * 2;
    float4 v0 = p[0], v1 = p[1];
    unsigned short r[8] = {f2bf(v0.x), f2bf(v0.y), f2bf(v0.z), f2bf(v0.w),
                           f2bf(v1.x), f2bf(v1.y), f2bf(v1.z), f2bf(v1.w)};
    *(bf16x8*)(out + (size_t)i * 8) = *(const bf16x8*)r;
}

// ---------------- ctx = tanh(colmean @ Wa), both graphs ----------------
__global__ void ctx_finalize(const float* __restrict__ gsum, const float* __restrict__ Wa,
                             float* __restrict__ ctx, int N) {
    int t = threadIdx.x;
    if (t >= 64) return;
    int g = t >> 5, c = t & 31;
    float invN = 1.0f / (float)N;
    float s = 0.f;
    for (int d = 0; d < 32; ++d) s = fmaf(gsum[g * 32 + d] * invN, Wa[d * 32 + c], s);
    ctx[g * 32 + c] = tanhf(s);
}

// ---------------- attention pool: p = af^T @ sigmoid(af @ ctx) ----------------
__global__ __launch_bounds__(256) void pool_att(const float* __restrict__ af,
                                                const float* __restrict__ ctx,
                                                float* __restrict__ p12, int N) {
    int g = blockIdx.y;
    af += (size_t)g * N * 32;
    float ctxl[32];
#pragma unroll
    for (int f = 0; f < 32; ++f) ctxl[f] = ctx[g * 32 + f];
    int r = blockIdx.x * 256 + threadIdx.x;
    float rowv[32];
    float att = 0.f;
    if (r < N) {
        const float4* row = (const float4*)(af + (size_t)r * 32);
        float dot = 0.f;
#pragma unroll
        for (int q = 0; q < 8; ++q) {
            float4 v = row[q];
            rowv[q * 4 + 0] = v.x; rowv[q * 4 + 1] = v.y;
            rowv[q * 4 + 2] = v.z; rowv[q * 4 + 3] = v.w;
            dot = fmaf(v.x, ctxl[q * 4 + 0], dot);
            dot = fmaf(v.y, ctxl[q * 4 + 1], dot);
            dot = fmaf(v.z, ctxl[q * 4 + 2], dot);
            dot = fmaf(v.w, ctxl[q * 4 + 3], dot);
        }
        att = 1.f / (1.f + expf(-dot));
    } else {
#pragma unroll
        for (int f = 0; f < 32; ++f) rowv[f] = 0.f;
    }
    __shared__ float wsum[4][32];
    int lane = threadIdx.x & 63, wid = threadIdx.x >> 6;
#pragma unroll
    for (int f = 0; f < 32; ++f) {
        float v = att * rowv[f];
#pragma unroll
        for (int off = 1; off < 64; off <<= 1) v += __shfl_xor(v, off);
        if (lane == 0) wsum[wid][f] = v;
    }
    __syncthreads();
    if (threadIdx.x < 32) {
        float s = wsum[0][threadIdx.x] + wsum[1][threadIdx.x] + wsum[2][threadIdx.x] +
                  wsum[3][threadIdx.x];
        atomicAdd(&p12[g * 32 + threadIdx.x], s);
    }
}

// ---------------- similarity passes: bf16 MFMA, no LDS staging ----------------
// block = 256 thr = 4 waves; block tile 128x128; wave tile 64x64 = 4x4 MFMA
// fragments loaded straight from global (16B contiguous per lane).
template <bool HIST>
__global__ __launch_bounds__(256) void sim_mfma(const unsigned short* __restrict__ a1,
                                                const unsigned short* __restrict__ a2,
                                                int N, unsigned* __restrict__ mm,
                                                unsigned* __restrict__ ghist) {
    int nb = N >> 7;
    int by = blockIdx.x / nb, bx = blockIdx.x % nb;
    int w = threadIdx.x >> 6, lane = threadIdx.x & 63;
    int r16 = lane & 15, kg = (lane >> 4) << 3;
    const unsigned short* arow = a1 + ((size_t)(by * 128 + (w >> 1) * 64 + r16)) * 32 + kg;
    const unsigned short* brow = a2 + ((size_t)(bx * 128 + (w & 1) * 64 + r16)) * 32 + kg;
    bf16x8 afr[4], bfr[4];
#pragma unroll
    for (int m = 0; m < 4; ++m) afr[m] = *(const bf16x8*)(arow + m * 16 * 32);
#pragma unroll
    for (int n = 0; n < 4; ++n) bfr[n] = *(const bf16x8*)(brow + n * 16 * 32);
    f32x4 zero = {0.f, 0.f, 0.f, 0.f};
    f32x4 acc[4][4];
#pragma unroll
    for (int m = 0; m < 4; ++m)
#pragma unroll
        for (int n = 0; n < 4; ++n)
            acc[m][n] = __builtin_amdgcn_mfma_f32_16x16x32_bf16(afr[m], bfr[n], zero, 0, 0, 0);

    if (!HIST) {
        float mn = acc[0][0][0], mx = acc[0][0][0];
#pragma unroll
        for (int m = 0; m < 4; ++m)
#pragma unroll
            for (int n = 0; n < 4; ++n)
#pragma unroll
                for (int e = 0; e < 4; ++e) {
                    float v = acc[m][n][e];
                    mn = fminf(mn, v);
                    mx = fmaxf(mx, v);
                }
#pragma unroll
        for (int off = 1; off < 64; off <<= 1) {
            mn = fminf(mn, __shfl_xor(mn, off));
            mx = fmaxf(mx, __shfl_xor(mx, off));
        }
        __shared__ float wmn[4], wmx[4];
        if (lane == 0) { wmn[w] = mn; wmx[w] = mx; }
        __syncthreads();
        if (threadIdx.x == 0) {
            float bmn = fminf(fminf(wmn[0], wmn[1]), fminf(wmn[2], wmn[3]));
            float bmx = fmaxf(fmaxf(wmx[0], wmx[1]), fmaxf(wmx[2], wmx[3]));
            atomicMax(&mm[0], fkey(bmx));    // max key
            atomicMax(&mm[1], ~fkey(bmn));   // complement-min key (zero-init ok)
        }
    } else {
        float mxv = funkey(mm[0]);
        float mnv = funkey(~mm[1]);
        float width = (mxv > mnv) ? (mxv - mnv) : 1.0f;
        float scale = 16.0f / width;
        unsigned h4_0 = 0, h4_1 = 0, h4_2 = 0, h4_3 = 0;
#pragma unroll
        for (int m = 0; m < 4; ++m)
#pragma unroll
            for (int n = 0; n < 4; ++n)
#pragma unroll
                for (int e = 0; e < 4; ++e) {
                    float v = acc[m][n][e];
                    int bin = (int)((v - mnv) * scale);
                    bin = bin < 0 ? 0 : (bin > 15 ? 15 : bin);
                    unsigned wbit = 1u << ((bin & 3) << 3);
                    int hi = bin >> 2;
                    h4_0 += (hi == 0) ? wbit : 0u;
                    h4_1 += (hi == 1) ? wbit : 0u;
                    h4_2 += (hi == 2) ? wbit : 0u;
                    h4_3 += (hi == 3) ? wbit : 0u;
                }
        // pair reduce at 8-bit fields (max 128 <= 255)
        h4_0 += (unsigned)__shfl_xor((int)h4_0, 1);
        h4_1 += (unsigned)__shfl_xor((int)h4_1, 1);
        h4_2 += (unsigned)__shfl_xor((int)h4_2, 1);
        h4_3 += (unsigned)__shfl_xor((int)h4_3, 1);
        unsigned hh[8];
        hh[0] = h4_0 & 0x00FF00FFu; hh[1] = (h4_0 >> 8) & 0x00FF00FFu;
        hh[2] = h4_1 & 0x00FF00FFu; hh[3] = (h4_1 >> 8) & 0x00FF00FFu;
        hh[4] = h4_2 & 0x00FF00FFu; hh[5] = (h4_2 >> 8) & 0x00FF00FFu;
        hh[6] = h4_3 & 0x00FF00FFu; hh[7] = (h4_3 >> 8) & 0x00FF00FFu;
#pragma unroll
        for (int off = 2; off < 64; off <<= 1) {
#pragma unroll
            for (int q = 0; q < 8; ++q) hh[q] += (unsigned)__shfl_xor((int)hh[q], off);
        }
        __shared__ unsigned hs[16];
        if (threadIdx.x < 16) hs[threadIdx.x] = 0;
        __syncthreads();
        if (lane == 0) {
#pragma unroll
            for (int q = 0; q < 4; ++q) {
                atomicAdd(&hs[4 * q + 0], hh[2 * q] & 0xFFFFu);
                atomicAdd(&hs[4 * q + 1], hh[2 * q + 1] & 0xFFFFu);
                atomicAdd(&hs[4 * q + 2], hh[2 * q] >> 16);
                atomicAdd(&hs[4 * q + 3], hh[2 * q + 1] >> 16);
            }
        }
        __syncthreads();
        if (threadIdx.x < 16) atomicAdd(&ghist[threadIdx.x * GH_STRIDE], hs[threadIdx.x]);
    }
}

// ---------------- NTN + final MLP head (fused) ----------------
__global__ void ntn_final(const float* __restrict__ p12, const float* __restrict__ Wt,
                          const float* __restrict__ V, const float* __restrict__ bt,
                          const unsigned* __restrict__ hist,
                          const float* __restrict__ fc1W, const float* __restrict__ fc1b,
                          const float* __restrict__ fc2W, const float* __restrict__ fc2b,
                          const float* __restrict__ fc3W, const float* __restrict__ fc3b,
                          const float* __restrict__ scW, const float* __restrict__ scb,
                          const float* __restrict__ avg_v, float* __restrict__ out) {
    __shared__ float sc[16];
    const float* p1 = p12;
    const float* p2 = p12 + 32;
    int k = threadIdx.x;
    if (k < 16) {
        float s = 0.f;
        for (int d = 0; d < 32; ++d) {
            float a = p1[d];
            for (int e = 0; e < 32; ++e) s = fmaf(a * p2[e], Wt[(d * 32 + e) * 16 + k], s);
        }
        float bl = 0.f;
        for (int m = 0; m < 32; ++m) bl = fmaf(V[k * 64 + m], p1[m], bl);
        for (int m = 0; m < 32; ++m) bl = fmaf(V[k * 64 + 32 + m], p2[m], bl);
        sc[k] = fmaxf(s + bl + bt[k], 0.f);
    }
    __syncthreads();
    if (k != 0) return;
    float s[32];
    for (int i = 0; i < 16; ++i) s[i] = sc[i];
    unsigned tot = 0;
    for (int b = 0; b < 16; ++b) tot += hist[b * GH_STRIDE];
    float ftot = (float)tot;
    for (int b = 0; b < 16; ++b) s[16 + b] = (float)hist[b * GH_STRIDE] / ftot;
    float h1[16];
    for (int r = 0; r < 16; ++r) {
        float a = fc1b[r];
        for (int m = 0; m < 32; ++m) a = fmaf(s[m], fc1W[m * 16 + r], a);
        h1[r] = fmaxf(a, 0.f);
    }
    float h2[8];
    for (int r = 0; r < 8; ++r) {
        float a = fc2b[r];
        for (int m = 0; m < 16; ++m) a = fmaf(h1[m], fc2W[m * 8 + r], a);
        h2[r] = fmaxf(a, 0.f);
    }
    float h3[4];
    for (int r = 0; r < 4; ++r) {
        float a = fc3b[r];
        for (int m = 0; m < 8; ++m) a = fmaf(h2[m], fc3W[m * 4 + r], a);
        h3[r] = fmaxf(a, 0.f);
    }
    float z = scb[0];
    for (int m = 0; m < 4; ++m) z = fmaf(h3[m], scW[m], z);
    float sig = 1.f / (1.f + expf(-z));
    out[0] = sig;
    out[1] = -logf(sig) * avg_v[0];
}

// ---------------------------------------------------------------------------
extern "C" void kernel_launch(void* const* d_in, const int* in_sizes, int n_in,
                              void* d_out, int out_size, void* d_ws, size_t ws_size,
                              hipStream_t stream) {
    (void)n_in; (void)out_size;
    const int* ei1 = (const int*)d_in[0];
    const int* ei2 = (const int*)d_in[1];
    const float* feat1 = (const float*)d_in[2];
    const float* feat2 = (const float*)d_in[3];
    const float* avg_v = (const float*)d_in[4];
    const float* W1 = (const float*)d_in[5];
    const float* b1 = (const float*)d_in[6];
    const float* W2 = (const float*)d_in[7];
    const float* b2 = (const float*)d_in[8];
    const float* W3 = (const float*)d_in[9];
    const float* b3 = (const float*)d_in[10];
    const float* Wa = (const float*)d_in[11];
    const float* Wt = (const float*)d_in[12];
    const float* V = (const float*)d_in[13];
    const float* bt = (const float*)d_in[14];
    const float* fc1W = (const float*)d_in[15];
    const float* fc1b = (const float*)d_in[16];
    const float* fc2W = (const float*)d_in[17];
    const float* fc2b = (const float*)d_in[18];
    const float* fc3W = (const float*)d_in[19];
    const float* fc3b = (const float*)d_in[20];
    const float* scW = (const float*)d_in[21];
    const float* scb = (const float*)d_in[22];

    const int E = in_sizes[0] / 2;
    const int N = in_sizes[2] / 64;

    // ---- workspace layout (lay out for ng graphs batched) ----
    auto layout = [&](int ng, bool commit,
                      float** af, unsigned short** afbf, float** gsum, float** p12,
                      unsigned** mm, unsigned** hist, float** ctx, float** dinv,
                      int** cnt, int** offs, int** cursor, int** esrc,
                      float** bufA, float** bufB) -> size_t {
        char* w = (char*)d_ws;
        size_t off = 0;
        auto take = [&](size_t bytes) -> char* {
            char* p = w + off;
            off = (off + bytes + 255) & ~(size_t)255;
            return p;
        };
        char* p;
        p = take((size_t)2 * N * 32 * 4); if (commit) *af = (float*)p;
        p = take((size_t)2 * N * 32 * 2); if (commit) *afbf = (unsigned short*)p;
        p = take(64 * 4);                 if (commit) *gsum = (float*)p;   // zero-group start
        p = take(64 * 4);                 if (commit) *p12 = (float*)p;
        p = take(2 * 4);                  if (commit) *mm = (unsigned*)p;
        p = take(16 * GH_STRIDE * 4);     if (commit) *hist = (unsigned*)p; // zero-group end
        p = take(64 * 4);                 if (commit) *ctx = (float*)p;
        p = take((size_t)ng * N * 4);     if (commit) *dinv = (float*)p;
        p = take((size_t)ng * N * 4);     if (commit) *cnt = (int*)p;
        p = take((size_t)ng * (N + 1) * 4); if (commit) *offs = (int*)p;
        p = take((size_t)ng * N * 4);     if (commit) *cursor = (int*)p;
        p = take((size_t)ng * E * 4);     if (commit) *esrc = (int*)p;
        p = take((size_t)ng * N * 128 * 4); if (commit) *bufA = (float*)p;
        p = take((size_t)ng * N * 128 * 4); if (commit) *bufB = (float*)p;
        return off;
    };

    float *af, *gsum, *p12, *ctx, *dinv, *bufA, *bufB;
    unsigned short* afbf;
    unsigned *mm, *hist;
    int *cnt, *offs, *cursor, *esrc;

    size_t need2 = layout(2, false, &af, &afbf, &gsum, &p12, &mm, &hist, &ctx, &dinv,
                          &cnt, &offs, &cursor, &esrc, &bufA, &bufB);
    int NG = (ws_size >= need2) ? 2 : 1;
    layout(NG, true, &af, &afbf, &gsum, &p12, &mm, &hist, &ctx, &dinv,
           &cnt, &offs, &cursor, &esrc, &bufA, &bufB);

    // zero the accumulator group (gsum..hist contiguous)
    size_t zspan = (char*)(hist + 16 * GH_STRIDE) - (char*)gsum;
    hipMemsetAsync(gsum, 0, zspan, stream);

    int iters = 2 / NG;
    for (int it = 0; it < iters; ++it) {
        const int *srcA, *srcB, *tgtA, *tgtB;
        const float *xA, *xB;
        float* afbase;
        float* gsbase;
        if (NG == 2) {
            srcA = ei1; tgtA = ei1 + E; srcB = ei2; tgtB = ei2 + E;
            xA = feat1; xB = feat2;
            afbase = af; gsbase = gsum;
        } else {
            const int* ei = it ? ei2 : ei1;
            srcA = srcB = ei; tgtA = tgtB = ei + E;
            xA = xB = it ? feat2 : feat1;
            afbase = af + (size_t)it * N * 32;
            gsbase = gsum + it * 32;
        }
        size_t bstride = (size_t)N * 128;

        hipMemsetAsync(cnt, 0, (size_t)NG * N * 4, stream);
        count_tgt<<<dim3((E + 255) / 256, NG), 256, 0, stream>>>(tgtA, tgtB, cnt, N, E);
        scan_offsets<<<NG, 1024, 0, stream>>>(cnt, offs, cursor, dinv, N);
        scatter_src<<<dim3((E + 255) / 256, NG), 256, 0, stream>>>(srcA, srcB, tgtA, tgtB,
                                                                   cursor, esrc, N, E);

        gemm_lds<64, 128><<<dim3(N / 2, NG), 256, 0, stream>>>(xA, xB, W1, bufA, bstride, N);
        agg_csr<128, true, false><<<dim3(N / 2, NG), 256, 0, stream>>>(
            bufA, bufA + bstride, offs, esrc, dinv, b1, bufB, bstride, nullptr, N, E);
        gemm_lds<128, 64><<<dim3(N / 4, NG), 256, 0, stream>>>(bufB, bufB + bstride, W2,
                                                               bufA, bstride, N);
        agg_csr<64, true, false><<<dim3(N / 4, NG), 256, 0, stream>>>(
            bufA, bufA + bstride, offs, esrc, dinv, b2, bufB, bstride, nullptr, N, E);
        gemm_lds<64, 32><<<dim3(N / 8, NG), 256, 0, stream>>>(bufB, bufB + bstride, W3,
                                                              bufA, bstride, N);
        agg_csr<32, false, true><<<dim3(N / 8, NG), 256, 0, stream>>>(
            bufA, bufA + bstride, offs, esrc, dinv, b3, afbase, (size_t)N * 32, gsbase, N, E);
    }

    to_bf16<<<(2 * N * 32 / 8 + 255) / 256, 256, 0, stream>>>(af, afbf, 2 * N * 32 / 8);
    ctx_finalize<<<1, 64, 0, stream>>>(gsum, Wa, ctx, N);
    pool_att<<<dim3(N / 256, 2), 256, 0, stream>>>(af, ctx, p12, N);

    int nb = N / 128;
    sim_mfma<false><<<nb * nb, 256, 0, stream>>>(afbf, afbf + (size_t)N * 32, N, mm, hist);
    sim_mfma<true><<<nb * nb, 256, 0, stream>>>(afbf, afbf + (size_t)N * 32, N, mm, hist);

    ntn_final<<<1, 64, 0, stream>>>(p12, Wt, V, bt, hist, fc1W, fc1b, fc2W, fc2b,
                                    fc3W, fc3b, scW, scb, avg_v, (float*)d_out);
}

// Round 4
// 398.205 us; speedup vs baseline: 5.1002x; 1.2848x over previous
//
#include <hip/hip_runtime.h>
#include <math.h>

// ---------------------------------------------------------------------------
// SimGNN forward on MI355X (gfx950).  f32 GCN pipeline (aggregation commuted
// to the narrow side of each layer), bf16-MFMA similarity histogram with
// register-packed bins and block-level operand reuse.
// ---------------------------------------------------------------------------

#define GH_STRIDE 32   // pad hist bins to separate cachelines
#define GH_REP 8       // replica histograms to spread atomic contention
#define SIM_CHUNK 2    // bx-tiles per block (128 values/thread <= 255 pack max)

using bf16x8 = __attribute__((ext_vector_type(8))) short;
using f32x4  = __attribute__((ext_vector_type(4))) float;

__device__ __forceinline__ unsigned fkey(float f) {
    unsigned u = __float_as_uint(f);
    return (u & 0x80000000u) ? ~u : (u | 0x80000000u);
}
__device__ __forceinline__ float funkey(unsigned k) {
    unsigned u = (k & 0x80000000u) ? (k & 0x7fffffffu) : ~k;
    return __uint_as_float(u);
}
__device__ __forceinline__ unsigned short f2bf(float f) {  // RNE
    unsigned u = __float_as_uint(f);
    unsigned r = ((u >> 16) & 1u) + 0x7FFFu;
    return (unsigned short)((u + r) >> 16);
}

// ---------------- CSR build (batched: blockIdx.y = graph) ----------------
__global__ void count_tgt(const int* __restrict__ t0, const int* __restrict__ t1,
                          int* __restrict__ cnt, int N, int E) {
    int g = blockIdx.y;
    const int* t = g ? t1 : t0;
    int i = blockIdx.x * 256 + threadIdx.x;
    if (i < E) atomicAdd(&cnt[g * N + t[i]], 1);
}

// wave-shfl scan: 3 barriers instead of 20
__global__ __launch_bounds__(1024) void scan_offsets(const int* __restrict__ cnt_,
                                                     int* __restrict__ offs_,
                                                     int* __restrict__ cursor_,
                                                     float* __restrict__ dinv_, int N) {
    int g = blockIdx.x;
    const int* cnt = cnt_ + g * N;
    int* offs = offs_ + g * (N + 1);
    int* cursor = cursor_ + g * N;
    float* dinv = dinv_ + g * N;
    int tid = threadIdx.x, lane = tid & 63, wid = tid >> 6;
    int chunk = (N + 1023) >> 10;
    int base = tid * chunk;
    int s = 0;
    for (int i = 0; i < chunk; ++i) {
        int idx = base + i;
        if (idx < N) s += cnt[idx];
    }
    int v = s;  // inclusive wave scan
#pragma unroll
    for (int d = 1; d < 64; d <<= 1) {
        int u = __shfl_up(v, d);
        if (lane >= d) v += u;
    }
    __shared__ int wtot[16], wbase[16];
    if (lane == 63) wtot[wid] = v;
    __syncthreads();
    if (tid == 0) {
        int r = 0;
        for (int i = 0; i < 16; ++i) { wbase[i] = r; r += wtot[i]; }
        offs[N] = r;
    }
    __syncthreads();
    int run = wbase[wid] + (v - s);  // exclusive prefix for this thread
    for (int i = 0; i < chunk; ++i) {
        int idx = base + i;
        if (idx < N) {
            int c = cnt[idx];
            offs[idx] = run;
            cursor[idx] = run;
            dinv[idx] = 1.0f / sqrtf((float)(c + 1));
            run += c;
        }
    }
}

__global__ void scatter_src(const int* __restrict__ s0, const int* __restrict__ s1,
                            const int* __restrict__ t0, const int* __restrict__ t1,
                            int* __restrict__ cursor, int* __restrict__ esrc, int N, int E) {
    int g = blockIdx.y;
    const int* src = g ? s1 : s0;
    const int* tgt = g ? t1 : t0;
    int i = blockIdx.x * 256 + threadIdx.x;
    if (i < E) {
        int t = tgt[i];
        int pos = atomicAdd(&cursor[g * N + t], 1);
        esrc[g * E + pos] = src[i];
    }
}

// ---------------- GEMM: out[N,FOUT] = x[N,FIN] @ W[FIN,FOUT] (+b, relu) ----------------
template <int FIN, int FOUT, bool BIAS, bool RELU>
__global__ __launch_bounds__(256) void gemm_lds(const float* __restrict__ x0,
                                                const float* __restrict__ x1,
                                                const float* __restrict__ W,
                                                const float* __restrict__ b,
                                                float* __restrict__ out, size_t ostride,
                                                int N) {
    int g = blockIdx.y;
    const float* x = g ? x1 : x0;
    out += (size_t)g * ostride;
    constexpr int RPB = 256 / FOUT;
    __shared__ float Wl[FIN * FOUT];
    for (int t = threadIdx.x; t < FIN * FOUT; t += 256) Wl[t] = W[t];
    __syncthreads();
    int fx = threadIdx.x % FOUT;
    int r = blockIdx.x * RPB + threadIdx.x / FOUT;
    if (r >= N) return;
    const float* xr = x + (size_t)r * FIN;
    float acc = 0.f;
#pragma unroll
    for (int k = 0; k < FIN; ++k) acc = fmaf(xr[k], Wl[k * FOUT + fx], acc);
    if (BIAS) acc += b[fx];
    if (RELU) acc = fmaxf(acc, 0.f);
    out[(size_t)r * FOUT + fx] = acc;
}

// ------------- GCN aggregation: out[t] = relu?(dt*(dt*h[t] + sum ds*h[s]) + b) -------------
// POOL: also column-sum into gsum and mirror output to bf16.
template <int F, bool RELU, bool POOL, bool BIAS>
__global__ __launch_bounds__(256) void agg_csr(const float* __restrict__ h0,
                                               const float* __restrict__ h1,
                                               const int* __restrict__ offs_,
                                               const int* __restrict__ esrc_,
                                               const float* __restrict__ dinv_,
                                               const float* __restrict__ b,
                                               float* __restrict__ out, size_t ostride,
                                               unsigned short* __restrict__ outbf,
                                               size_t obfstride,
                                               float* __restrict__ gsum, int N, int E) {
    int g = blockIdx.y;
    const float* h = g ? h1 : h0;
    const int* offs = offs_ + g * (N + 1);
    const int* esrc = esrc_ + g * E;
    const float* dinv = dinv_ + g * N;
    out += (size_t)g * ostride;
    constexpr int RPB = 256 / F;
    int fx = threadIdx.x % F;
    int t = blockIdx.x * RPB + threadIdx.x / F;
    float v = 0.f;
    if (t < N) {
        float dt = dinv[t];
        float acc = dt * h[(size_t)t * F + fx];  // self-loop / dt
        int e1 = offs[t + 1];
        for (int e = offs[t]; e < e1; ++e) {
            int s = esrc[e];
            acc = fmaf(dinv[s], h[(size_t)s * F + fx], acc);
        }
        v = fmaf(dt, acc, BIAS ? b[fx] : 0.f);
        if (RELU) v = fmaxf(v, 0.f);
        out[(size_t)t * F + fx] = v;
    }
    if (POOL) {
        if (t < N) outbf[(size_t)g * obfstride + (size_t)t * F + fx] = f2bf(v);
        __shared__ float ls[F];
        if (threadIdx.x < F) ls[threadIdx.x] = 0.f;
        __syncthreads();
        atomicAdd(&ls[fx], v);
        __syncthreads();
        if (threadIdx.x < F) atomicAdd(&gsum[g * 32 + threadIdx.x], ls[threadIdx.x]);
    }
}

// ---------------- ctx = tanh(colmean @ Wa), both graphs ----------------
__global__ void ctx_finalize(const float* __restrict__ gsum, const float* __restrict__ Wa,
                             float* __restrict__ ctx, int N) {
    int t = threadIdx.x;
    if (t >= 64) return;
    int g = t >> 5, c = t & 31;
    float invN = 1.0f / (float)N;
    float s = 0.f;
    for (int d = 0; d < 32; ++d) s = fmaf(gsum[g * 32 + d] * invN, Wa[d * 32 + c], s);
    ctx[g * 32 + c] = tanhf(s);
}

// ---------------- attention pool: p = af^T @ sigmoid(af @ ctx) ----------------
__global__ __launch_bounds__(256) void pool_att(const float* __restrict__ af,
                                                const float* __restrict__ ctx,
                                                float* __restrict__ p12, int N) {
    int g = blockIdx.y;
    af += (size_t)g * N * 32;
    float ctxl[32];
#pragma unroll
    for (int f = 0; f < 32; ++f) ctxl[f] = ctx[g * 32 + f];
    int r = blockIdx.x * 256 + threadIdx.x;
    float rowv[32];
    float att = 0.f;
    if (r < N) {
        const float4* row = (const float4*)(af + (size_t)r * 32);
        float dot = 0.f;
#pragma unroll
        for (int q = 0; q < 8; ++q) {
            float4 v = row[q];
            rowv[q * 4 + 0] = v.x; rowv[q * 4 + 1] = v.y;
            rowv[q * 4 + 2] = v.z; rowv[q * 4 + 3] = v.w;
            dot = fmaf(v.x, ctxl[q * 4 + 0], dot);
            dot = fmaf(v.y, ctxl[q * 4 + 1], dot);
            dot = fmaf(v.z, ctxl[q * 4 + 2], dot);
            dot = fmaf(v.w, ctxl[q * 4 + 3], dot);
        }
        att = 1.f / (1.f + expf(-dot));
    } else {
#pragma unroll
        for (int f = 0; f < 32; ++f) rowv[f] = 0.f;
    }
    __shared__ float wsum[4][32];
    int lane = threadIdx.x & 63, wid = threadIdx.x >> 6;
#pragma unroll
    for (int f = 0; f < 32; ++f) {
        float v = att * rowv[f];
#pragma unroll
        for (int off = 1; off < 64; off <<= 1) v += __shfl_xor(v, off);
        if (lane == 0) wsum[wid][f] = v;
    }
    __syncthreads();
    if (threadIdx.x < 32) {
        float s = wsum[0][threadIdx.x] + wsum[1][threadIdx.x] + wsum[2][threadIdx.x] +
                  wsum[3][threadIdx.x];
        atomicAdd(&p12[g * 32 + threadIdx.x], s);
    }
}

// ---------------- similarity passes: bf16 MFMA, block-level A reuse ----------------
// grid = nb x nchunk; block owns 128 A-rows (frags in regs), sweeps SIM_CHUNK
// bx-tiles.  4 waves: wave tile 64x64 = 4x4 MFMA.  Histogram in packed regs.
template <bool HIST>
__global__ __launch_bounds__(256) void sim_mfma(const unsigned short* __restrict__ a1,
                                                const unsigned short* __restrict__ a2,
                                                int N, unsigned* __restrict__ mm,
                                                unsigned* __restrict__ ghist) {
    int nb = N >> 7;
    int nchunk = nb / SIM_CHUNK;
    int by = blockIdx.x / nchunk;
    int ch = blockIdx.x % nchunk;
    int w = threadIdx.x >> 6, lane = threadIdx.x & 63;
    int r16 = lane & 15, kg = (lane >> 4) << 3;

    __shared__ unsigned hs[16];
    if (HIST && threadIdx.x < 16) hs[threadIdx.x] = 0;

    const unsigned short* arow = a1 + ((size_t)(by * 128 + (w >> 1) * 64 + r16)) * 32 + kg;
    bf16x8 afr[4];
#pragma unroll
    for (int m = 0; m < 4; ++m) afr[m] = *(const bf16x8*)(arow + m * 16 * 32);

    float mn = 1e30f, mx = -1e30f;
    unsigned h4_0 = 0, h4_1 = 0, h4_2 = 0, h4_3 = 0;
    float scale = 0.f, nbias = 0.f;
    if (HIST) {
        float mxv = funkey(mm[0]);
        float mnv = funkey(~mm[1]);
        float width = (mxv > mnv) ? (mxv - mnv) : 1.0f;
        scale = 16.0f / width;
        nbias = -mnv * scale;
    }

#pragma unroll
    for (int t = 0; t < SIM_CHUNK; ++t) {
        int bx = ch * SIM_CHUNK + t;
        const unsigned short* brow =
            a2 + ((size_t)(bx * 128 + (w & 1) * 64 + r16)) * 32 + kg;
        bf16x8 bfr[4];
#pragma unroll
        for (int n = 0; n < 4; ++n) bfr[n] = *(const bf16x8*)(brow + n * 16 * 32);
        f32x4 zero = {0.f, 0.f, 0.f, 0.f};
        f32x4 acc[4][4];
#pragma unroll
        for (int m = 0; m < 4; ++m)
#pragma unroll
            for (int n = 0; n < 4; ++n)
                acc[m][n] =
                    __builtin_amdgcn_mfma_f32_16x16x32_bf16(afr[m], bfr[n], zero, 0, 0, 0);
        if (!HIST) {
#pragma unroll
            for (int m = 0; m < 4; ++m)
#pragma unroll
                for (int n = 0; n < 4; ++n)
#pragma unroll
                    for (int e = 0; e < 4; ++e) {
                        float v = acc[m][n][e];
                        mn = fminf(mn, v);
                        mx = fmaxf(mx, v);
                    }
        } else {
#pragma unroll
            for (int m = 0; m < 4; ++m)
#pragma unroll
                for (int n = 0; n < 4; ++n)
#pragma unroll
                    for (int e = 0; e < 4; ++e) {
                        float v = acc[m][n][e];
                        int bin = (int)fmaf(v, scale, nbias);
                        bin = bin < 0 ? 0 : (bin > 15 ? 15 : bin);
                        unsigned wbit = 1u << ((bin & 3) << 3);
                        int hi = bin >> 2;
                        h4_0 += (hi == 0) ? wbit : 0u;
                        h4_1 += (hi == 1) ? wbit : 0u;
                        h4_2 += (hi == 2) ? wbit : 0u;
                        h4_3 += (hi == 3) ? wbit : 0u;
                    }
        }
    }

    if (!HIST) {
#pragma unroll
        for (int off = 1; off < 64; off <<= 1) {
            mn = fminf(mn, __shfl_xor(mn, off));
            mx = fmaxf(mx, __shfl_xor(mx, off));
        }
        __shared__ float wmn[4], wmx[4];
        if (lane == 0) { wmn[w] = mn; wmx[w] = mx; }
        __syncthreads();
        if (threadIdx.x == 0) {
            float bmn = fminf(fminf(wmn[0], wmn[1]), fminf(wmn[2], wmn[3]));
            float bmx = fmaxf(fmaxf(wmx[0], wmx[1]), fmaxf(wmx[2], wmx[3]));
            atomicMax(&mm[0], fkey(bmx));    // max key
            atomicMax(&mm[1], ~fkey(bmn));   // complement-min key (zero-init ok)
        }
    } else {
        // unpack 8-bit fields (<=128 per thread) to 16-bit before any reduce
        unsigned hh[8];
        hh[0] = h4_0 & 0x00FF00FFu; hh[1] = (h4_0 >> 8) & 0x00FF00FFu;
        hh[2] = h4_1 & 0x00FF00FFu; hh[3] = (h4_1 >> 8) & 0x00FF00FFu;
        hh[4] = h4_2 & 0x00FF00FFu; hh[5] = (h4_2 >> 8) & 0x00FF00FFu;
        hh[6] = h4_3 & 0x00FF00FFu; hh[7] = (h4_3 >> 8) & 0x00FF00FFu;
#pragma unroll
        for (int off = 1; off < 64; off <<= 1) {
#pragma unroll
            for (int q = 0; q < 8; ++q) hh[q] += (unsigned)__shfl_xor((int)hh[q], off);
        }
        __syncthreads();  // hs init visible
        if (lane < 16) {  // lane b owns bin b; all lanes hold full sums
            int q = lane >> 2, r = lane & 3;
            unsigned word = hh[2 * q + (r & 1)];
            unsigned val = (r < 2) ? (word & 0xFFFFu) : (word >> 16);
            atomicAdd(&hs[lane], val);
        }
        __syncthreads();
        if (threadIdx.x < 16)
            atomicAdd(&ghist[(((unsigned)blockIdx.x & (GH_REP - 1)) * 16 + threadIdx.x) *
                             GH_STRIDE],
                      hs[threadIdx.x]);
    }
}

// ---------------- NTN + final MLP head (fused) ----------------
__global__ void ntn_final(const float* __restrict__ p12, const float* __restrict__ Wt,
                          const float* __restrict__ V, const float* __restrict__ bt,
                          const unsigned* __restrict__ hist,
                          const float* __restrict__ fc1W, const float* __restrict__ fc1b,
                          const float* __restrict__ fc2W, const float* __restrict__ fc2b,
                          const float* __restrict__ fc3W, const float* __restrict__ fc3b,
                          const float* __restrict__ scW, const float* __restrict__ scb,
                          const float* __restrict__ avg_v, float* __restrict__ out) {
    __shared__ float sc[16];
    const float* p1 = p12;
    const float* p2 = p12 + 32;
    int k = threadIdx.x;
    if (k < 16) {
        float s = 0.f;
        for (int d = 0; d < 32; ++d) {
            float a = p1[d];
            for (int e = 0; e < 32; ++e) s = fmaf(a * p2[e], Wt[(d * 32 + e) * 16 + k], s);
        }
        float bl = 0.f;
        for (int m = 0; m < 32; ++m) bl = fmaf(V[k * 64 + m], p1[m], bl);
        for (int m = 0; m < 32; ++m) bl = fmaf(V[k * 64 + 32 + m], p2[m], bl);
        sc[k] = fmaxf(s + bl + bt[k], 0.f);
    }
    __syncthreads();
    if (k != 0) return;
    float s[32];
    for (int i = 0; i < 16; ++i) s[i] = sc[i];
    unsigned hb[16];
    unsigned tot = 0;
    for (int b = 0; b < 16; ++b) {
        unsigned h = 0;
        for (int r = 0; r < GH_REP; ++r) h += hist[(r * 16 + b) * GH_STRIDE];
        hb[b] = h;
        tot += h;
    }
    float ftot = (float)tot;
    for (int b = 0; b < 16; ++b) s[16 + b] = (float)hb[b] / ftot;
    float h1[16];
    for (int r = 0; r < 16; ++r) {
        float a = fc1b[r];
        for (int m = 0; m < 32; ++m) a = fmaf(s[m], fc1W[m * 16 + r], a);
        h1[r] = fmaxf(a, 0.f);
    }
    float h2[8];
    for (int r = 0; r < 8; ++r) {
        float a = fc2b[r];
        for (int m = 0; m < 16; ++m) a = fmaf(h1[m], fc2W[m * 8 + r], a);
        h2[r] = fmaxf(a, 0.f);
    }
    float h3[4];
    for (int r = 0; r < 4; ++r) {
        float a = fc3b[r];
        for (int m = 0; m < 8; ++m) a = fmaf(h2[m], fc3W[m * 4 + r], a);
        h3[r] = fmaxf(a, 0.f);
    }
    float z = scb[0];
    for (int m = 0; m < 4; ++m) z = fmaf(h3[m], scW[m], z);
    float sig = 1.f / (1.f + expf(-z));
    out[0] = sig;
    out[1] = -logf(sig) * avg_v[0];
}

// ---------------------------------------------------------------------------
extern "C" void kernel_launch(void* const* d_in, const int* in_sizes, int n_in,
                              void* d_out, int out_size, void* d_ws, size_t ws_size,
                              hipStream_t stream) {
    (void)n_in; (void)out_size;
    const int* ei1 = (const int*)d_in[0];
    const int* ei2 = (const int*)d_in[1];
    const float* feat1 = (const float*)d_in[2];
    const float* feat2 = (const float*)d_in[3];
    const float* avg_v = (const float*)d_in[4];
    const float* W1 = (const float*)d_in[5];
    const float* b1 = (const float*)d_in[6];
    const float* W2 = (const float*)d_in[7];
    const float* b2 = (const float*)d_in[8];
    const float* W3 = (const float*)d_in[9];
    const float* b3 = (const float*)d_in[10];
    const float* Wa = (const float*)d_in[11];
    const float* Wt = (const float*)d_in[12];
    const float* V = (const float*)d_in[13];
    const float* bt = (const float*)d_in[14];
    const float* fc1W = (const float*)d_in[15];
    const float* fc1b = (const float*)d_in[16];
    const float* fc2W = (const float*)d_in[17];
    const float* fc2b = (const float*)d_in[18];
    const float* fc3W = (const float*)d_in[19];
    const float* fc3b = (const float*)d_in[20];
    const float* scW = (const float*)d_in[21];
    const float* scb = (const float*)d_in[22];

    const int E = in_sizes[0] / 2;
    const int N = in_sizes[2] / 64;

    // ---- workspace layout (lay out for ng graphs batched) ----
    auto layout = [&](int ng, bool commit,
                      float** af, unsigned short** afbf, float** gsum, float** p12,
                      unsigned** mm, unsigned** hist, float** ctx, float** dinv,
                      int** cnt, int** offs, int** cursor, int** esrc,
                      float** bufA, float** bufB) -> size_t {
        char* w = (char*)d_ws;
        size_t off = 0;
        auto take = [&](size_t bytes) -> char* {
            char* p = w + off;
            off = (off + bytes + 255) & ~(size_t)255;
            return p;
        };
        char* p;
        p = take((size_t)2 * N * 32 * 4); if (commit) *af = (float*)p;
        p = take((size_t)2 * N * 32 * 2); if (commit) *afbf = (unsigned short*)p;
        p = take(64 * 4);                 if (commit) *gsum = (float*)p;   // zero-group start
        p = take(64 * 4);                 if (commit) *p12 = (float*)p;
        p = take(2 * 4);                  if (commit) *mm = (unsigned*)p;
        p = take((size_t)GH_REP * 16 * GH_STRIDE * 4); if (commit) *hist = (unsigned*)p; // zero-group end
        p = take(64 * 4);                 if (commit) *ctx = (float*)p;
        p = take((size_t)ng * N * 4);     if (commit) *dinv = (float*)p;
        p = take((size_t)ng * N * 4);     if (commit) *cnt = (int*)p;
        p = take((size_t)ng * (N + 1) * 4); if (commit) *offs = (int*)p;
        p = take((size_t)ng * N * 4);     if (commit) *cursor = (int*)p;
        p = take((size_t)ng * E * 4);     if (commit) *esrc = (int*)p;
        p = take((size_t)ng * N * 128 * 4); if (commit) *bufA = (float*)p;
        p = take((size_t)ng * N * 128 * 4); if (commit) *bufB = (float*)p;
        return off;
    };

    float *af, *gsum, *p12, *ctx, *dinv, *bufA, *bufB;
    unsigned short* afbf;
    unsigned *mm, *hist;
    int *cnt, *offs, *cursor, *esrc;

    size_t need2 = layout(2, false, &af, &afbf, &gsum, &p12, &mm, &hist, &ctx, &dinv,
                          &cnt, &offs, &cursor, &esrc, &bufA, &bufB);
    int NG = (ws_size >= need2) ? 2 : 1;
    layout(NG, true, &af, &afbf, &gsum, &p12, &mm, &hist, &ctx, &dinv,
           &cnt, &offs, &cursor, &esrc, &bufA, &bufB);

    // zero the accumulator group (gsum..hist contiguous)
    size_t zspan = (char*)(hist + GH_REP * 16 * GH_STRIDE) - (char*)gsum;
    hipMemsetAsync(gsum, 0, zspan, stream);

    int iters = 2 / NG;
    for (int it = 0; it < iters; ++it) {
        const int *srcA, *srcB, *tgtA, *tgtB;
        const float *xA, *xB;
        float* afbase;
        unsigned short* afbfbase;
        float* gsbase;
        if (NG == 2) {
            srcA = ei1; tgtA = ei1 + E; srcB = ei2; tgtB = ei2 + E;
            xA = feat1; xB = feat2;
            afbase = af; afbfbase = afbf; gsbase = gsum;
        } else {
            const int* ei = it ? ei2 : ei1;
            srcA = srcB = ei; tgtA = tgtB = ei + E;
            xA = xB = it ? feat2 : feat1;
            afbase = af + (size_t)it * N * 32;
            afbfbase = afbf + (size_t)it * N * 32;
            gsbase = gsum + it * 32;
        }
        size_t bstride = (size_t)N * 128;

        hipMemsetAsync(cnt, 0, (size_t)NG * N * 4, stream);
        count_tgt<<<dim3((E + 255) / 256, NG), 256, 0, stream>>>(tgtA, tgtB, cnt, N, E);
        scan_offsets<<<NG, 1024, 0, stream>>>(cnt, offs, cursor, dinv, N);
        scatter_src<<<dim3((E + 255) / 256, NG), 256, 0, stream>>>(srcA, srcB, tgtA, tgtB,
                                                                   cursor, esrc, N, E);

        // layer 1 (commuted): aggregate raw x (64 cols), then GEMM +b1, relu
        agg_csr<64, false, false, false><<<dim3(N / 4, NG), 256, 0, stream>>>(
            xA, xB, offs, esrc, dinv, nullptr, bufB, bstride, nullptr, 0, nullptr, N, E);
        gemm_lds<64, 128, true, true><<<dim3(N / 2, NG), 256, 0, stream>>>(
            bufB, bufB + bstride, W1, b1, bufA, bstride, N);
        // layer 2: GEMM 128->64, then aggregate +b2, relu
        gemm_lds<128, 64, false, false><<<dim3(N / 4, NG), 256, 0, stream>>>(
            bufA, bufA + bstride, W2, nullptr, bufB, bstride, N);
        agg_csr<64, true, false, true><<<dim3(N / 4, NG), 256, 0, stream>>>(
            bufB, bufB + bstride, offs, esrc, dinv, b2, bufA, bstride, nullptr, 0, nullptr,
            N, E);
        // layer 3: GEMM 64->32, then aggregate +b3 (no relu) + pool + bf16
        gemm_lds<64, 32, false, false><<<dim3(N / 8, NG), 256, 0, stream>>>(
            bufA, bufA + bstride, W3, nullptr, bufB, bstride, N);
        agg_csr<32, false, true, true><<<dim3(N / 8, NG), 256, 0, stream>>>(
            bufB, bufB + bstride, offs, esrc, dinv, b3, afbase, (size_t)N * 32, afbfbase,
            (size_t)N * 32, gsbase, N, E);
    }

    ctx_finalize<<<1, 64, 0, stream>>>(gsum, Wa, ctx, N);
    pool_att<<<dim3(N / 256, 2), 256, 0, stream>>>(af, ctx, p12, N);

    int nb = N / 128;
    int nchunk = nb / SIM_CHUNK;
    sim_mfma<false><<<nb * nchunk, 256, 0, stream>>>(afbf, afbf + (size_t)N * 32, N, mm,
                                                     hist);
    sim_mfma<true><<<nb * nchunk, 256, 0, stream>>>(afbf, afbf + (size_t)N * 32, N, mm,
                                                    hist);

    ntn_final<<<1, 64, 0, stream>>>(p12, Wt, V, bt, hist, fc1W, fc1b, fc2W, fc2b,
                                    fc3W, fc3b, scW, scb, avg_v, (float*)d_out);
}

// Round 5
// 353.685 us; speedup vs baseline: 5.7422x; 1.1259x over previous
//
#include <hip/hip_runtime.h>
#include <math.h>

// ---------------------------------------------------------------------------
// SimGNN forward on MI355X (gfx950).  f32 GCN pipeline (aggregation commuted
// to the narrow side of each layer), bf16-MFMA similarity histogram.
// R5: all contended global atomics replaced by per-block stores + tiny
// reductions (R4 profile: sim passes were atomic-drain-bound at ~25ns/block).
// ---------------------------------------------------------------------------

#define SIM_CHUNK 2    // bx-tiles per block (128 values/thread <= 255 pack max)
#define GS_PAD 16      // floats of padding per gsum counter (64B lines)
#define GS_REP 8       // gsum replicas to spread residual atomic contention

using bf16x8 = __attribute__((ext_vector_type(8))) short;
using f32x4  = __attribute__((ext_vector_type(4))) float;

__device__ __forceinline__ unsigned short f2bf(float f) {  // RNE
    unsigned u = __float_as_uint(f);
    unsigned r = ((u >> 16) & 1u) + 0x7FFFu;
    return (unsigned short)((u + r) >> 16);
}

// ---------------- CSR build (batched: blockIdx.y = graph) ----------------
__global__ void count_tgt(const int* __restrict__ t0, const int* __restrict__ t1,
                          int* __restrict__ cnt, int N, int E) {
    int g = blockIdx.y;
    const int* t = g ? t1 : t0;
    int i = blockIdx.x * 256 + threadIdx.x;
    if (i < E) atomicAdd(&cnt[g * N + t[i]], 1);
}

// wave-shfl scan: 3 barriers
__global__ __launch_bounds__(1024) void scan_offsets(const int* __restrict__ cnt_,
                                                     int* __restrict__ offs_,
                                                     int* __restrict__ cursor_,
                                                     float* __restrict__ dinv_, int N) {
    int g = blockIdx.x;
    const int* cnt = cnt_ + g * N;
    int* offs = offs_ + g * (N + 1);
    int* cursor = cursor_ + g * N;
    float* dinv = dinv_ + g * N;
    int tid = threadIdx.x, lane = tid & 63, wid = tid >> 6;
    int chunk = (N + 1023) >> 10;
    int base = tid * chunk;
    int s = 0;
    for (int i = 0; i < chunk; ++i) {
        int idx = base + i;
        if (idx < N) s += cnt[idx];
    }
    int v = s;  // inclusive wave scan
#pragma unroll
    for (int d = 1; d < 64; d <<= 1) {
        int u = __shfl_up(v, d);
        if (lane >= d) v += u;
    }
    __shared__ int wtot[16], wbase[16];
    if (lane == 63) wtot[wid] = v;
    __syncthreads();
    if (tid == 0) {
        int r = 0;
        for (int i = 0; i < 16; ++i) { wbase[i] = r; r += wtot[i]; }
        offs[N] = r;
    }
    __syncthreads();
    int run = wbase[wid] + (v - s);  // exclusive prefix for this thread
    for (int i = 0; i < chunk; ++i) {
        int idx = base + i;
        if (idx < N) {
            int c = cnt[idx];
            offs[idx] = run;
            cursor[idx] = run;
            dinv[idx] = 1.0f / sqrtf((float)(c + 1));
            run += c;
        }
    }
}

__global__ void scatter_src(const int* __restrict__ s0, const int* __restrict__ s1,
                            const int* __restrict__ t0, const int* __restrict__ t1,
                            int* __restrict__ cursor, int* __restrict__ esrc, int N, int E) {
    int g = blockIdx.y;
    const int* src = g ? s1 : s0;
    const int* tgt = g ? t1 : t0;
    int i = blockIdx.x * 256 + threadIdx.x;
    if (i < E) {
        int t = tgt[i];
        int pos = atomicAdd(&cursor[g * N + t], 1);
        esrc[g * E + pos] = src[i];
    }
}

// ---------------- GEMM: out[N,FOUT] = x[N,FIN] @ W[FIN,FOUT] (+b, relu) ----------------
template <int FIN, int FOUT, bool BIAS, bool RELU>
__global__ __launch_bounds__(256) void gemm_lds(const float* __restrict__ x0,
                                                const float* __restrict__ x1,
                                                const float* __restrict__ W,
                                                const float* __restrict__ b,
                                                float* __restrict__ out, size_t ostride,
                                                int N) {
    int g = blockIdx.y;
    const float* x = g ? x1 : x0;
    out += (size_t)g * ostride;
    constexpr int RPB = 256 / FOUT;
    __shared__ float Wl[FIN * FOUT];
    for (int t = threadIdx.x; t < FIN * FOUT; t += 256) Wl[t] = W[t];
    __syncthreads();
    int fx = threadIdx.x % FOUT;
    int r = blockIdx.x * RPB + threadIdx.x / FOUT;
    if (r >= N) return;
    const float* xr = x + (size_t)r * FIN;
    float acc = 0.f;
#pragma unroll
    for (int k = 0; k < FIN; ++k) acc = fmaf(xr[k], Wl[k * FOUT + fx], acc);
    if (BIAS) acc += b[fx];
    if (RELU) acc = fmaxf(acc, 0.f);
    out[(size_t)r * FOUT + fx] = acc;
}

// ------------- GCN aggregation: out[t] = relu?(dt*(dt*h[t] + sum ds*h[s]) + b) -------------
// POOL: column-sum into replicated/padded gsum and mirror output to bf16.
template <int F, bool RELU, bool POOL, bool BIAS>
__global__ __launch_bounds__(256) void agg_csr(const float* __restrict__ h0,
                                               const float* __restrict__ h1,
                                               const int* __restrict__ offs_,
                                               const int* __restrict__ esrc_,
                                               const float* __restrict__ dinv_,
                                               const float* __restrict__ b,
                                               float* __restrict__ out, size_t ostride,
                                               unsigned short* __restrict__ outbf,
                                               size_t obfstride,
                                               float* __restrict__ gsum, int N, int E) {
    int g = blockIdx.y;
    const float* h = g ? h1 : h0;
    const int* offs = offs_ + g * (N + 1);
    const int* esrc = esrc_ + g * E;
    const float* dinv = dinv_ + g * N;
    out += (size_t)g * ostride;
    constexpr int RPB = 256 / F;
    int fx = threadIdx.x % F;
    int t = blockIdx.x * RPB + threadIdx.x / F;
    float v = 0.f;
    if (t < N) {
        float dt = dinv[t];
        float acc = dt * h[(size_t)t * F + fx];  // self-loop / dt
        int e1 = offs[t + 1];
        for (int e = offs[t]; e < e1; ++e) {
            int s = esrc[e];
            acc = fmaf(dinv[s], h[(size_t)s * F + fx], acc);
        }
        v = fmaf(dt, acc, BIAS ? b[fx] : 0.f);
        if (RELU) v = fmaxf(v, 0.f);
        out[(size_t)t * F + fx] = v;
    }
    if (POOL) {
        if (t < N) outbf[(size_t)g * obfstride + (size_t)t * F + fx] = f2bf(v);
        __shared__ float ls[F];
        if (threadIdx.x < F) ls[threadIdx.x] = 0.f;
        __syncthreads();
        atomicAdd(&ls[fx], v);
        __syncthreads();
        if (threadIdx.x < 32) {
            int rep = blockIdx.x & (GS_REP - 1);
            atomicAdd(&gsum[((g * GS_REP + rep) * 32 + threadIdx.x) * GS_PAD],
                      ls[threadIdx.x]);
        }
    }
}

// ---------------- ctx = tanh(colmean @ Wa), both graphs ----------------
__global__ void ctx_finalize(const float* __restrict__ gsum, const float* __restrict__ Wa,
                             float* __restrict__ ctx, int N) {
    __shared__ float cm[2][32];
    int t = threadIdx.x;
    if (t < 64) {
        int g = t >> 5, f = t & 31;
        float s = 0.f;
#pragma unroll
        for (int r = 0; r < GS_REP; ++r)
            s += gsum[((g * GS_REP + r) * 32 + f) * GS_PAD];
        cm[g][f] = s / (float)N;
    }
    __syncthreads();
    if (t < 64) {
        int g = t >> 5, c = t & 31;
        float s = 0.f;
        for (int d = 0; d < 32; ++d) s = fmaf(cm[g][d], Wa[d * 32 + c], s);
        ctx[g * 32 + c] = tanhf(s);
    }
}

// ---------------- attention pool: p = af^T @ sigmoid(af @ ctx) ----------------
__global__ __launch_bounds__(256) void pool_att(const float* __restrict__ af,
                                                const float* __restrict__ ctx,
                                                float* __restrict__ p12, int N) {
    int g = blockIdx.y;
    af += (size_t)g * N * 32;
    float ctxl[32];
#pragma unroll
    for (int f = 0; f < 32; ++f) ctxl[f] = ctx[g * 32 + f];
    int r = blockIdx.x * 256 + threadIdx.x;
    float rowv[32];
    float att = 0.f;
    if (r < N) {
        const float4* row = (const float4*)(af + (size_t)r * 32);
        float dot = 0.f;
#pragma unroll
        for (int q = 0; q < 8; ++q) {
            float4 v = row[q];
            rowv[q * 4 + 0] = v.x; rowv[q * 4 + 1] = v.y;
            rowv[q * 4 + 2] = v.z; rowv[q * 4 + 3] = v.w;
            dot = fmaf(v.x, ctxl[q * 4 + 0], dot);
            dot = fmaf(v.y, ctxl[q * 4 + 1], dot);
            dot = fmaf(v.z, ctxl[q * 4 + 2], dot);
            dot = fmaf(v.w, ctxl[q * 4 + 3], dot);
        }
        att = 1.f / (1.f + expf(-dot));
    } else {
#pragma unroll
        for (int f = 0; f < 32; ++f) rowv[f] = 0.f;
    }
    __shared__ float wsum[4][32];
    int lane = threadIdx.x & 63, wid = threadIdx.x >> 6;
#pragma unroll
    for (int f = 0; f < 32; ++f) {
        float v = att * rowv[f];
#pragma unroll
        for (int off = 1; off < 64; off <<= 1) v += __shfl_xor(v, off);
        if (lane == 0) wsum[wid][f] = v;
    }
    __syncthreads();
    if (threadIdx.x < 32) {
        float s = wsum[0][threadIdx.x] + wsum[1][threadIdx.x] + wsum[2][threadIdx.x] +
                  wsum[3][threadIdx.x];
        atomicAdd(&p12[g * 32 + threadIdx.x], s);
    }
}

// ---------------- similarity passes: bf16 MFMA, block-level A reuse ----------------
// grid = nb x nchunk; block owns 128 A-rows (frags in regs), sweeps SIM_CHUNK
// bx-tiles.  4 waves: wave tile 64x64 = 4x4 MFMA.  No contended atomics:
// per-block results stored plain, reduced by tiny follow-up kernels.
template <bool HIST>
__global__ __launch_bounds__(256) void sim_mfma(const unsigned short* __restrict__ a1,
                                                const unsigned short* __restrict__ a2,
                                                int N, const float* __restrict__ mmf,
                                                float2* __restrict__ pbmm,
                                                unsigned* __restrict__ pbhist) {
    int nb = N >> 7;
    int nchunk = nb / SIM_CHUNK;
    int by = blockIdx.x / nchunk;
    int ch = blockIdx.x % nchunk;
    int w = threadIdx.x >> 6, lane = threadIdx.x & 63;
    int r16 = lane & 15, kg = (lane >> 4) << 3;

    __shared__ unsigned hs[16];
    if (HIST && threadIdx.x < 16) hs[threadIdx.x] = 0;

    const unsigned short* arow = a1 + ((size_t)(by * 128 + (w >> 1) * 64 + r16)) * 32 + kg;
    bf16x8 afr[4];
#pragma unroll
    for (int m = 0; m < 4; ++m) afr[m] = *(const bf16x8*)(arow + m * 16 * 32);

    float mn = 1e30f, mx = -1e30f;
    unsigned h4_0 = 0, h4_1 = 0, h4_2 = 0, h4_3 = 0;
    float scale = 0.f, nbias = 0.f;
    if (HIST) {
        float mnv = mmf[0], mxv = mmf[1];
        float width = (mxv > mnv) ? (mxv - mnv) : 1.0f;
        scale = 16.0f / width;
        nbias = -mnv * scale;
    }

#pragma unroll
    for (int t = 0; t < SIM_CHUNK; ++t) {
        int bx = ch * SIM_CHUNK + t;
        const unsigned short* brow =
            a2 + ((size_t)(bx * 128 + (w & 1) * 64 + r16)) * 32 + kg;
        bf16x8 bfr[4];
#pragma unroll
        for (int n = 0; n < 4; ++n) bfr[n] = *(const bf16x8*)(brow + n * 16 * 32);
        f32x4 zero = {0.f, 0.f, 0.f, 0.f};
        f32x4 acc[4][4];
#pragma unroll
        for (int m = 0; m < 4; ++m)
#pragma unroll
            for (int n = 0; n < 4; ++n)
                acc[m][n] =
                    __builtin_amdgcn_mfma_f32_16x16x32_bf16(afr[m], bfr[n], zero, 0, 0, 0);
        if (!HIST) {
#pragma unroll
            for (int m = 0; m < 4; ++m)
#pragma unroll
                for (int n = 0; n < 4; ++n)
#pragma unroll
                    for (int e = 0; e < 4; ++e) {
                        float v = acc[m][n][e];
                        mn = fminf(mn, v);
                        mx = fmaxf(mx, v);
                    }
        } else {
#pragma unroll
            for (int m = 0; m < 4; ++m)
#pragma unroll
                for (int n = 0; n < 4; ++n)
#pragma unroll
                    for (int e = 0; e < 4; ++e) {
                        float v = acc[m][n][e];
                        int bin = (int)fmaf(v, scale, nbias);
                        bin = bin < 0 ? 0 : (bin > 15 ? 15 : bin);
                        unsigned wbit = 1u << ((bin & 3) << 3);
                        int hi = bin >> 2;
                        h4_0 += (hi == 0) ? wbit : 0u;
                        h4_1 += (hi == 1) ? wbit : 0u;
                        h4_2 += (hi == 2) ? wbit : 0u;
                        h4_3 += (hi == 3) ? wbit : 0u;
                    }
        }
    }

    if (!HIST) {
#pragma unroll
        for (int off = 1; off < 64; off <<= 1) {
            mn = fminf(mn, __shfl_xor(mn, off));
            mx = fmaxf(mx, __shfl_xor(mx, off));
        }
        __shared__ float wmn[4], wmx[4];
        if (lane == 0) { wmn[w] = mn; wmx[w] = mx; }
        __syncthreads();
        if (threadIdx.x == 0) {
            float bmn = fminf(fminf(wmn[0], wmn[1]), fminf(wmn[2], wmn[3]));
            float bmx = fmaxf(fmaxf(wmx[0], wmx[1]), fmaxf(wmx[2], wmx[3]));
            pbmm[blockIdx.x] = make_float2(bmn, bmx);
        }
    } else {
        // unpack 8-bit fields (<=128 per thread) to 16-bit before any reduce
        unsigned hh[8];
        hh[0] = h4_0 & 0x00FF00FFu; hh[1] = (h4_0 >> 8) & 0x00FF00FFu;
        hh[2] = h4_1 & 0x00FF00FFu; hh[3] = (h4_1 >> 8) & 0x00FF00FFu;
        hh[4] = h4_2 & 0x00FF00FFu; hh[5] = (h4_2 >> 8) & 0x00FF00FFu;
        hh[6] = h4_3 & 0x00FF00FFu; hh[7] = (h4_3 >> 8) & 0x00FF00FFu;
#pragma unroll
        for (int off = 1; off < 64; off <<= 1) {
#pragma unroll
            for (int q = 0; q < 8; ++q) hh[q] += (unsigned)__shfl_xor((int)hh[q], off);
        }
        __syncthreads();  // hs init visible
        if (lane < 16) {  // lane b owns bin b (LDS merge across 4 waves)
            int q = lane >> 2, r = lane & 3;
            unsigned word = hh[2 * q + (r & 1)];
            unsigned val = (r < 2) ? (word & 0xFFFFu) : (word >> 16);
            atomicAdd(&hs[lane], val);
        }
        __syncthreads();
        if (threadIdx.x < 16)
            pbhist[(size_t)blockIdx.x * 16 + threadIdx.x] = hs[threadIdx.x];
    }
}

// ---------------- reduce per-block minmax -> mmf[2] = {mn, mx} ----------------
__global__ __launch_bounds__(256) void reduce_mm(const float2* __restrict__ pbmm,
                                                 float* __restrict__ mmf, int nblk) {
    float mn = 1e30f, mx = -1e30f;
    for (int i = threadIdx.x; i < nblk; i += 256) {
        float2 v = pbmm[i];
        mn = fminf(mn, v.x);
        mx = fmaxf(mx, v.y);
    }
#pragma unroll
    for (int off = 1; off < 64; off <<= 1) {
        mn = fminf(mn, __shfl_xor(mn, off));
        mx = fmaxf(mx, __shfl_xor(mx, off));
    }
    __shared__ float wmn[4], wmx[4];
    int lane = threadIdx.x & 63, wid = threadIdx.x >> 6;
    if (lane == 0) { wmn[wid] = mn; wmx[wid] = mx; }
    __syncthreads();
    if (threadIdx.x == 0) {
        mmf[0] = fminf(fminf(wmn[0], wmn[1]), fminf(wmn[2], wmn[3]));
        mmf[1] = fmaxf(fmaxf(wmx[0], wmx[1]), fmaxf(wmx[2], wmx[3]));
    }
}

// ---------------- hist reduce + NTN + final MLP head (fused, 256 thr) ----------------
__global__ __launch_bounds__(256) void ntn_final(
    const float* __restrict__ p12, const float* __restrict__ Wt,
    const float* __restrict__ V, const float* __restrict__ bt,
    const unsigned* __restrict__ pbhist, int nblk,
    const float* __restrict__ fc1W, const float* __restrict__ fc1b,
    const float* __restrict__ fc2W, const float* __restrict__ fc2b,
    const float* __restrict__ fc3W, const float* __restrict__ fc3b,
    const float* __restrict__ scW, const float* __restrict__ scb,
    const float* __restrict__ avg_v, float* __restrict__ out) {
    __shared__ float sc[16];
    __shared__ unsigned hsum[16];
    int t = threadIdx.x;
    if (t < 16) hsum[t] = 0;
    __syncthreads();
    // phase 1: reduce per-block histograms (16 parts x 16 bins, coalesced)
    {
        int bin = t & 15, part = t >> 4;
        int psz = nblk >> 4;  // nblk multiple of 16
        unsigned s = 0;
        for (int j = 0; j < psz; ++j)
            s += pbhist[(size_t)(part * psz + j) * 16 + bin];
        atomicAdd(&hsum[bin], s);
    }
    // phase 2: NTN (threads 0..15), independent of hist
    const float* p1 = p12;
    const float* p2 = p12 + 32;
    if (t < 16) {
        float s = 0.f;
        for (int d = 0; d < 32; ++d) {
            float a = p1[d];
            for (int e = 0; e < 32; ++e) s = fmaf(a * p2[e], Wt[(d * 32 + e) * 16 + t], s);
        }
        float bl = 0.f;
        for (int m = 0; m < 32; ++m) bl = fmaf(V[t * 64 + m], p1[m], bl);
        for (int m = 0; m < 32; ++m) bl = fmaf(V[t * 64 + 32 + m], p2[m], bl);
        sc[t] = fmaxf(s + bl + bt[t], 0.f);
    }
    __syncthreads();
    if (t != 0) return;
    float s[32];
    for (int i = 0; i < 16; ++i) s[i] = sc[i];
    unsigned tot = 0;
    for (int b = 0; b < 16; ++b) tot += hsum[b];
    float ftot = (float)tot;
    for (int b = 0; b < 16; ++b) s[16 + b] = (float)hsum[b] / ftot;
    float h1[16];
    for (int r = 0; r < 16; ++r) {
        float a = fc1b[r];
        for (int m = 0; m < 32; ++m) a = fmaf(s[m], fc1W[m * 16 + r], a);
        h1[r] = fmaxf(a, 0.f);
    }
    float h2[8];
    for (int r = 0; r < 8; ++r) {
        float a = fc2b[r];
        for (int m = 0; m < 16; ++m) a = fmaf(h1[m], fc2W[m * 8 + r], a);
        h2[r] = fmaxf(a, 0.f);
    }
    float h3[4];
    for (int r = 0; r < 4; ++r) {
        float a = fc3b[r];
        for (int m = 0; m < 8; ++m) a = fmaf(h2[m], fc3W[m * 4 + r], a);
        h3[r] = fmaxf(a, 0.f);
    }
    float z = scb[0];
    for (int m = 0; m < 4; ++m) z = fmaf(h3[m], scW[m], z);
    float sig = 1.f / (1.f + expf(-z));
    out[0] = sig;
    out[1] = -logf(sig) * avg_v[0];
}

// ---------------------------------------------------------------------------
extern "C" void kernel_launch(void* const* d_in, const int* in_sizes, int n_in,
                              void* d_out, int out_size, void* d_ws, size_t ws_size,
                              hipStream_t stream) {
    (void)n_in; (void)out_size;
    const int* ei1 = (const int*)d_in[0];
    const int* ei2 = (const int*)d_in[1];
    const float* feat1 = (const float*)d_in[2];
    const float* feat2 = (const float*)d_in[3];
    const float* avg_v = (const float*)d_in[4];
    const float* W1 = (const float*)d_in[5];
    const float* b1 = (const float*)d_in[6];
    const float* W2 = (const float*)d_in[7];
    const float* b2 = (const float*)d_in[8];
    const float* W3 = (const float*)d_in[9];
    const float* b3 = (const float*)d_in[10];
    const float* Wa = (const float*)d_in[11];
    const float* Wt = (const float*)d_in[12];
    const float* V = (const float*)d_in[13];
    const float* bt = (const float*)d_in[14];
    const float* fc1W = (const float*)d_in[15];
    const float* fc1b = (const float*)d_in[16];
    const float* fc2W = (const float*)d_in[17];
    const float* fc2b = (const float*)d_in[18];
    const float* fc3W = (const float*)d_in[19];
    const float* fc3b = (const float*)d_in[20];
    const float* scW = (const float*)d_in[21];
    const float* scb = (const float*)d_in[22];

    const int E = in_sizes[0] / 2;
    const int N = in_sizes[2] / 64;

    const int nb = N / 128;
    const int nchunk = nb / SIM_CHUNK;
    const int NBLK = nb * nchunk;

    // ---- workspace layout (lay out for ng graphs batched) ----
    auto layout = [&](int ng, bool commit,
                      float** af, unsigned short** afbf, float** gsum, float** p12,
                      float** mmf, float2** pbmm, unsigned** pbhist, float** ctx,
                      float** dinv, int** cnt, int** offs, int** cursor, int** esrc,
                      float** bufA, float** bufB) -> size_t {
        char* w = (char*)d_ws;
        size_t off = 0;
        auto take = [&](size_t bytes) -> char* {
            char* p = w + off;
            off = (off + bytes + 255) & ~(size_t)255;
            return p;
        };
        char* p;
        p = take((size_t)2 * N * 32 * 4); if (commit) *af = (float*)p;
        p = take((size_t)2 * N * 32 * 2); if (commit) *afbf = (unsigned short*)p;
        p = take((size_t)2 * GS_REP * 32 * GS_PAD * 4); if (commit) *gsum = (float*)p;  // zero start
        p = take(64 * 4);                 if (commit) *p12 = (float*)p;                 // zero end
        p = take(2 * 4);                  if (commit) *mmf = (float*)p;
        p = take((size_t)NBLK * 8);       if (commit) *pbmm = (float2*)p;
        p = take((size_t)NBLK * 16 * 4);  if (commit) *pbhist = (unsigned*)p;
        p = take(64 * 4);                 if (commit) *ctx = (float*)p;
        p = take((size_t)ng * N * 4);     if (commit) *dinv = (float*)p;
        p = take((size_t)ng * N * 4);     if (commit) *cnt = (int*)p;
        p = take((size_t)ng * (N + 1) * 4); if (commit) *offs = (int*)p;
        p = take((size_t)ng * N * 4);     if (commit) *cursor = (int*)p;
        p = take((size_t)ng * E * 4);     if (commit) *esrc = (int*)p;
        p = take((size_t)ng * N * 128 * 4); if (commit) *bufA = (float*)p;
        p = take((size_t)ng * N * 128 * 4); if (commit) *bufB = (float*)p;
        return off;
    };

    float *af, *gsum, *p12, *mmf, *ctx, *dinv, *bufA, *bufB;
    unsigned short* afbf;
    float2* pbmm;
    unsigned* pbhist;
    int *cnt, *offs, *cursor, *esrc;

    size_t need2 = layout(2, false, &af, &afbf, &gsum, &p12, &mmf, &pbmm, &pbhist, &ctx,
                          &dinv, &cnt, &offs, &cursor, &esrc, &bufA, &bufB);
    int NG = (ws_size >= need2) ? 2 : 1;
    layout(NG, true, &af, &afbf, &gsum, &p12, &mmf, &pbmm, &pbhist, &ctx,
           &dinv, &cnt, &offs, &cursor, &esrc, &bufA, &bufB);

    // zero the accumulator group (gsum..p12 contiguous)
    size_t zspan = (char*)(p12 + 64) - (char*)gsum;
    hipMemsetAsync(gsum, 0, zspan, stream);

    int iters = 2 / NG;
    for (int it = 0; it < iters; ++it) {
        const int *srcA, *srcB, *tgtA, *tgtB;
        const float *xA, *xB;
        float* afbase;
        unsigned short* afbfbase;
        float* gsbase;
        if (NG == 2) {
            srcA = ei1; tgtA = ei1 + E; srcB = ei2; tgtB = ei2 + E;
            xA = feat1; xB = feat2;
            afbase = af; afbfbase = afbf; gsbase = gsum;
        } else {
            const int* ei = it ? ei2 : ei1;
            srcA = srcB = ei; tgtA = tgtB = ei + E;
            xA = xB = it ? feat2 : feat1;
            afbase = af + (size_t)it * N * 32;
            afbfbase = afbf + (size_t)it * N * 32;
            gsbase = gsum + (size_t)it * GS_REP * 32 * GS_PAD;
        }
        size_t bstride = (size_t)N * 128;

        hipMemsetAsync(cnt, 0, (size_t)NG * N * 4, stream);
        count_tgt<<<dim3((E + 255) / 256, NG), 256, 0, stream>>>(tgtA, tgtB, cnt, N, E);
        scan_offsets<<<NG, 1024, 0, stream>>>(cnt, offs, cursor, dinv, N);
        scatter_src<<<dim3((E + 255) / 256, NG), 256, 0, stream>>>(srcA, srcB, tgtA, tgtB,
                                                                   cursor, esrc, N, E);

        // layer 1 (commuted): aggregate raw x (64 cols), then GEMM +b1, relu
        agg_csr<64, false, false, false><<<dim3(N / 4, NG), 256, 0, stream>>>(
            xA, xB, offs, esrc, dinv, nullptr, bufB, bstride, nullptr, 0, nullptr, N, E);
        gemm_lds<64, 128, true, true><<<dim3(N / 2, NG), 256, 0, stream>>>(
            bufB, bufB + bstride, W1, b1, bufA, bstride, N);
        // layer 2: GEMM 128->64, then aggregate +b2, relu
        gemm_lds<128, 64, false, false><<<dim3(N / 4, NG), 256, 0, stream>>>(
            bufA, bufA + bstride, W2, nullptr, bufB, bstride, N);
        agg_csr<64, true, false, true><<<dim3(N / 4, NG), 256, 0, stream>>>(
            bufB, bufB + bstride, offs, esrc, dinv, b2, bufA, bstride, nullptr, 0, nullptr,
            N, E);
        // layer 3: GEMM 64->32, then aggregate +b3 (no relu) + pool + bf16
        gemm_lds<64, 32, false, false><<<dim3(N / 8, NG), 256, 0, stream>>>(
            bufA, bufA + bstride, W3, nullptr, bufB, bstride, N);
        agg_csr<32, false, true, true><<<dim3(N / 8, NG), 256, 0, stream>>>(
            bufB, bufB + bstride, offs, esrc, dinv, b3, afbase, (size_t)N * 32, afbfbase,
            (size_t)N * 32, gsbase, N, E);
    }

    ctx_finalize<<<1, 64, 0, stream>>>(gsum, Wa, ctx, N);
    pool_att<<<dim3(N / 256, 2), 256, 0, stream>>>(af, ctx, p12, N);

    sim_mfma<false><<<NBLK, 256, 0, stream>>>(afbf, afbf + (size_t)N * 32, N, mmf, pbmm,
                                              pbhist);
    reduce_mm<<<1, 256, 0, stream>>>(pbmm, mmf, NBLK);
    sim_mfma<true><<<NBLK, 256, 0, stream>>>(afbf, afbf + (size_t)N * 32, N, mmf, pbmm,
                                             pbhist);

    ntn_final<<<1, 256, 0, stream>>>(p12, Wt, V, bt, pbhist, NBLK, fc1W, fc1b, fc2W, fc2b,
                                     fc3W, fc3b, scW, scb, avg_v, (float*)d_out);
}

// Round 6
// 335.607 us; speedup vs baseline: 6.0515x; 1.0539x over previous
//
#include <hip/hip_runtime.h>
#include <math.h>

// ---------------------------------------------------------------------------
// SimGNN forward on MI355X (gfx950).  R6: parallelized ntn_final (was 50us
// serial-latency-bound), streaming GEMM (W staged once per block), float4
// CSR gathers, fused reduce_mm->sim<true> and ctx_finalize->pool_att.
// ---------------------------------------------------------------------------

#define SIM_CHUNK 2    // bx-tiles per block (128 values/thread <= 255 pack max)
#define GS_PAD 16      // floats of padding per gsum counter (64B lines)
#define GS_REP 8       // gsum replicas to spread residual atomic contention
#define GEMM_GRID 256  // blocks per gemm_stream launch (x-dim)

using bf16x8 = __attribute__((ext_vector_type(8))) short;
using f32x4  = __attribute__((ext_vector_type(4))) float;

__device__ __forceinline__ unsigned short f2bf(float f) {  // RNE
    unsigned u = __float_as_uint(f);
    unsigned r = ((u >> 16) & 1u) + 0x7FFFu;
    return (unsigned short)((u + r) >> 16);
}

// ---------------- CSR build (batched: blockIdx.y = graph) ----------------
__global__ void count_tgt(const int* __restrict__ t0, const int* __restrict__ t1,
                          int* __restrict__ cnt, int N, int E) {
    int g = blockIdx.y;
    const int* t = g ? t1 : t0;
    int i = blockIdx.x * 256 + threadIdx.x;
    if (i < E) atomicAdd(&cnt[g * N + t[i]], 1);
}

__global__ __launch_bounds__(1024) void scan_offsets(const int* __restrict__ cnt_,
                                                     int* __restrict__ offs_,
                                                     int* __restrict__ cursor_,
                                                     float* __restrict__ dinv_, int N) {
    int g = blockIdx.x;
    const int* cnt = cnt_ + g * N;
    int* offs = offs_ + g * (N + 1);
    int* cursor = cursor_ + g * N;
    float* dinv = dinv_ + g * N;
    int tid = threadIdx.x, lane = tid & 63, wid = tid >> 6;
    int chunk = (N + 1023) >> 10;
    int base = tid * chunk;
    int s = 0;
    for (int i = 0; i < chunk; ++i) {
        int idx = base + i;
        if (idx < N) s += cnt[idx];
    }
    int v = s;  // inclusive wave scan
#pragma unroll
    for (int d = 1; d < 64; d <<= 1) {
        int u = __shfl_up(v, d);
        if (lane >= d) v += u;
    }
    __shared__ int wtot[16], wbase[16];
    if (lane == 63) wtot[wid] = v;
    __syncthreads();
    if (tid == 0) {
        int r = 0;
        for (int i = 0; i < 16; ++i) { wbase[i] = r; r += wtot[i]; }
        offs[N] = r;
    }
    __syncthreads();
    int run = wbase[wid] + (v - s);  // exclusive prefix for this thread
    for (int i = 0; i < chunk; ++i) {
        int idx = base + i;
        if (idx < N) {
            int c = cnt[idx];
            offs[idx] = run;
            cursor[idx] = run;
            dinv[idx] = 1.0f / sqrtf((float)(c + 1));
            run += c;
        }
    }
}

__global__ void scatter_src(const int* __restrict__ s0, const int* __restrict__ s1,
                            const int* __restrict__ t0, const int* __restrict__ t1,
                            int* __restrict__ cursor, int* __restrict__ esrc, int N, int E) {
    int g = blockIdx.y;
    const int* src = g ? s1 : s0;
    const int* tgt = g ? t1 : t0;
    int i = blockIdx.x * 256 + threadIdx.x;
    if (i < E) {
        int t = tgt[i];
        int pos = atomicAdd(&cursor[g * N + t], 1);
        esrc[g * E + pos] = src[i];
    }
}

// --------- streaming GEMM: out[N,FOUT] = x[N,FIN] @ W[FIN,FOUT] (+b, relu) ---------
// W staged to LDS once per block; block strides over rows.  Thread owns 4 cols.
template <int FIN, int FOUT, bool BIAS, bool RELU>
__global__ __launch_bounds__(256) void gemm_stream(const float* __restrict__ x0,
                                                   const float* __restrict__ x1,
                                                   const float* __restrict__ W,
                                                   const float* __restrict__ b,
                                                   float* __restrict__ out, size_t ostride,
                                                   int N) {
    int g = blockIdx.y;
    const float* x = g ? x1 : x0;
    out += (size_t)g * ostride;
    constexpr int TPR = FOUT / 4;   // threads per row
    constexpr int RPB = 256 / TPR;  // rows per iteration
    __shared__ float Wl[FIN * FOUT];
    for (int t = threadIdx.x; t < FIN * FOUT / 4; t += 256)
        ((float4*)Wl)[t] = ((const float4*)W)[t];
    __syncthreads();
    int fx = (threadIdx.x % TPR) * 4;
    int rl = threadIdx.x / TPR;
    float4 bias = {0.f, 0.f, 0.f, 0.f};
    if (BIAS) bias = *(const float4*)&b[fx];
    for (int r = blockIdx.x * RPB + rl; r < N; r += GEMM_GRID * RPB) {
        const float* xr = x + (size_t)r * FIN;
        float4 acc = bias;
#pragma unroll
        for (int k0 = 0; k0 < FIN; k0 += 4) {
            float4 xv = *(const float4*)(xr + k0);
            float4 w0 = *(const float4*)&Wl[(k0 + 0) * FOUT + fx];
            float4 w1 = *(const float4*)&Wl[(k0 + 1) * FOUT + fx];
            float4 w2 = *(const float4*)&Wl[(k0 + 2) * FOUT + fx];
            float4 w3 = *(const float4*)&Wl[(k0 + 3) * FOUT + fx];
            acc.x = fmaf(xv.x, w0.x, acc.x); acc.y = fmaf(xv.x, w0.y, acc.y);
            acc.z = fmaf(xv.x, w0.z, acc.z); acc.w = fmaf(xv.x, w0.w, acc.w);
            acc.x = fmaf(xv.y, w1.x, acc.x); acc.y = fmaf(xv.y, w1.y, acc.y);
            acc.z = fmaf(xv.y, w1.z, acc.z); acc.w = fmaf(xv.y, w1.w, acc.w);
            acc.x = fmaf(xv.z, w2.x, acc.x); acc.y = fmaf(xv.z, w2.y, acc.y);
            acc.z = fmaf(xv.z, w2.z, acc.z); acc.w = fmaf(xv.z, w2.w, acc.w);
            acc.x = fmaf(xv.w, w3.x, acc.x); acc.y = fmaf(xv.w, w3.y, acc.y);
            acc.z = fmaf(xv.w, w3.z, acc.z); acc.w = fmaf(xv.w, w3.w, acc.w);
        }
        if (RELU) {
            acc.x = fmaxf(acc.x, 0.f); acc.y = fmaxf(acc.y, 0.f);
            acc.z = fmaxf(acc.z, 0.f); acc.w = fmaxf(acc.w, 0.f);
        }
        *(float4*)&out[(size_t)r * FOUT + fx] = acc;
    }
}

// ------------- GCN aggregation (float4 per thread): -------------
// out[t] = relu?(dt*(dt*h[t] + sum ds*h[s]) + b).  POOL: gsum + bf16 mirror.
template <int F, bool RELU, bool POOL, bool BIAS>
__global__ __launch_bounds__(256) void agg_csr(const float* __restrict__ h0,
                                               const float* __restrict__ h1,
                                               const int* __restrict__ offs_,
                                               const int* __restrict__ esrc_,
                                               const float* __restrict__ dinv_,
                                               const float* __restrict__ b,
                                               float* __restrict__ out, size_t ostride,
                                               unsigned short* __restrict__ outbf,
                                               size_t obfstride,
                                               float* __restrict__ gsum, int N, int E) {
    int g = blockIdx.y;
    const float* h = g ? h1 : h0;
    const int* offs = offs_ + g * (N + 1);
    const int* esrc = esrc_ + g * E;
    const float* dinv = dinv_ + g * N;
    out += (size_t)g * ostride;
    constexpr int TPR = F / 4;
    constexpr int RPB = 256 / TPR;
    int fq = (threadIdx.x % TPR) * 4;
    int t = blockIdx.x * RPB + threadIdx.x / TPR;
    float4 v = {0.f, 0.f, 0.f, 0.f};
    if (t < N) {
        float dt = dinv[t];
        float4 hv = *(const float4*)&h[(size_t)t * F + fq];
        float4 acc;
        acc.x = dt * hv.x; acc.y = dt * hv.y; acc.z = dt * hv.z; acc.w = dt * hv.w;
        int e1 = offs[t + 1];
        for (int e = offs[t]; e < e1; ++e) {
            int s = esrc[e];
            float ds = dinv[s];
            float4 sv = *(const float4*)&h[(size_t)s * F + fq];
            acc.x = fmaf(ds, sv.x, acc.x); acc.y = fmaf(ds, sv.y, acc.y);
            acc.z = fmaf(ds, sv.z, acc.z); acc.w = fmaf(ds, sv.w, acc.w);
        }
        float4 bb = {0.f, 0.f, 0.f, 0.f};
        if (BIAS) bb = *(const float4*)&b[fq];
        v.x = fmaf(dt, acc.x, bb.x); v.y = fmaf(dt, acc.y, bb.y);
        v.z = fmaf(dt, acc.z, bb.z); v.w = fmaf(dt, acc.w, bb.w);
        if (RELU) {
            v.x = fmaxf(v.x, 0.f); v.y = fmaxf(v.y, 0.f);
            v.z = fmaxf(v.z, 0.f); v.w = fmaxf(v.w, 0.f);
        }
        *(float4*)&out[(size_t)t * F + fq] = v;
    }
    if (POOL) {
        if (t < N) {
            unsigned short r4[4] = {f2bf(v.x), f2bf(v.y), f2bf(v.z), f2bf(v.w)};
            *(uint2*)&outbf[(size_t)g * obfstride + (size_t)t * F + fq] = *(uint2*)r4;
        }
        __shared__ float ls[F];
        if (threadIdx.x < F) ls[threadIdx.x] = 0.f;
        __syncthreads();
        atomicAdd(&ls[fq + 0], v.x);
        atomicAdd(&ls[fq + 1], v.y);
        atomicAdd(&ls[fq + 2], v.z);
        atomicAdd(&ls[fq + 3], v.w);
        __syncthreads();
        if (threadIdx.x < 32) {
            int rep = blockIdx.x & (GS_REP - 1);
            atomicAdd(&gsum[((g * GS_REP + rep) * 32 + threadIdx.x) * GS_PAD],
                      ls[threadIdx.x]);
        }
    }
}

// ------- attention pool (ctx computed in-block): p = af^T @ sigmoid(af@ctx) -------
__global__ __launch_bounds__(256) void pool_att(const float* __restrict__ af,
                                                const float* __restrict__ gsum,
                                                const float* __restrict__ Wa,
                                                float* __restrict__ p12, int N) {
    int g = blockIdx.y;
    af += (size_t)g * N * 32;
    __shared__ float cm[32], ctxs[32];
    int tid = threadIdx.x;
    if (tid < 32) {
        float s = 0.f;
#pragma unroll
        for (int r = 0; r < GS_REP; ++r) s += gsum[((g * GS_REP + r) * 32 + tid) * GS_PAD];
        cm[tid] = s / (float)N;
    }
    __syncthreads();
    if (tid < 32) {
        float s = 0.f;
        for (int d = 0; d < 32; ++d) s = fmaf(cm[d], Wa[d * 32 + tid], s);
        ctxs[tid] = tanhf(s);
    }
    __syncthreads();
    float ctxl[32];
#pragma unroll
    for (int f = 0; f < 32; ++f) ctxl[f] = ctxs[f];
    int r = blockIdx.x * 256 + tid;
    float rowv[32];
    float att = 0.f;
    if (r < N) {
        const float4* row = (const float4*)(af + (size_t)r * 32);
        float dot = 0.f;
#pragma unroll
        for (int q = 0; q < 8; ++q) {
            float4 v = row[q];
            rowv[q * 4 + 0] = v.x; rowv[q * 4 + 1] = v.y;
            rowv[q * 4 + 2] = v.z; rowv[q * 4 + 3] = v.w;
            dot = fmaf(v.x, ctxl[q * 4 + 0], dot);
            dot = fmaf(v.y, ctxl[q * 4 + 1], dot);
            dot = fmaf(v.z, ctxl[q * 4 + 2], dot);
            dot = fmaf(v.w, ctxl[q * 4 + 3], dot);
        }
        att = 1.f / (1.f + expf(-dot));
    } else {
#pragma unroll
        for (int f = 0; f < 32; ++f) rowv[f] = 0.f;
    }
    __shared__ float wsum[4][32];
    int lane = tid & 63, wid = tid >> 6;
#pragma unroll
    for (int f = 0; f < 32; ++f) {
        float v = att * rowv[f];
#pragma unroll
        for (int off = 1; off < 64; off <<= 1) v += __shfl_xor(v, off);
        if (lane == 0) wsum[wid][f] = v;
    }
    __syncthreads();
    if (tid < 32) {
        float s = wsum[0][tid] + wsum[1][tid] + wsum[2][tid] + wsum[3][tid];
        atomicAdd(&p12[g * 32 + tid], s);
    }
}

// ---------------- similarity passes: bf16 MFMA, block-level A reuse ----------------
// !HIST: per-block (mn,mx) -> pbmm.  HIST: block pre-reduces pbmm (fused
// reduce_mm), register-packed bins -> per-block pbhist (no contended atomics).
template <bool HIST>
__global__ __launch_bounds__(256) void sim_mfma(const unsigned short* __restrict__ a1,
                                                const unsigned short* __restrict__ a2,
                                                int N, int nblk,
                                                float2* __restrict__ pbmm,
                                                unsigned* __restrict__ pbhist) {
    int nb = N >> 7;
    int nchunk = nb / SIM_CHUNK;
    int by = blockIdx.x / nchunk;
    int ch = blockIdx.x % nchunk;
    int w = threadIdx.x >> 6, lane = threadIdx.x & 63;
    int r16 = lane & 15, kg = (lane >> 4) << 3;

    __shared__ unsigned hs[16];
    __shared__ float mnmx[2];
    if (HIST && threadIdx.x < 16) hs[threadIdx.x] = 0;

    float scale = 0.f, nbias = 0.f;
    if (HIST) {  // fused min/max reduce over per-block results
        float mn2 = 1e30f, mx2 = -1e30f;
        for (int i = threadIdx.x; i < nblk; i += 256) {
            float2 vv = pbmm[i];
            mn2 = fminf(mn2, vv.x);
            mx2 = fmaxf(mx2, vv.y);
        }
#pragma unroll
        for (int off = 1; off < 64; off <<= 1) {
            mn2 = fminf(mn2, __shfl_xor(mn2, off));
            mx2 = fmaxf(mx2, __shfl_xor(mx2, off));
        }
        __shared__ float wmn2[4], wmx2[4];
        if (lane == 0) { wmn2[w] = mn2; wmx2[w] = mx2; }
        __syncthreads();
        if (threadIdx.x == 0) {
            mnmx[0] = fminf(fminf(wmn2[0], wmn2[1]), fminf(wmn2[2], wmn2[3]));
            mnmx[1] = fmaxf(fmaxf(wmx2[0], wmx2[1]), fmaxf(wmx2[2], wmx2[3]));
        }
        __syncthreads();
        float mnv = mnmx[0], mxv = mnmx[1];
        float width = (mxv > mnv) ? (mxv - mnv) : 1.0f;
        scale = 16.0f / width;
        nbias = -mnv * scale;
    }

    const unsigned short* arow = a1 + ((size_t)(by * 128 + (w >> 1) * 64 + r16)) * 32 + kg;
    bf16x8 afr[4];
#pragma unroll
    for (int m = 0; m < 4; ++m) afr[m] = *(const bf16x8*)(arow + m * 16 * 32);

    float mn = 1e30f, mx = -1e30f;
    unsigned h4_0 = 0, h4_1 = 0, h4_2 = 0, h4_3 = 0;

#pragma unroll
    for (int t = 0; t < SIM_CHUNK; ++t) {
        int bx = ch * SIM_CHUNK + t;
        const unsigned short* brow =
            a2 + ((size_t)(bx * 128 + (w & 1) * 64 + r16)) * 32 + kg;
        bf16x8 bfr[4];
#pragma unroll
        for (int n = 0; n < 4; ++n) bfr[n] = *(const bf16x8*)(brow + n * 16 * 32);
        f32x4 zero = {0.f, 0.f, 0.f, 0.f};
        f32x4 acc[4][4];
#pragma unroll
        for (int m = 0; m < 4; ++m)
#pragma unroll
            for (int n = 0; n < 4; ++n)
                acc[m][n] =
                    __builtin_amdgcn_mfma_f32_16x16x32_bf16(afr[m], bfr[n], zero, 0, 0, 0);
        if (!HIST) {
#pragma unroll
            for (int m = 0; m < 4; ++m)
#pragma unroll
                for (int n = 0; n < 4; ++n)
#pragma unroll
                    for (int e = 0; e < 4; ++e) {
                        float v = acc[m][n][e];
                        mn = fminf(mn, v);
                        mx = fmaxf(mx, v);
                    }
        } else {
#pragma unroll
            for (int m = 0; m < 4; ++m)
#pragma unroll
                for (int n = 0; n < 4; ++n)
#pragma unroll
                    for (int e = 0; e < 4; ++e) {
                        float v = acc[m][n][e];
                        int bin = (int)fmaf(v, scale, nbias);
                        bin = bin < 0 ? 0 : (bin > 15 ? 15 : bin);
                        unsigned wbit = 1u << ((bin & 3) << 3);
                        int hi = bin >> 2;
                        h4_0 += (hi == 0) ? wbit : 0u;
                        h4_1 += (hi == 1) ? wbit : 0u;
                        h4_2 += (hi == 2) ? wbit : 0u;
                        h4_3 += (hi == 3) ? wbit : 0u;
                    }
        }
    }

    if (!HIST) {
#pragma unroll
        for (int off = 1; off < 64; off <<= 1) {
            mn = fminf(mn, __shfl_xor(mn, off));
            mx = fmaxf(mx, __shfl_xor(mx, off));
        }
        __shared__ float wmn[4], wmx[4];
        if (lane == 0) { wmn[w] = mn; wmx[w] = mx; }
        __syncthreads();
        if (threadIdx.x == 0) {
            float bmn = fminf(fminf(wmn[0], wmn[1]), fminf(wmn[2], wmn[3]));
            float bmx = fmaxf(fmaxf(wmx[0], wmx[1]), fmaxf(wmx[2], wmx[3]));
            pbmm[blockIdx.x] = make_float2(bmn, bmx);
        }
    } else {
        unsigned hh[8];
        hh[0] = h4_0 & 0x00FF00FFu; hh[1] = (h4_0 >> 8) & 0x00FF00FFu;
        hh[2] = h4_1 & 0x00FF00FFu; hh[3] = (h4_1 >> 8) & 0x00FF00FFu;
        hh[4] = h4_2 & 0x00FF00FFu; hh[5] = (h4_2 >> 8) & 0x00FF00FFu;
        hh[6] = h4_3 & 0x00FF00FFu; hh[7] = (h4_3 >> 8) & 0x00FF00FFu;
#pragma unroll
        for (int off = 1; off < 64; off <<= 1) {
#pragma unroll
            for (int q = 0; q < 8; ++q) hh[q] += (unsigned)__shfl_xor((int)hh[q], off);
        }
        __syncthreads();
        if (lane < 16) {
            int q = lane >> 2, r = lane & 3;
            unsigned word = hh[2 * q + (r & 1)];
            unsigned val = (r < 2) ? (word & 0xFFFFu) : (word >> 16);
            atomicAdd(&hs[lane], val);
        }
        __syncthreads();
        if (threadIdx.x < 16)
            pbhist[(size_t)blockIdx.x * 16 + threadIdx.x] = hs[threadIdx.x];
    }
}

// ------- hist reduce (vectorized) + NTN (parallel) + MLP head, one block -------
__global__ __launch_bounds__(256) void ntn_final(
    const float* __restrict__ p12, const float* __restrict__ Wt,
    const float* __restrict__ V, const float* __restrict__ bt,
    const unsigned* __restrict__ pbhist, int nblk,
    const float* __restrict__ fc1W, const float* __restrict__ fc1b,
    const float* __restrict__ fc2W, const float* __restrict__ fc2b,
    const float* __restrict__ fc3W, const float* __restrict__ fc3b,
    const float* __restrict__ scW, const float* __restrict__ scb,
    const float* __restrict__ avg_v, float* __restrict__ out) {
    __shared__ float p1l[32], p2l[32];
    __shared__ float scp[16][17];
    __shared__ unsigned hs[16];
    __shared__ float sc[16];
    __shared__ float sfeat[32];
    __shared__ float h1s[16];
    int t = threadIdx.x;
    if (t < 16) hs[t] = 0;
    if (t < 32) p1l[t] = p12[t];
    else if (t < 64) p2l[t - 32] = p12[t];
    __syncthreads();
    // --- hist reduce: uint4 strided, quadrant q = t&3 fixed per thread ---
    {
        const uint4* pb = (const uint4*)pbhist;
        int total = nblk * 4;
        uint4 a = {0u, 0u, 0u, 0u};
        for (int i = t; i < total; i += 256) {
            uint4 v = pb[i];
            a.x += v.x; a.y += v.y; a.z += v.z; a.w += v.w;
        }
#pragma unroll
        for (int off = 4; off < 64; off <<= 1) {
            a.x += (unsigned)__shfl_xor((int)a.x, off);
            a.y += (unsigned)__shfl_xor((int)a.y, off);
            a.z += (unsigned)__shfl_xor((int)a.z, off);
            a.w += (unsigned)__shfl_xor((int)a.w, off);
        }
        int lane = t & 63;
        if (lane < 4) {
            atomicAdd(&hs[lane * 4 + 0], a.x);
            atomicAdd(&hs[lane * 4 + 1], a.y);
            atomicAdd(&hs[lane * 4 + 2], a.z);
            atomicAdd(&hs[lane * 4 + 3], a.w);
        }
    }
    // --- NTN partials: k = t&15 (output), dp = t>>4 (d-partition of 2) ---
    {
        int k = t & 15, dp = t >> 4;
        float s = 0.f;
#pragma unroll
        for (int dd = 0; dd < 2; ++dd) {
            int d = dp * 2 + dd;
            float a = p1l[d];
            for (int e = 0; e < 32; ++e)
                s = fmaf(a * p2l[e], Wt[(d * 32 + e) * 16 + k], s);
        }
        scp[dp][k] = s;
    }
    __syncthreads();
    if (t < 16) {
        float s = 0.f;
#pragma unroll
        for (int dp = 0; dp < 16; ++dp) s += scp[dp][t];
        float bl = 0.f;
        for (int m = 0; m < 32; ++m) bl = fmaf(V[t * 64 + m], p1l[m], bl);
        for (int m = 0; m < 32; ++m) bl = fmaf(V[t * 64 + 32 + m], p2l[m], bl);
        sc[t] = fmaxf(s + bl + bt[t], 0.f);
    }
    __syncthreads();
    if (t < 16) sfeat[t] = sc[t];
    if (t == 16) {
        unsigned tot = 0;
        for (int b = 0; b < 16; ++b) tot += hs[b];
        float ftot = (float)tot;
        for (int b = 0; b < 16; ++b) sfeat[16 + b] = (float)hs[b] / ftot;
    }
    __syncthreads();
    if (t < 16) {  // fc1 in parallel
        float a = fc1b[t];
        for (int m = 0; m < 32; ++m) a = fmaf(sfeat[m], fc1W[m * 16 + t], a);
        h1s[t] = fmaxf(a, 0.f);
    }
    __syncthreads();
    if (t != 0) return;
    float h2[8];
    for (int r = 0; r < 8; ++r) {
        float a = fc2b[r];
        for (int m = 0; m < 16; ++m) a = fmaf(h1s[m], fc2W[m * 8 + r], a);
        h2[r] = fmaxf(a, 0.f);
    }
    float h3[4];
    for (int r = 0; r < 4; ++r) {
        float a = fc3b[r];
        for (int m = 0; m < 8; ++m) a = fmaf(h2[m], fc3W[m * 4 + r], a);
        h3[r] = fmaxf(a, 0.f);
    }
    float z = scb[0];
    for (int m = 0; m < 4; ++m) z = fmaf(h3[m], scW[m], z);
    float sig = 1.f / (1.f + expf(-z));
    out[0] = sig;
    out[1] = -logf(sig) * avg_v[0];
}

// ---------------------------------------------------------------------------
extern "C" void kernel_launch(void* const* d_in, const int* in_sizes, int n_in,
                              void* d_out, int out_size, void* d_ws, size_t ws_size,
                              hipStream_t stream) {
    (void)n_in; (void)out_size;
    const int* ei1 = (const int*)d_in[0];
    const int* ei2 = (const int*)d_in[1];
    const float* feat1 = (const float*)d_in[2];
    const float* feat2 = (const float*)d_in[3];
    const float* avg_v = (const float*)d_in[4];
    const float* W1 = (const float*)d_in[5];
    const float* b1 = (const float*)d_in[6];
    const float* W2 = (const float*)d_in[7];
    const float* b2 = (const float*)d_in[8];
    const float* W3 = (const float*)d_in[9];
    const float* b3 = (const float*)d_in[10];
    const float* Wa = (const float*)d_in[11];
    const float* Wt = (const float*)d_in[12];
    const float* V = (const float*)d_in[13];
    const float* bt = (const float*)d_in[14];
    const float* fc1W = (const float*)d_in[15];
    const float* fc1b = (const float*)d_in[16];
    const float* fc2W = (const float*)d_in[17];
    const float* fc2b = (const float*)d_in[18];
    const float* fc3W = (const float*)d_in[19];
    const float* fc3b = (const float*)d_in[20];
    const float* scW = (const float*)d_in[21];
    const float* scb = (const float*)d_in[22];

    const int E = in_sizes[0] / 2;
    const int N = in_sizes[2] / 64;

    const int nb = N / 128;
    const int nchunk = nb / SIM_CHUNK;
    const int NBLK = nb * nchunk;

    // ---- workspace layout (lay out for ng graphs batched) ----
    auto layout = [&](int ng, bool commit,
                      float** af, unsigned short** afbf, float** gsum, float** p12,
                      float2** pbmm, unsigned** pbhist,
                      float** dinv, int** cnt, int** offs, int** cursor, int** esrc,
                      float** bufA, float** bufB) -> size_t {
        char* w = (char*)d_ws;
        size_t off = 0;
        auto take = [&](size_t bytes) -> char* {
            char* p = w + off;
            off = (off + bytes + 255) & ~(size_t)255;
            return p;
        };
        char* p;
        p = take((size_t)2 * N * 32 * 4); if (commit) *af = (float*)p;
        p = take((size_t)2 * N * 32 * 2); if (commit) *afbf = (unsigned short*)p;
        p = take((size_t)2 * GS_REP * 32 * GS_PAD * 4); if (commit) *gsum = (float*)p;  // zero start
        p = take(64 * 4);                 if (commit) *p12 = (float*)p;                 // zero end
        p = take((size_t)NBLK * 8);       if (commit) *pbmm = (float2*)p;
        p = take((size_t)NBLK * 16 * 4);  if (commit) *pbhist = (unsigned*)p;
        p = take((size_t)ng * N * 4);     if (commit) *dinv = (float*)p;
        p = take((size_t)ng * N * 4);     if (commit) *cnt = (int*)p;
        p = take((size_t)ng * (N + 1) * 4); if (commit) *offs = (int*)p;
        p = take((size_t)ng * N * 4);     if (commit) *cursor = (int*)p;
        p = take((size_t)ng * E * 4);     if (commit) *esrc = (int*)p;
        p = take((size_t)ng * N * 128 * 4); if (commit) *bufA = (float*)p;
        p = take((size_t)ng * N * 128 * 4); if (commit) *bufB = (float*)p;
        return off;
    };

    float *af, *gsum, *p12, *dinv, *bufA, *bufB;
    unsigned short* afbf;
    float2* pbmm;
    unsigned* pbhist;
    int *cnt, *offs, *cursor, *esrc;

    size_t need2 = layout(2, false, &af, &afbf, &gsum, &p12, &pbmm, &pbhist,
                          &dinv, &cnt, &offs, &cursor, &esrc, &bufA, &bufB);
    int NG = (ws_size >= need2) ? 2 : 1;
    layout(NG, true, &af, &afbf, &gsum, &p12, &pbmm, &pbhist,
           &dinv, &cnt, &offs, &cursor, &esrc, &bufA, &bufB);

    // zero the accumulator group (gsum..p12 contiguous)
    size_t zspan = (char*)(p12 + 64) - (char*)gsum;
    hipMemsetAsync(gsum, 0, zspan, stream);

    int iters = 2 / NG;
    for (int it = 0; it < iters; ++it) {
        const int *srcA, *srcB, *tgtA, *tgtB;
        const float *xA, *xB;
        float* afbase;
        unsigned short* afbfbase;
        float* gsbase;
        if (NG == 2) {
            srcA = ei1; tgtA = ei1 + E; srcB = ei2; tgtB = ei2 + E;
            xA = feat1; xB = feat2;
            afbase = af; afbfbase = afbf; gsbase = gsum;
        } else {
            const int* ei = it ? ei2 : ei1;
            srcA = srcB = ei; tgtA = tgtB = ei + E;
            xA = xB = it ? feat2 : feat1;
            afbase = af + (size_t)it * N * 32;
            afbfbase = afbf + (size_t)it * N * 32;
            gsbase = gsum + (size_t)it * GS_REP * 32 * GS_PAD;
        }
        size_t bstride = (size_t)N * 128;

        hipMemsetAsync(cnt, 0, (size_t)NG * N * 4, stream);
        count_tgt<<<dim3((E + 255) / 256, NG), 256, 0, stream>>>(tgtA, tgtB, cnt, N, E);
        scan_offsets<<<NG, 1024, 0, stream>>>(cnt, offs, cursor, dinv, N);
        scatter_src<<<dim3((E + 255) / 256, NG), 256, 0, stream>>>(srcA, srcB, tgtA, tgtB,
                                                                   cursor, esrc, N, E);

        // layer 1 (commuted): aggregate raw x (64 cols), then GEMM +b1, relu
        agg_csr<64, false, false, false><<<dim3(N / 16, NG), 256, 0, stream>>>(
            xA, xB, offs, esrc, dinv, nullptr, bufB, bstride, nullptr, 0, nullptr, N, E);
        gemm_stream<64, 128, true, true><<<dim3(GEMM_GRID, NG), 256, 0, stream>>>(
            bufB, bufB + bstride, W1, b1, bufA, bstride, N);
        // layer 2: GEMM 128->64, then aggregate +b2, relu
        gemm_stream<128, 64, false, false><<<dim3(GEMM_GRID, NG), 256, 0, stream>>>(
            bufA, bufA + bstride, W2, nullptr, bufB, bstride, N);
        agg_csr<64, true, false, true><<<dim3(N / 16, NG), 256, 0, stream>>>(
            bufB, bufB + bstride, offs, esrc, dinv, b2, bufA, bstride, nullptr, 0, nullptr,
            N, E);
        // layer 3: GEMM 64->32, then aggregate +b3 (no relu) + pool + bf16
        gemm_stream<64, 32, false, false><<<dim3(GEMM_GRID, NG), 256, 0, stream>>>(
            bufA, bufA + bstride, W3, nullptr, bufB, bstride, N);
        agg_csr<32, false, true, true><<<dim3(N / 32, NG), 256, 0, stream>>>(
            bufB, bufB + bstride, offs, esrc, dinv, b3, afbase, (size_t)N * 32, afbfbase,
            (size_t)N * 32, gsbase, N, E);
    }

    pool_att<<<dim3(N / 256, 2), 256, 0, stream>>>(af, gsum, Wa, p12, N);

    sim_mfma<false><<<NBLK, 256, 0, stream>>>(afbf, afbf + (size_t)N * 32, N, NBLK, pbmm,
                                              pbhist);
    sim_mfma<true><<<NBLK, 256, 0, stream>>>(afbf, afbf + (size_t)N * 32, N, NBLK, pbmm,
                                             pbhist);

    ntn_final<<<1, 256, 0, stream>>>(p12, Wt, V, bt, pbhist, NBLK, fc1W, fc1b, fc2W, fc2b,
                                     fc3W, fc3b, scW, scb, avg_v, (float*)d_out);
}

// Round 7
// 259.410 us; speedup vs baseline: 7.8290x; 1.2937x over previous
//
#include <hip/hip_runtime.h>
#include <math.h>

// ---------------------------------------------------------------------------
// SimGNN forward on MI355X (gfx950).  R7: proper 64-row tiled f32 GEMM
// (R6's gemm_stream was occupancy-starved at 256 VGPR / 10% occ / 68us;
// this one is 16x16 threads, 4xTN thread tile, K-chunked LDS, 3-6 blocks/CU).
// ---------------------------------------------------------------------------

#define SIM_CHUNK 2    // bx-tiles per block (128 values/thread <= 255 pack max)
#define GS_PAD 16      // floats of padding per gsum counter (64B lines)
#define GS_REP 8       // gsum replicas to spread residual atomic contention

using bf16x8 = __attribute__((ext_vector_type(8))) short;
using f32x4  = __attribute__((ext_vector_type(4))) float;

__device__ __forceinline__ unsigned short f2bf(float f) {  // RNE
    unsigned u = __float_as_uint(f);
    unsigned r = ((u >> 16) & 1u) + 0x7FFFu;
    return (unsigned short)((u + r) >> 16);
}

// ---------------- CSR build (batched: blockIdx.y = graph) ----------------
__global__ void count_tgt(const int* __restrict__ t0, const int* __restrict__ t1,
                          int* __restrict__ cnt, int N, int E) {
    int g = blockIdx.y;
    const int* t = g ? t1 : t0;
    int i = blockIdx.x * 256 + threadIdx.x;
    if (i < E) atomicAdd(&cnt[g * N + t[i]], 1);
}

__global__ __launch_bounds__(1024) void scan_offsets(const int* __restrict__ cnt_,
                                                     int* __restrict__ offs_,
                                                     int* __restrict__ cursor_,
                                                     float* __restrict__ dinv_, int N) {
    int g = blockIdx.x;
    const int* cnt = cnt_ + g * N;
    int* offs = offs_ + g * (N + 1);
    int* cursor = cursor_ + g * N;
    float* dinv = dinv_ + g * N;
    int tid = threadIdx.x, lane = tid & 63, wid = tid >> 6;
    int chunk = (N + 1023) >> 10;
    int base = tid * chunk;
    int s = 0;
    for (int i = 0; i < chunk; ++i) {
        int idx = base + i;
        if (idx < N) s += cnt[idx];
    }
    int v = s;  // inclusive wave scan
#pragma unroll
    for (int d = 1; d < 64; d <<= 1) {
        int u = __shfl_up(v, d);
        if (lane >= d) v += u;
    }
    __shared__ int wtot[16], wbase[16];
    if (lane == 63) wtot[wid] = v;
    __syncthreads();
    if (tid == 0) {
        int r = 0;
        for (int i = 0; i < 16; ++i) { wbase[i] = r; r += wtot[i]; }
        offs[N] = r;
    }
    __syncthreads();
    int run = wbase[wid] + (v - s);  // exclusive prefix for this thread
    for (int i = 0; i < chunk; ++i) {
        int idx = base + i;
        if (idx < N) {
            int c = cnt[idx];
            offs[idx] = run;
            cursor[idx] = run;
            dinv[idx] = 1.0f / sqrtf((float)(c + 1));
            run += c;
        }
    }
}

__global__ void scatter_src(const int* __restrict__ s0, const int* __restrict__ s1,
                            const int* __restrict__ t0, const int* __restrict__ t1,
                            int* __restrict__ cursor, int* __restrict__ esrc, int N, int E) {
    int g = blockIdx.y;
    const int* src = g ? s1 : s0;
    const int* tgt = g ? t1 : t0;
    int i = blockIdx.x * 256 + threadIdx.x;
    if (i < E) {
        int t = tgt[i];
        int pos = atomicAdd(&cursor[g * N + t], 1);
        esrc[g * E + pos] = src[i];
    }
}

// --------- tiled GEMM: out[N,FOUT] = x[N,FIN] @ W[FIN,FOUT] (+b, relu) ---------
// 64-row tile, 16x16 threads, thread tile 4 x (FOUT/16), K chunked at 64.
// LDS: XL 17KB (+2 pad: conflict-free a-reads) + W-chunk <= 32KB.
template <int FIN, int FOUT, bool BIAS, bool RELU>
__global__ __launch_bounds__(256, 2) void tiled_gemm(const float* __restrict__ x0,
                                                     const float* __restrict__ x1,
                                                     const float* __restrict__ W,
                                                     const float* __restrict__ b,
                                                     float* __restrict__ out,
                                                     size_t ostride, int N) {
    constexpr int KT = 64;
    constexpr int TN = FOUT / 16;
    int g = blockIdx.y;
    const float* x = g ? x1 : x0;
    out += (size_t)g * ostride;
    __shared__ float XL[64][KT + 2];
    __shared__ float WL[KT * FOUT];
    int t = threadIdx.x;
    int tc = t & 15, tr = t >> 4;
    int rb = blockIdx.x * 64;

    float acc[4][TN];
#pragma unroll
    for (int i = 0; i < 4; ++i)
#pragma unroll
        for (int j = 0; j < TN; ++j)
            acc[i][j] = BIAS ? b[tc * TN + j] : 0.f;

    for (int k0 = 0; k0 < FIN; k0 += KT) {
        if (k0) __syncthreads();
        // stage W chunk (KT rows x FOUT, contiguous)
        constexpr int W4 = KT * FOUT / 4;
        const float4* Wsrc = (const float4*)(W + (size_t)k0 * FOUT);
#pragma unroll
        for (int i = t; i < W4; i += 256) ((float4*)WL)[i] = Wsrc[i];
        // stage X tile (64 rows x KT), float2 granularity
#pragma unroll
        for (int idx = t; idx < 64 * KT / 2; idx += 256) {
            int r = idx >> 5;          // KT/2 = 32 float2 per row
            int c2 = idx & 31;
            float2 v = *(const float2*)&x[(size_t)(rb + r) * FIN + k0 + c2 * 2];
            *(float2*)&XL[r][c2 * 2] = v;
        }
        __syncthreads();
#pragma unroll 4
        for (int k = 0; k < KT; ++k) {
            float a[4], bv[TN];
#pragma unroll
            for (int i = 0; i < 4; ++i) a[i] = XL[tr * 4 + i][k];
#pragma unroll
            for (int j = 0; j < TN; ++j) bv[j] = WL[k * FOUT + tc * TN + j];
#pragma unroll
            for (int i = 0; i < 4; ++i)
#pragma unroll
                for (int j = 0; j < TN; ++j) acc[i][j] = fmaf(a[i], bv[j], acc[i][j]);
        }
    }

#pragma unroll
    for (int i = 0; i < 4; ++i) {
        int row = rb + tr * 4 + i;
        float* orow = &out[(size_t)row * FOUT + tc * TN];
#pragma unroll
        for (int j = 0; j < TN; ++j) {
            float v = acc[i][j];
            if (RELU) v = fmaxf(v, 0.f);
            acc[i][j] = v;
        }
        if (TN == 8) {
            *(float4*)&orow[0] = make_float4(acc[i][0], acc[i][1], acc[i][2], acc[i][3]);
            *(float4*)&orow[4] = make_float4(acc[i][4], acc[i][5], acc[i][6], acc[i][7]);
        } else if (TN == 4) {
            *(float4*)&orow[0] = make_float4(acc[i][0], acc[i][1], acc[i][2], acc[i][3]);
        } else {
            *(float2*)&orow[0] = make_float2(acc[i][0], acc[i][1]);
        }
    }
}

// ------------- GCN aggregation (float4 per thread): -------------
// out[t] = relu?(dt*(dt*h[t] + sum ds*h[s]) + b).  POOL: gsum + bf16 mirror.
template <int F, bool RELU, bool POOL, bool BIAS>
__global__ __launch_bounds__(256) void agg_csr(const float* __restrict__ h0,
                                               const float* __restrict__ h1,
                                               const int* __restrict__ offs_,
                                               const int* __restrict__ esrc_,
                                               const float* __restrict__ dinv_,
                                               const float* __restrict__ b,
                                               float* __restrict__ out, size_t ostride,
                                               unsigned short* __restrict__ outbf,
                                               size_t obfstride,
                                               float* __restrict__ gsum, int N, int E) {
    int g = blockIdx.y;
    const float* h = g ? h1 : h0;
    const int* offs = offs_ + g * (N + 1);
    const int* esrc = esrc_ + g * E;
    const float* dinv = dinv_ + g * N;
    out += (size_t)g * ostride;
    constexpr int TPR = F / 4;
    constexpr int RPB = 256 / TPR;
    int fq = (threadIdx.x % TPR) * 4;
    int t = blockIdx.x * RPB + threadIdx.x / TPR;
    float4 v = {0.f, 0.f, 0.f, 0.f};
    if (t < N) {
        float dt = dinv[t];
        float4 hv = *(const float4*)&h[(size_t)t * F + fq];
        float4 acc;
        acc.x = dt * hv.x; acc.y = dt * hv.y; acc.z = dt * hv.z; acc.w = dt * hv.w;
        int e1 = offs[t + 1];
        for (int e = offs[t]; e < e1; ++e) {
            int s = esrc[e];
            float ds = dinv[s];
            float4 sv = *(const float4*)&h[(size_t)s * F + fq];
            acc.x = fmaf(ds, sv.x, acc.x); acc.y = fmaf(ds, sv.y, acc.y);
            acc.z = fmaf(ds, sv.z, acc.z); acc.w = fmaf(ds, sv.w, acc.w);
        }
        float4 bb = {0.f, 0.f, 0.f, 0.f};
        if (BIAS) bb = *(const float4*)&b[fq];
        v.x = fmaf(dt, acc.x, bb.x); v.y = fmaf(dt, acc.y, bb.y);
        v.z = fmaf(dt, acc.z, bb.z); v.w = fmaf(dt, acc.w, bb.w);
        if (RELU) {
            v.x = fmaxf(v.x, 0.f); v.y = fmaxf(v.y, 0.f);
            v.z = fmaxf(v.z, 0.f); v.w = fmaxf(v.w, 0.f);
        }
        *(float4*)&out[(size_t)t * F + fq] = v;
    }
    if (POOL) {
        if (t < N) {
            unsigned short r4[4] = {f2bf(v.x), f2bf(v.y), f2bf(v.z), f2bf(v.w)};
            *(uint2*)&outbf[(size_t)g * obfstride + (size_t)t * F + fq] = *(uint2*)r4;
        }
        __shared__ float ls[F];
        if (threadIdx.x < F) ls[threadIdx.x] = 0.f;
        __syncthreads();
        atomicAdd(&ls[fq + 0], v.x);
        atomicAdd(&ls[fq + 1], v.y);
        atomicAdd(&ls[fq + 2], v.z);
        atomicAdd(&ls[fq + 3], v.w);
        __syncthreads();
        if (threadIdx.x < 32) {
            int rep = blockIdx.x & (GS_REP - 1);
            atomicAdd(&gsum[((g * GS_REP + rep) * 32 + threadIdx.x) * GS_PAD],
                      ls[threadIdx.x]);
        }
    }
}

// ------- attention pool (ctx computed in-block): p = af^T @ sigmoid(af@ctx) -------
__global__ __launch_bounds__(256) void pool_att(const float* __restrict__ af,
                                                const float* __restrict__ gsum,
                                                const float* __restrict__ Wa,
                                                float* __restrict__ p12, int N) {
    int g = blockIdx.y;
    af += (size_t)g * N * 32;
    __shared__ float cm[32], ctxs[32];
    int tid = threadIdx.x;
    if (tid < 32) {
        float s = 0.f;
#pragma unroll
        for (int r = 0; r < GS_REP; ++r) s += gsum[((g * GS_REP + r) * 32 + tid) * GS_PAD];
        cm[tid] = s / (float)N;
    }
    __syncthreads();
    if (tid < 32) {
        float s = 0.f;
        for (int d = 0; d < 32; ++d) s = fmaf(cm[d], Wa[d * 32 + tid], s);
        ctxs[tid] = tanhf(s);
    }
    __syncthreads();
    float ctxl[32];
#pragma unroll
    for (int f = 0; f < 32; ++f) ctxl[f] = ctxs[f];
    int r = blockIdx.x * 256 + tid;
    float rowv[32];
    float att = 0.f;
    if (r < N) {
        const float4* row = (const float4*)(af + (size_t)r * 32);
        float dot = 0.f;
#pragma unroll
        for (int q = 0; q < 8; ++q) {
            float4 v = row[q];
            rowv[q * 4 + 0] = v.x; rowv[q * 4 + 1] = v.y;
            rowv[q * 4 + 2] = v.z; rowv[q * 4 + 3] = v.w;
            dot = fmaf(v.x, ctxl[q * 4 + 0], dot);
            dot = fmaf(v.y, ctxl[q * 4 + 1], dot);
            dot = fmaf(v.z, ctxl[q * 4 + 2], dot);
            dot = fmaf(v.w, ctxl[q * 4 + 3], dot);
        }
        att = 1.f / (1.f + expf(-dot));
    } else {
#pragma unroll
        for (int f = 0; f < 32; ++f) rowv[f] = 0.f;
    }
    __shared__ float wsum[4][32];
    int lane = tid & 63, wid = tid >> 6;
#pragma unroll
    for (int f = 0; f < 32; ++f) {
        float v = att * rowv[f];
#pragma unroll
        for (int off = 1; off < 64; off <<= 1) v += __shfl_xor(v, off);
        if (lane == 0) wsum[wid][f] = v;
    }
    __syncthreads();
    if (tid < 32) {
        float s = wsum[0][tid] + wsum[1][tid] + wsum[2][tid] + wsum[3][tid];
        atomicAdd(&p12[g * 32 + tid], s);
    }
}

// ---------------- similarity passes: bf16 MFMA, block-level A reuse ----------------
template <bool HIST>
__global__ __launch_bounds__(256) void sim_mfma(const unsigned short* __restrict__ a1,
                                                const unsigned short* __restrict__ a2,
                                                int N, int nblk,
                                                float2* __restrict__ pbmm,
                                                unsigned* __restrict__ pbhist) {
    int nb = N >> 7;
    int nchunk = nb / SIM_CHUNK;
    int by = blockIdx.x / nchunk;
    int ch = blockIdx.x % nchunk;
    int w = threadIdx.x >> 6, lane = threadIdx.x & 63;
    int r16 = lane & 15, kg = (lane >> 4) << 3;

    __shared__ unsigned hs[16];
    __shared__ float mnmx[2];
    if (HIST && threadIdx.x < 16) hs[threadIdx.x] = 0;

    float scale = 0.f, nbias = 0.f;
    if (HIST) {  // fused min/max reduce over per-block results
        float mn2 = 1e30f, mx2 = -1e30f;
        for (int i = threadIdx.x; i < nblk; i += 256) {
            float2 vv = pbmm[i];
            mn2 = fminf(mn2, vv.x);
            mx2 = fmaxf(mx2, vv.y);
        }
#pragma unroll
        for (int off = 1; off < 64; off <<= 1) {
            mn2 = fminf(mn2, __shfl_xor(mn2, off));
            mx2 = fmaxf(mx2, __shfl_xor(mx2, off));
        }
        __shared__ float wmn2[4], wmx2[4];
        if (lane == 0) { wmn2[w] = mn2; wmx2[w] = mx2; }
        __syncthreads();
        if (threadIdx.x == 0) {
            mnmx[0] = fminf(fminf(wmn2[0], wmn2[1]), fminf(wmn2[2], wmn2[3]));
            mnmx[1] = fmaxf(fmaxf(wmx2[0], wmx2[1]), fmaxf(wmx2[2], wmx2[3]));
        }
        __syncthreads();
        float mnv = mnmx[0], mxv = mnmx[1];
        float width = (mxv > mnv) ? (mxv - mnv) : 1.0f;
        scale = 16.0f / width;
        nbias = -mnv * scale;
    }

    const unsigned short* arow = a1 + ((size_t)(by * 128 + (w >> 1) * 64 + r16)) * 32 + kg;
    bf16x8 afr[4];
#pragma unroll
    for (int m = 0; m < 4; ++m) afr[m] = *(const bf16x8*)(arow + m * 16 * 32);

    float mn = 1e30f, mx = -1e30f;
    unsigned h4_0 = 0, h4_1 = 0, h4_2 = 0, h4_3 = 0;

#pragma unroll
    for (int t = 0; t < SIM_CHUNK; ++t) {
        int bx = ch * SIM_CHUNK + t;
        const unsigned short* brow =
            a2 + ((size_t)(bx * 128 + (w & 1) * 64 + r16)) * 32 + kg;
        bf16x8 bfr[4];
#pragma unroll
        for (int n = 0; n < 4; ++n) bfr[n] = *(const bf16x8*)(brow + n * 16 * 32);
        f32x4 zero = {0.f, 0.f, 0.f, 0.f};
        f32x4 acc[4][4];
#pragma unroll
        for (int m = 0; m < 4; ++m)
#pragma unroll
            for (int n = 0; n < 4; ++n)
                acc[m][n] =
                    __builtin_amdgcn_mfma_f32_16x16x32_bf16(afr[m], bfr[n], zero, 0, 0, 0);
        if (!HIST) {
#pragma unroll
            for (int m = 0; m < 4; ++m)
#pragma unroll
                for (int n = 0; n < 4; ++n)
#pragma unroll
                    for (int e = 0; e < 4; ++e) {
                        float v = acc[m][n][e];
                        mn = fminf(mn, v);
                        mx = fmaxf(mx, v);
                    }
        } else {
#pragma unroll
            for (int m = 0; m < 4; ++m)
#pragma unroll
                for (int n = 0; n < 4; ++n)
#pragma unroll
                    for (int e = 0; e < 4; ++e) {
                        float v = acc[m][n][e];
                        int bin = (int)fmaf(v, scale, nbias);
                        bin = bin < 0 ? 0 : (bin > 15 ? 15 : bin);
                        unsigned wbit = 1u << ((bin & 3) << 3);
                        int hi = bin >> 2;
                        h4_0 += (hi == 0) ? wbit : 0u;
                        h4_1 += (hi == 1) ? wbit : 0u;
                        h4_2 += (hi == 2) ? wbit : 0u;
                        h4_3 += (hi == 3) ? wbit : 0u;
                    }
        }
    }

    if (!HIST) {
#pragma unroll
        for (int off = 1; off < 64; off <<= 1) {
            mn = fminf(mn, __shfl_xor(mn, off));
            mx = fmaxf(mx, __shfl_xor(mx, off));
        }
        __shared__ float wmn[4], wmx[4];
        if (lane == 0) { wmn[w] = mn; wmx[w] = mx; }
        __syncthreads();
        if (threadIdx.x == 0) {
            float bmn = fminf(fminf(wmn[0], wmn[1]), fminf(wmn[2], wmn[3]));
            float bmx = fmaxf(fmaxf(wmx[0], wmx[1]), fmaxf(wmx[2], wmx[3]));
            pbmm[blockIdx.x] = make_float2(bmn, bmx);
        }
    } else {
        unsigned hh[8];
        hh[0] = h4_0 & 0x00FF00FFu; hh[1] = (h4_0 >> 8) & 0x00FF00FFu;
        hh[2] = h4_1 & 0x00FF00FFu; hh[3] = (h4_1 >> 8) & 0x00FF00FFu;
        hh[4] = h4_2 & 0x00FF00FFu; hh[5] = (h4_2 >> 8) & 0x00FF00FFu;
        hh[6] = h4_3 & 0x00FF00FFu; hh[7] = (h4_3 >> 8) & 0x00FF00FFu;
#pragma unroll
        for (int off = 1; off < 64; off <<= 1) {
#pragma unroll
            for (int q = 0; q < 8; ++q) hh[q] += (unsigned)__shfl_xor((int)hh[q], off);
        }
        __syncthreads();
        if (lane < 16) {
            int q = lane >> 2, r = lane & 3;
            unsigned word = hh[2 * q + (r & 1)];
            unsigned val = (r < 2) ? (word & 0xFFFFu) : (word >> 16);
            atomicAdd(&hs[lane], val);
        }
        __syncthreads();
        if (threadIdx.x < 16)
            pbhist[(size_t)blockIdx.x * 16 + threadIdx.x] = hs[threadIdx.x];
    }
}

// ------- hist reduce (vectorized) + NTN (parallel) + MLP head, one block -------
__global__ __launch_bounds__(256) void ntn_final(
    const float* __restrict__ p12, const float* __restrict__ Wt,
    const float* __restrict__ V, const float* __restrict__ bt,
    const unsigned* __restrict__ pbhist, int nblk,
    const float* __restrict__ fc1W, const float* __restrict__ fc1b,
    const float* __restrict__ fc2W, const float* __restrict__ fc2b,
    const float* __restrict__ fc3W, const float* __restrict__ fc3b,
    const float* __restrict__ scW, const float* __restrict__ scb,
    const float* __restrict__ avg_v, float* __restrict__ out) {
    __shared__ float p1l[32], p2l[32];
    __shared__ float scp[16][17];
    __shared__ unsigned hs[16];
    __shared__ float sc[16];
    __shared__ float sfeat[32];
    __shared__ float h1s[16];
    int t = threadIdx.x;
    if (t < 16) hs[t] = 0;
    if (t < 32) p1l[t] = p12[t];
    else if (t < 64) p2l[t - 32] = p12[t];
    __syncthreads();
    {
        const uint4* pb = (const uint4*)pbhist;
        int total = nblk * 4;
        uint4 a = {0u, 0u, 0u, 0u};
        for (int i = t; i < total; i += 256) {
            uint4 v = pb[i];
            a.x += v.x; a.y += v.y; a.z += v.z; a.w += v.w;
        }
#pragma unroll
        for (int off = 4; off < 64; off <<= 1) {
            a.x += (unsigned)__shfl_xor((int)a.x, off);
            a.y += (unsigned)__shfl_xor((int)a.y, off);
            a.z += (unsigned)__shfl_xor((int)a.z, off);
            a.w += (unsigned)__shfl_xor((int)a.w, off);
        }
        int lane = t & 63;
        if (lane < 4) {
            atomicAdd(&hs[lane * 4 + 0], a.x);
            atomicAdd(&hs[lane * 4 + 1], a.y);
            atomicAdd(&hs[lane * 4 + 2], a.z);
            atomicAdd(&hs[lane * 4 + 3], a.w);
        }
    }
    {
        int k = t & 15, dp = t >> 4;
        float s = 0.f;
#pragma unroll
        for (int dd = 0; dd < 2; ++dd) {
            int d = dp * 2 + dd;
            float a = p1l[d];
            for (int e = 0; e < 32; ++e)
                s = fmaf(a * p2l[e], Wt[(d * 32 + e) * 16 + k], s);
        }
        scp[dp][k] = s;
    }
    __syncthreads();
    if (t < 16) {
        float s = 0.f;
#pragma unroll
        for (int dp = 0; dp < 16; ++dp) s += scp[dp][t];
        float bl = 0.f;
        for (int m = 0; m < 32; ++m) bl = fmaf(V[t * 64 + m], p1l[m], bl);
        for (int m = 0; m < 32; ++m) bl = fmaf(V[t * 64 + 32 + m], p2l[m], bl);
        sc[t] = fmaxf(s + bl + bt[t], 0.f);
    }
    __syncthreads();
    if (t < 16) sfeat[t] = sc[t];
    if (t == 16) {
        unsigned tot = 0;
        for (int b = 0; b < 16; ++b) tot += hs[b];
        float ftot = (float)tot;
        for (int b = 0; b < 16; ++b) sfeat[16 + b] = (float)hs[b] / ftot;
    }
    __syncthreads();
    if (t < 16) {
        float a = fc1b[t];
        for (int m = 0; m < 32; ++m) a = fmaf(sfeat[m], fc1W[m * 16 + t], a);
        h1s[t] = fmaxf(a, 0.f);
    }
    __syncthreads();
    if (t != 0) return;
    float h2[8];
    for (int r = 0; r < 8; ++r) {
        float a = fc2b[r];
        for (int m = 0; m < 16; ++m) a = fmaf(h1s[m], fc2W[m * 8 + r], a);
        h2[r] = fmaxf(a, 0.f);
    }
    float h3[4];
    for (int r = 0; r < 4; ++r) {
        float a = fc3b[r];
        for (int m = 0; m < 8; ++m) a = fmaf(h2[m], fc3W[m * 4 + r], a);
        h3[r] = fmaxf(a, 0.f);
    }
    float z = scb[0];
    for (int m = 0; m < 4; ++m) z = fmaf(h3[m], scW[m], z);
    float sig = 1.f / (1.f + expf(-z));
    out[0] = sig;
    out[1] = -logf(sig) * avg_v[0];
}

// ---------------------------------------------------------------------------
extern "C" void kernel_launch(void* const* d_in, const int* in_sizes, int n_in,
                              void* d_out, int out_size, void* d_ws, size_t ws_size,
                              hipStream_t stream) {
    (void)n_in; (void)out_size;
    const int* ei1 = (const int*)d_in[0];
    const int* ei2 = (const int*)d_in[1];
    const float* feat1 = (const float*)d_in[2];
    const float* feat2 = (const float*)d_in[3];
    const float* avg_v = (const float*)d_in[4];
    const float* W1 = (const float*)d_in[5];
    const float* b1 = (const float*)d_in[6];
    const float* W2 = (const float*)d_in[7];
    const float* b2 = (const float*)d_in[8];
    const float* W3 = (const float*)d_in[9];
    const float* b3 = (const float*)d_in[10];
    const float* Wa = (const float*)d_in[11];
    const float* Wt = (const float*)d_in[12];
    const float* V = (const float*)d_in[13];
    const float* bt = (const float*)d_in[14];
    const float* fc1W = (const float*)d_in[15];
    const float* fc1b = (const float*)d_in[16];
    const float* fc2W = (const float*)d_in[17];
    const float* fc2b = (const float*)d_in[18];
    const float* fc3W = (const float*)d_in[19];
    const float* fc3b = (const float*)d_in[20];
    const float* scW = (const float*)d_in[21];
    const float* scb = (const float*)d_in[22];

    const int E = in_sizes[0] / 2;
    const int N = in_sizes[2] / 64;

    const int nb = N / 128;
    const int nchunk = nb / SIM_CHUNK;
    const int NBLK = nb * nchunk;

    auto layout = [&](int ng, bool commit,
                      float** af, unsigned short** afbf, float** gsum, float** p12,
                      float2** pbmm, unsigned** pbhist,
                      float** dinv, int** cnt, int** offs, int** cursor, int** esrc,
                      float** bufA, float** bufB) -> size_t {
        char* w = (char*)d_ws;
        size_t off = 0;
        auto take = [&](size_t bytes) -> char* {
            char* p = w + off;
            off = (off + bytes + 255) & ~(size_t)255;
            return p;
        };
        char* p;
        p = take((size_t)2 * N * 32 * 4); if (commit) *af = (float*)p;
        p = take((size_t)2 * N * 32 * 2); if (commit) *afbf = (unsigned short*)p;
        p = take((size_t)2 * GS_REP * 32 * GS_PAD * 4); if (commit) *gsum = (float*)p;  // zero start
        p = take(64 * 4);                 if (commit) *p12 = (float*)p;                 // zero end
        p = take((size_t)NBLK * 8);       if (commit) *pbmm = (float2*)p;
        p = take((size_t)NBLK * 16 * 4);  if (commit) *pbhist = (unsigned*)p;
        p = take((size_t)ng * N * 4);     if (commit) *dinv = (float*)p;
        p = take((size_t)ng * N * 4);     if (commit) *cnt = (int*)p;
        p = take((size_t)ng * (N + 1) * 4); if (commit) *offs = (int*)p;
        p = take((size_t)ng * N * 4);     if (commit) *cursor = (int*)p;
        p = take((size_t)ng * E * 4);     if (commit) *esrc = (int*)p;
        p = take((size_t)ng * N * 128 * 4); if (commit) *bufA = (float*)p;
        p = take((size_t)ng * N * 128 * 4); if (commit) *bufB = (float*)p;
        return off;
    };

    float *af, *gsum, *p12, *dinv, *bufA, *bufB;
    unsigned short* afbf;
    float2* pbmm;
    unsigned* pbhist;
    int *cnt, *offs, *cursor, *esrc;

    size_t need2 = layout(2, false, &af, &afbf, &gsum, &p12, &pbmm, &pbhist,
                          &dinv, &cnt, &offs, &cursor, &esrc, &bufA, &bufB);
    int NG = (ws_size >= need2) ? 2 : 1;
    layout(NG, true, &af, &afbf, &gsum, &p12, &pbmm, &pbhist,
           &dinv, &cnt, &offs, &cursor, &esrc, &bufA, &bufB);

    size_t zspan = (char*)(p12 + 64) - (char*)gsum;
    hipMemsetAsync(gsum, 0, zspan, stream);

    int iters = 2 / NG;
    for (int it = 0; it < iters; ++it) {
        const int *srcA, *srcB, *tgtA, *tgtB;
        const float *xA, *xB;
        float* afbase;
        unsigned short* afbfbase;
        float* gsbase;
        if (NG == 2) {
            srcA = ei1; tgtA = ei1 + E; srcB = ei2; tgtB = ei2 + E;
            xA = feat1; xB = feat2;
            afbase = af; afbfbase = afbf; gsbase = gsum;
        } else {
            const int* ei = it ? ei2 : ei1;
            srcA = srcB = ei; tgtA = tgtB = ei + E;
            xA = xB = it ? feat2 : feat1;
            afbase = af + (size_t)it * N * 32;
            afbfbase = afbf + (size_t)it * N * 32;
            gsbase = gsum + (size_t)it * GS_REP * 32 * GS_PAD;
        }
        size_t bstride = (size_t)N * 128;

        hipMemsetAsync(cnt, 0, (size_t)NG * N * 4, stream);
        count_tgt<<<dim3((E + 255) / 256, NG), 256, 0, stream>>>(tgtA, tgtB, cnt, N, E);
        scan_offsets<<<NG, 1024, 0, stream>>>(cnt, offs, cursor, dinv, N);
        scatter_src<<<dim3((E + 255) / 256, NG), 256, 0, stream>>>(srcA, srcB, tgtA, tgtB,
                                                                   cursor, esrc, N, E);

        // layer 1 (commuted): aggregate raw x (64 cols), then GEMM +b1, relu
        agg_csr<64, false, false, false><<<dim3(N / 16, NG), 256, 0, stream>>>(
            xA, xB, offs, esrc, dinv, nullptr, bufB, bstride, nullptr, 0, nullptr, N, E);
        tiled_gemm<64, 128, true, true><<<dim3(N / 64, NG), 256, 0, stream>>>(
            bufB, bufB + bstride, W1, b1, bufA, bstride, N);
        // layer 2: GEMM 128->64, then aggregate +b2, relu
        tiled_gemm<128, 64, false, false><<<dim3(N / 64, NG), 256, 0, stream>>>(
            bufA, bufA + bstride, W2, nullptr, bufB, bstride, N);
        agg_csr<64, true, false, true><<<dim3(N / 16, NG), 256, 0, stream>>>(
            bufB, bufB + bstride, offs, esrc, dinv, b2, bufA, bstride, nullptr, 0, nullptr,
            N, E);
        // layer 3: GEMM 64->32, then aggregate +b3 (no relu) + pool + bf16
        tiled_gemm<64, 32, false, false><<<dim3(N / 64, NG), 256, 0, stream>>>(
            bufA, bufA + bstride, W3, nullptr, bufB, bstride, N);
        agg_csr<32, false, true, true><<<dim3(N / 32, NG), 256, 0, stream>>>(
            bufB, bufB + bstride, offs, esrc, dinv, b3, afbase, (size_t)N * 32, afbfbase,
            (size_t)N * 32, gsbase, N, E);
    }

    pool_att<<<dim3(N / 256, 2), 256, 0, stream>>>(af, gsum, Wa, p12, N);

    sim_mfma<false><<<NBLK, 256, 0, stream>>>(afbf, afbf + (size_t)N * 32, N, NBLK, pbmm,
                                              pbhist);
    sim_mfma<true><<<NBLK, 256, 0, stream>>>(afbf, afbf + (size_t)N * 32, N, NBLK, pbmm,
                                             pbhist);

    ntn_final<<<1, 256, 0, stream>>>(p12, Wt, V, bt, pbhist, NBLK, fc1W, fc1b, fc2W, fc2b,
                                     fc3W, fc3b, scW, scb, avg_v, (float*)d_out);
}

// Round 8
// 259.087 us; speedup vs baseline: 7.8388x; 1.0012x over previous
//
#include <hip/hip_runtime.h>
#include <math.h>

// ---------------------------------------------------------------------------
// SimGNN forward on MI355X (gfx950).  R8: replaced in-graph hipMemsetAsync
// (rocclr fillBufferAligned was ~41us each for 64KB!) with one custom
// grid-strided zero kernel over a contiguous gsum|p12|cnt region.
// ---------------------------------------------------------------------------

#define SIM_CHUNK 2    // bx-tiles per block (128 values/thread <= 255 pack max)
#define GS_PAD 16      // floats of padding per gsum counter (64B lines)
#define GS_REP 8       // gsum replicas to spread residual atomic contention

using bf16x8 = __attribute__((ext_vector_type(8))) short;
using f32x4  = __attribute__((ext_vector_type(4))) float;

__device__ __forceinline__ unsigned short f2bf(float f) {  // RNE
    unsigned u = __float_as_uint(f);
    unsigned r = ((u >> 16) & 1u) + 0x7FFFu;
    return (unsigned short)((u + r) >> 16);
}

// ---------------- custom zero fill (rocclr fill kernel is ~41us in-graph) ----------------
__global__ void zero_ws(float4* __restrict__ p, int n4) {
    int i = blockIdx.x * 256 + threadIdx.x;
    if (i < n4) p[i] = make_float4(0.f, 0.f, 0.f, 0.f);
}

// ---------------- CSR build (batched: blockIdx.y = graph) ----------------
__global__ void count_tgt(const int* __restrict__ t0, const int* __restrict__ t1,
                          int* __restrict__ cnt, int N, int E) {
    int g = blockIdx.y;
    const int* t = g ? t1 : t0;
    int i = blockIdx.x * 256 + threadIdx.x;
    if (i < E) atomicAdd(&cnt[g * N + t[i]], 1);
}

__global__ __launch_bounds__(1024) void scan_offsets(const int* __restrict__ cnt_,
                                                     int* __restrict__ offs_,
                                                     int* __restrict__ cursor_,
                                                     float* __restrict__ dinv_, int N) {
    int g = blockIdx.x;
    const int* cnt = cnt_ + g * N;
    int* offs = offs_ + g * (N + 1);
    int* cursor = cursor_ + g * N;
    float* dinv = dinv_ + g * N;
    int tid = threadIdx.x, lane = tid & 63, wid = tid >> 6;
    int chunk = (N + 1023) >> 10;
    int base = tid * chunk;
    int s = 0;
    for (int i = 0; i < chunk; ++i) {
        int idx = base + i;
        if (idx < N) s += cnt[idx];
    }
    int v = s;  // inclusive wave scan
#pragma unroll
    for (int d = 1; d < 64; d <<= 1) {
        int u = __shfl_up(v, d);
        if (lane >= d) v += u;
    }
    __shared__ int wtot[16], wbase[16];
    if (lane == 63) wtot[wid] = v;
    __syncthreads();
    if (tid == 0) {
        int r = 0;
        for (int i = 0; i < 16; ++i) { wbase[i] = r; r += wtot[i]; }
        offs[N] = r;
    }
    __syncthreads();
    int run = wbase[wid] + (v - s);  // exclusive prefix for this thread
    for (int i = 0; i < chunk; ++i) {
        int idx = base + i;
        if (idx < N) {
            int c = cnt[idx];
            offs[idx] = run;
            cursor[idx] = run;
            dinv[idx] = 1.0f / sqrtf((float)(c + 1));
            run += c;
        }
    }
}

__global__ void scatter_src(const int* __restrict__ s0, const int* __restrict__ s1,
                            const int* __restrict__ t0, const int* __restrict__ t1,
                            int* __restrict__ cursor, int* __restrict__ esrc, int N, int E) {
    int g = blockIdx.y;
    const int* src = g ? s1 : s0;
    const int* tgt = g ? t1 : t0;
    int i = blockIdx.x * 256 + threadIdx.x;
    if (i < E) {
        int t = tgt[i];
        int pos = atomicAdd(&cursor[g * N + t], 1);
        esrc[g * E + pos] = src[i];
    }
}

// --------- tiled GEMM: out[N,FOUT] = x[N,FIN] @ W[FIN,FOUT] (+b, relu) ---------
template <int FIN, int FOUT, bool BIAS, bool RELU>
__global__ __launch_bounds__(256, 2) void tiled_gemm(const float* __restrict__ x0,
                                                     const float* __restrict__ x1,
                                                     const float* __restrict__ W,
                                                     const float* __restrict__ b,
                                                     float* __restrict__ out,
                                                     size_t ostride, int N) {
    constexpr int KT = 64;
    constexpr int TN = FOUT / 16;
    int g = blockIdx.y;
    const float* x = g ? x1 : x0;
    out += (size_t)g * ostride;
    __shared__ float XL[64][KT + 2];
    __shared__ float WL[KT * FOUT];
    int t = threadIdx.x;
    int tc = t & 15, tr = t >> 4;
    int rb = blockIdx.x * 64;

    float acc[4][TN];
#pragma unroll
    for (int i = 0; i < 4; ++i)
#pragma unroll
        for (int j = 0; j < TN; ++j)
            acc[i][j] = BIAS ? b[tc * TN + j] : 0.f;

    for (int k0 = 0; k0 < FIN; k0 += KT) {
        if (k0) __syncthreads();
        constexpr int W4 = KT * FOUT / 4;
        const float4* Wsrc = (const float4*)(W + (size_t)k0 * FOUT);
#pragma unroll
        for (int i = t; i < W4; i += 256) ((float4*)WL)[i] = Wsrc[i];
#pragma unroll
        for (int idx = t; idx < 64 * KT / 2; idx += 256) {
            int r = idx >> 5;
            int c2 = idx & 31;
            float2 v = *(const float2*)&x[(size_t)(rb + r) * FIN + k0 + c2 * 2];
            *(float2*)&XL[r][c2 * 2] = v;
        }
        __syncthreads();
#pragma unroll 4
        for (int k = 0; k < KT; ++k) {
            float a[4], bv[TN];
#pragma unroll
            for (int i = 0; i < 4; ++i) a[i] = XL[tr * 4 + i][k];
#pragma unroll
            for (int j = 0; j < TN; ++j) bv[j] = WL[k * FOUT + tc * TN + j];
#pragma unroll
            for (int i = 0; i < 4; ++i)
#pragma unroll
                for (int j = 0; j < TN; ++j) acc[i][j] = fmaf(a[i], bv[j], acc[i][j]);
        }
    }

#pragma unroll
    for (int i = 0; i < 4; ++i) {
        int row = rb + tr * 4 + i;
        float* orow = &out[(size_t)row * FOUT + tc * TN];
#pragma unroll
        for (int j = 0; j < TN; ++j) {
            float v = acc[i][j];
            if (RELU) v = fmaxf(v, 0.f);
            acc[i][j] = v;
        }
        if (TN == 8) {
            *(float4*)&orow[0] = make_float4(acc[i][0], acc[i][1], acc[i][2], acc[i][3]);
            *(float4*)&orow[4] = make_float4(acc[i][4], acc[i][5], acc[i][6], acc[i][7]);
        } else if (TN == 4) {
            *(float4*)&orow[0] = make_float4(acc[i][0], acc[i][1], acc[i][2], acc[i][3]);
        } else {
            *(float2*)&orow[0] = make_float2(acc[i][0], acc[i][1]);
        }
    }
}

// ------------- GCN aggregation (float4 per thread) -------------
template <int F, bool RELU, bool POOL, bool BIAS>
__global__ __launch_bounds__(256) void agg_csr(const float* __restrict__ h0,
                                               const float* __restrict__ h1,
                                               const int* __restrict__ offs_,
                                               const int* __restrict__ esrc_,
                                               const float* __restrict__ dinv_,
                                               const float* __restrict__ b,
                                               float* __restrict__ out, size_t ostride,
                                               unsigned short* __restrict__ outbf,
                                               size_t obfstride,
                                               float* __restrict__ gsum, int N, int E) {
    int g = blockIdx.y;
    const float* h = g ? h1 : h0;
    const int* offs = offs_ + g * (N + 1);
    const int* esrc = esrc_ + g * E;
    const float* dinv = dinv_ + g * N;
    out += (size_t)g * ostride;
    constexpr int TPR = F / 4;
    constexpr int RPB = 256 / TPR;
    int fq = (threadIdx.x % TPR) * 4;
    int t = blockIdx.x * RPB + threadIdx.x / TPR;
    float4 v = {0.f, 0.f, 0.f, 0.f};
    if (t < N) {
        float dt = dinv[t];
        float4 hv = *(const float4*)&h[(size_t)t * F + fq];
        float4 acc;
        acc.x = dt * hv.x; acc.y = dt * hv.y; acc.z = dt * hv.z; acc.w = dt * hv.w;
        int e1 = offs[t + 1];
        for (int e = offs[t]; e < e1; ++e) {
            int s = esrc[e];
            float ds = dinv[s];
            float4 sv = *(const float4*)&h[(size_t)s * F + fq];
            acc.x = fmaf(ds, sv.x, acc.x); acc.y = fmaf(ds, sv.y, acc.y);
            acc.z = fmaf(ds, sv.z, acc.z); acc.w = fmaf(ds, sv.w, acc.w);
        }
        float4 bb = {0.f, 0.f, 0.f, 0.f};
        if (BIAS) bb = *(const float4*)&b[fq];
        v.x = fmaf(dt, acc.x, bb.x); v.y = fmaf(dt, acc.y, bb.y);
        v.z = fmaf(dt, acc.z, bb.z); v.w = fmaf(dt, acc.w, bb.w);
        if (RELU) {
            v.x = fmaxf(v.x, 0.f); v.y = fmaxf(v.y, 0.f);
            v.z = fmaxf(v.z, 0.f); v.w = fmaxf(v.w, 0.f);
        }
        *(float4*)&out[(size_t)t * F + fq] = v;
    }
    if (POOL) {
        if (t < N) {
            unsigned short r4[4] = {f2bf(v.x), f2bf(v.y), f2bf(v.z), f2bf(v.w)};
            *(uint2*)&outbf[(size_t)g * obfstride + (size_t)t * F + fq] = *(uint2*)r4;
        }
        __shared__ float ls[F];
        if (threadIdx.x < F) ls[threadIdx.x] = 0.f;
        __syncthreads();
        atomicAdd(&ls[fq + 0], v.x);
        atomicAdd(&ls[fq + 1], v.y);
        atomicAdd(&ls[fq + 2], v.z);
        atomicAdd(&ls[fq + 3], v.w);
        __syncthreads();
        if (threadIdx.x < 32) {
            int rep = blockIdx.x & (GS_REP - 1);
            atomicAdd(&gsum[((g * GS_REP + rep) * 32 + threadIdx.x) * GS_PAD],
                      ls[threadIdx.x]);
        }
    }
}

// ------- attention pool (ctx computed in-block): p = af^T @ sigmoid(af@ctx) -------
__global__ __launch_bounds__(256) void pool_att(const float* __restrict__ af,
                                                const float* __restrict__ gsum,
                                                const float* __restrict__ Wa,
                                                float* __restrict__ p12, int N) {
    int g = blockIdx.y;
    af += (size_t)g * N * 32;
    __shared__ float cm[32], ctxs[32];
    int tid = threadIdx.x;
    if (tid < 32) {
        float s = 0.f;
#pragma unroll
        for (int r = 0; r < GS_REP; ++r) s += gsum[((g * GS_REP + r) * 32 + tid) * GS_PAD];
        cm[tid] = s / (float)N;
    }
    __syncthreads();
    if (tid < 32) {
        float s = 0.f;
        for (int d = 0; d < 32; ++d) s = fmaf(cm[d], Wa[d * 32 + tid], s);
        ctxs[tid] = tanhf(s);
    }
    __syncthreads();
    float ctxl[32];
#pragma unroll
    for (int f = 0; f < 32; ++f) ctxl[f] = ctxs[f];
    int r = blockIdx.x * 256 + tid;
    float rowv[32];
    float att = 0.f;
    if (r < N) {
        const float4* row = (const float4*)(af + (size_t)r * 32);
        float dot = 0.f;
#pragma unroll
        for (int q = 0; q < 8; ++q) {
            float4 v = row[q];
            rowv[q * 4 + 0] = v.x; rowv[q * 4 + 1] = v.y;
            rowv[q * 4 + 2] = v.z; rowv[q * 4 + 3] = v.w;
            dot = fmaf(v.x, ctxl[q * 4 + 0], dot);
            dot = fmaf(v.y, ctxl[q * 4 + 1], dot);
            dot = fmaf(v.z, ctxl[q * 4 + 2], dot);
            dot = fmaf(v.w, ctxl[q * 4 + 3], dot);
        }
        att = 1.f / (1.f + expf(-dot));
    } else {
#pragma unroll
        for (int f = 0; f < 32; ++f) rowv[f] = 0.f;
    }
    __shared__ float wsum[4][32];
    int lane = tid & 63, wid = tid >> 6;
#pragma unroll
    for (int f = 0; f < 32; ++f) {
        float v = att * rowv[f];
#pragma unroll
        for (int off = 1; off < 64; off <<= 1) v += __shfl_xor(v, off);
        if (lane == 0) wsum[wid][f] = v;
    }
    __syncthreads();
    if (tid < 32) {
        float s = wsum[0][tid] + wsum[1][tid] + wsum[2][tid] + wsum[3][tid];
        atomicAdd(&p12[g * 32 + tid], s);
    }
}

// ---------------- similarity passes: bf16 MFMA, block-level A reuse ----------------
template <bool HIST>
__global__ __launch_bounds__(256) void sim_mfma(const unsigned short* __restrict__ a1,
                                                const unsigned short* __restrict__ a2,
                                                int N, int nblk,
                                                float2* __restrict__ pbmm,
                                                unsigned* __restrict__ pbhist) {
    int nb = N >> 7;
    int nchunk = nb / SIM_CHUNK;
    int by = blockIdx.x / nchunk;
    int ch = blockIdx.x % nchunk;
    int w = threadIdx.x >> 6, lane = threadIdx.x & 63;
    int r16 = lane & 15, kg = (lane >> 4) << 3;

    __shared__ unsigned hs[16];
    __shared__ float mnmx[2];
    if (HIST && threadIdx.x < 16) hs[threadIdx.x] = 0;

    float scale = 0.f, nbias = 0.f;
    if (HIST) {  // fused min/max reduce over per-block results
        float mn2 = 1e30f, mx2 = -1e30f;
        for (int i = threadIdx.x; i < nblk; i += 256) {
            float2 vv = pbmm[i];
            mn2 = fminf(mn2, vv.x);
            mx2 = fmaxf(mx2, vv.y);
        }
#pragma unroll
        for (int off = 1; off < 64; off <<= 1) {
            mn2 = fminf(mn2, __shfl_xor(mn2, off));
            mx2 = fmaxf(mx2, __shfl_xor(mx2, off));
        }
        __shared__ float wmn2[4], wmx2[4];
        if (lane == 0) { wmn2[w] = mn2; wmx2[w] = mx2; }
        __syncthreads();
        if (threadIdx.x == 0) {
            mnmx[0] = fminf(fminf(wmn2[0], wmn2[1]), fminf(wmn2[2], wmn2[3]));
            mnmx[1] = fmaxf(fmaxf(wmx2[0], wmx2[1]), fmaxf(wmx2[2], wmx2[3]));
        }
        __syncthreads();
        float mnv = mnmx[0], mxv = mnmx[1];
        float width = (mxv > mnv) ? (mxv - mnv) : 1.0f;
        scale = 16.0f / width;
        nbias = -mnv * scale;
    }

    const unsigned short* arow = a1 + ((size_t)(by * 128 + (w >> 1) * 64 + r16)) * 32 + kg;
    bf16x8 afr[4];
#pragma unroll
    for (int m = 0; m < 4; ++m) afr[m] = *(const bf16x8*)(arow + m * 16 * 32);

    float mn = 1e30f, mx = -1e30f;
    unsigned h4_0 = 0, h4_1 = 0, h4_2 = 0, h4_3 = 0;

#pragma unroll
    for (int t = 0; t < SIM_CHUNK; ++t) {
        int bx = ch * SIM_CHUNK + t;
        const unsigned short* brow =
            a2 + ((size_t)(bx * 128 + (w & 1) * 64 + r16)) * 32 + kg;
        bf16x8 bfr[4];
#pragma unroll
        for (int n = 0; n < 4; ++n) bfr[n] = *(const bf16x8*)(brow + n * 16 * 32);
        f32x4 zero = {0.f, 0.f, 0.f, 0.f};
        f32x4 acc[4][4];
#pragma unroll
        for (int m = 0; m < 4; ++m)
#pragma unroll
            for (int n = 0; n < 4; ++n)
                acc[m][n] =
                    __builtin_amdgcn_mfma_f32_16x16x32_bf16(afr[m], bfr[n], zero, 0, 0, 0);
        if (!HIST) {
#pragma unroll
            for (int m = 0; m < 4; ++m)
#pragma unroll
                for (int n = 0; n < 4; ++n)
#pragma unroll
                    for (int e = 0; e < 4; ++e) {
                        float v = acc[m][n][e];
                        mn = fminf(mn, v);
                        mx = fmaxf(mx, v);
                    }
        } else {
#pragma unroll
            for (int m = 0; m < 4; ++m)
#pragma unroll
                for (int n = 0; n < 4; ++n)
#pragma unroll
                    for (int e = 0; e < 4; ++e) {
                        float v = acc[m][n][e];
                        int bin = (int)fmaf(v, scale, nbias);
                        bin = bin < 0 ? 0 : (bin > 15 ? 15 : bin);
                        unsigned wbit = 1u << ((bin & 3) << 3);
                        int hi = bin >> 2;
                        h4_0 += (hi == 0) ? wbit : 0u;
                        h4_1 += (hi == 1) ? wbit : 0u;
                        h4_2 += (hi == 2) ? wbit : 0u;
                        h4_3 += (hi == 3) ? wbit : 0u;
                    }
        }
    }

    if (!HIST) {
#pragma unroll
        for (int off = 1; off < 64; off <<= 1) {
            mn = fminf(mn, __shfl_xor(mn, off));
            mx = fmaxf(mx, __shfl_xor(mx, off));
        }
        __shared__ float wmn[4], wmx[4];
        if (lane == 0) { wmn[w] = mn; wmx[w] = mx; }
        __syncthreads();
        if (threadIdx.x == 0) {
            float bmn = fminf(fminf(wmn[0], wmn[1]), fminf(wmn[2], wmn[3]));
            float bmx = fmaxf(fmaxf(wmx[0], wmx[1]), fmaxf(wmx[2], wmx[3]));
            pbmm[blockIdx.x] = make_float2(bmn, bmx);
        }
    } else {
        unsigned hh[8];
        hh[0] = h4_0 & 0x00FF00FFu; hh[1] = (h4_0 >> 8) & 0x00FF00FFu;
        hh[2] = h4_1 & 0x00FF00FFu; hh[3] = (h4_1 >> 8) & 0x00FF00FFu;
        hh[4] = h4_2 & 0x00FF00FFu; hh[5] = (h4_2 >> 8) & 0x00FF00FFu;
        hh[6] = h4_3 & 0x00FF00FFu; hh[7] = (h4_3 >> 8) & 0x00FF00FFu;
#pragma unroll
        for (int off = 1; off < 64; off <<= 1) {
#pragma unroll
            for (int q = 0; q < 8; ++q) hh[q] += (unsigned)__shfl_xor((int)hh[q], off);
        }
        __syncthreads();
        if (lane < 16) {
            int q = lane >> 2, r = lane & 3;
            unsigned word = hh[2 * q + (r & 1)];
            unsigned val = (r < 2) ? (word & 0xFFFFu) : (word >> 16);
            atomicAdd(&hs[lane], val);
        }
        __syncthreads();
        if (threadIdx.x < 16)
            pbhist[(size_t)blockIdx.x * 16 + threadIdx.x] = hs[threadIdx.x];
    }
}

// ------- hist reduce (vectorized) + NTN (parallel) + MLP head, one block -------
__global__ __launch_bounds__(256) void ntn_final(
    const float* __restrict__ p12, const float* __restrict__ Wt,
    const float* __restrict__ V, const float* __restrict__ bt,
    const unsigned* __restrict__ pbhist, int nblk,
    const float* __restrict__ fc1W, const float* __restrict__ fc1b,
    const float* __restrict__ fc2W, const float* __restrict__ fc2b,
    const float* __restrict__ fc3W, const float* __restrict__ fc3b,
    const float* __restrict__ scW, const float* __restrict__ scb,
    const float* __restrict__ avg_v, float* __restrict__ out) {
    __shared__ float p1l[32], p2l[32];
    __shared__ float scp[16][17];
    __shared__ unsigned hs[16];
    __shared__ float sc[16];
    __shared__ float sfeat[32];
    __shared__ float h1s[16];
    int t = threadIdx.x;
    if (t < 16) hs[t] = 0;
    if (t < 32) p1l[t] = p12[t];
    else if (t < 64) p2l[t - 32] = p12[t];
    __syncthreads();
    {
        const uint4* pb = (const uint4*)pbhist;
        int total = nblk * 4;
        uint4 a = {0u, 0u, 0u, 0u};
        for (int i = t; i < total; i += 256) {
            uint4 v = pb[i];
            a.x += v.x; a.y += v.y; a.z += v.z; a.w += v.w;
        }
#pragma unroll
        for (int off = 4; off < 64; off <<= 1) {
            a.x += (unsigned)__shfl_xor((int)a.x, off);
            a.y += (unsigned)__shfl_xor((int)a.y, off);
            a.z += (unsigned)__shfl_xor((int)a.z, off);
            a.w += (unsigned)__shfl_xor((int)a.w, off);
        }
        int lane = t & 63;
        if (lane < 4) {
            atomicAdd(&hs[lane * 4 + 0], a.x);
            atomicAdd(&hs[lane * 4 + 1], a.y);
            atomicAdd(&hs[lane * 4 + 2], a.z);
            atomicAdd(&hs[lane * 4 + 3], a.w);
        }
    }
    {
        int k = t & 15, dp = t >> 4;
        float s = 0.f;
#pragma unroll
        for (int dd = 0; dd < 2; ++dd) {
            int d = dp * 2 + dd;
            float a = p1l[d];
            for (int e = 0; e < 32; ++e)
                s = fmaf(a * p2l[e], Wt[(d * 32 + e) * 16 + k], s);
        }
        scp[dp][k] = s;
    }
    __syncthreads();
    if (t < 16) {
        float s = 0.f;
#pragma unroll
        for (int dp = 0; dp < 16; ++dp) s += scp[dp][t];
        float bl = 0.f;
        for (int m = 0; m < 32; ++m) bl = fmaf(V[t * 64 + m], p1l[m], bl);
        for (int m = 0; m < 32; ++m) bl = fmaf(V[t * 64 + 32 + m], p2l[m], bl);
        sc[t] = fmaxf(s + bl + bt[t], 0.f);
    }
    __syncthreads();
    if (t < 16) sfeat[t] = sc[t];
    if (t == 16) {
        unsigned tot = 0;
        for (int b = 0; b < 16; ++b) tot += hs[b];
        float ftot = (float)tot;
        for (int b = 0; b < 16; ++b) sfeat[16 + b] = (float)hs[b] / ftot;
    }
    __syncthreads();
    if (t < 16) {
        float a = fc1b[t];
        for (int m = 0; m < 32; ++m) a = fmaf(sfeat[m], fc1W[m * 16 + t], a);
        h1s[t] = fmaxf(a, 0.f);
    }
    __syncthreads();
    if (t != 0) return;
    float h2[8];
    for (int r = 0; r < 8; ++r) {
        float a = fc2b[r];
        for (int m = 0; m < 16; ++m) a = fmaf(h1s[m], fc2W[m * 8 + r], a);
        h2[r] = fmaxf(a, 0.f);
    }
    float h3[4];
    for (int r = 0; r < 4; ++r) {
        float a = fc3b[r];
        for (int m = 0; m < 8; ++m) a = fmaf(h2[m], fc3W[m * 4 + r], a);
        h3[r] = fmaxf(a, 0.f);
    }
    float z = scb[0];
    for (int m = 0; m < 4; ++m) z = fmaf(h3[m], scW[m], z);
    float sig = 1.f / (1.f + expf(-z));
    out[0] = sig;
    out[1] = -logf(sig) * avg_v[0];
}

// ---------------------------------------------------------------------------
extern "C" void kernel_launch(void* const* d_in, const int* in_sizes, int n_in,
                              void* d_out, int out_size, void* d_ws, size_t ws_size,
                              hipStream_t stream) {
    (void)n_in; (void)out_size;
    const int* ei1 = (const int*)d_in[0];
    const int* ei2 = (const int*)d_in[1];
    const float* feat1 = (const float*)d_in[2];
    const float* feat2 = (const float*)d_in[3];
    const float* avg_v = (const float*)d_in[4];
    const float* W1 = (const float*)d_in[5];
    const float* b1 = (const float*)d_in[6];
    const float* W2 = (const float*)d_in[7];
    const float* b2 = (const float*)d_in[8];
    const float* W3 = (const float*)d_in[9];
    const float* b3 = (const float*)d_in[10];
    const float* Wa = (const float*)d_in[11];
    const float* Wt = (const float*)d_in[12];
    const float* V = (const float*)d_in[13];
    const float* bt = (const float*)d_in[14];
    const float* fc1W = (const float*)d_in[15];
    const float* fc1b = (const float*)d_in[16];
    const float* fc2W = (const float*)d_in[17];
    const float* fc2b = (const float*)d_in[18];
    const float* fc3W = (const float*)d_in[19];
    const float* fc3b = (const float*)d_in[20];
    const float* scW = (const float*)d_in[21];
    const float* scb = (const float*)d_in[22];

    const int E = in_sizes[0] / 2;
    const int N = in_sizes[2] / 64;

    const int nb = N / 128;
    const int nchunk = nb / SIM_CHUNK;
    const int NBLK = nb * nchunk;

    // ---- workspace layout: gsum | p12 | cnt contiguous => single zero pass ----
    auto layout = [&](int ng, bool commit,
                      float** af, unsigned short** afbf, float** gsum, float** p12,
                      int** cnt, float2** pbmm, unsigned** pbhist,
                      float** dinv, int** offs, int** cursor, int** esrc,
                      float** bufA, float** bufB) -> size_t {
        char* w = (char*)d_ws;
        size_t off = 0;
        auto take = [&](size_t bytes) -> char* {
            char* p = w + off;
            off = (off + bytes + 255) & ~(size_t)255;
            return p;
        };
        char* p;
        p = take((size_t)2 * N * 32 * 4); if (commit) *af = (float*)p;
        p = take((size_t)2 * N * 32 * 2); if (commit) *afbf = (unsigned short*)p;
        p = take((size_t)2 * GS_REP * 32 * GS_PAD * 4); if (commit) *gsum = (float*)p;  // zero start
        p = take(64 * 4);                 if (commit) *p12 = (float*)p;
        p = take((size_t)ng * N * 4);     if (commit) *cnt = (int*)p;                   // zero end
        p = take((size_t)NBLK * 8);       if (commit) *pbmm = (float2*)p;
        p = take((size_t)NBLK * 16 * 4);  if (commit) *pbhist = (unsigned*)p;
        p = take((size_t)ng * N * 4);     if (commit) *dinv = (float*)p;
        p = take((size_t)ng * (N + 1) * 4); if (commit) *offs = (int*)p;
        p = take((size_t)ng * N * 4);     if (commit) *cursor = (int*)p;
        p = take((size_t)ng * E * 4);     if (commit) *esrc = (int*)p;
        p = take((size_t)ng * N * 128 * 4); if (commit) *bufA = (float*)p;
        p = take((size_t)ng * N * 128 * 4); if (commit) *bufB = (float*)p;
        return off;
    };

    float *af, *gsum, *p12, *dinv, *bufA, *bufB;
    unsigned short* afbf;
    int* cnt;
    float2* pbmm;
    unsigned* pbhist;
    int *offs, *cursor, *esrc;

    size_t need2 = layout(2, false, &af, &afbf, &gsum, &p12, &cnt, &pbmm, &pbhist,
                          &dinv, &offs, &cursor, &esrc, &bufA, &bufB);
    int NG = (ws_size >= need2) ? 2 : 1;
    layout(NG, true, &af, &afbf, &gsum, &p12, &cnt, &pbmm, &pbhist,
           &dinv, &offs, &cursor, &esrc, &bufA, &bufB);

    // zero gsum..cnt in one custom kernel (rocclr fill was ~41us per call)
    {
        size_t zbytes = ((char*)cnt + (size_t)NG * N * 4) - (char*)gsum;
        int n4 = (int)(zbytes / 16);
        zero_ws<<<(n4 + 255) / 256, 256, 0, stream>>>((float4*)gsum, n4);
    }

    int iters = 2 / NG;
    for (int it = 0; it < iters; ++it) {
        const int *srcA, *srcB, *tgtA, *tgtB;
        const float *xA, *xB;
        float* afbase;
        unsigned short* afbfbase;
        float* gsbase;
        if (NG == 2) {
            srcA = ei1; tgtA = ei1 + E; srcB = ei2; tgtB = ei2 + E;
            xA = feat1; xB = feat2;
            afbase = af; afbfbase = afbf; gsbase = gsum;
        } else {
            const int* ei = it ? ei2 : ei1;
            srcA = srcB = ei; tgtA = tgtB = ei + E;
            xA = xB = it ? feat2 : feat1;
            afbase = af + (size_t)it * N * 32;
            afbfbase = afbf + (size_t)it * N * 32;
            gsbase = gsum + (size_t)it * GS_REP * 32 * GS_PAD;
            if (it) {  // re-zero cnt for second pass
                int n4 = NG * N * 4 / 16;
                zero_ws<<<(n4 + 255) / 256, 256, 0, stream>>>((float4*)cnt, n4);
            }
        }

        size_t bstride = (size_t)N * 128;

        count_tgt<<<dim3((E + 255) / 256, NG), 256, 0, stream>>>(tgtA, tgtB, cnt, N, E);
        scan_offsets<<<NG, 1024, 0, stream>>>(cnt, offs, cursor, dinv, N);
        scatter_src<<<dim3((E + 255) / 256, NG), 256, 0, stream>>>(srcA, srcB, tgtA, tgtB,
                                                                   cursor, esrc, N, E);

        // layer 1 (commuted): aggregate raw x (64 cols), then GEMM +b1, relu
        agg_csr<64, false, false, false><<<dim3(N / 16, NG), 256, 0, stream>>>(
            xA, xB, offs, esrc, dinv, nullptr, bufB, bstride, nullptr, 0, nullptr, N, E);
        tiled_gemm<64, 128, true, true><<<dim3(N / 64, NG), 256, 0, stream>>>(
            bufB, bufB + bstride, W1, b1, bufA, bstride, N);
        // layer 2: GEMM 128->64, then aggregate +b2, relu
        tiled_gemm<128, 64, false, false><<<dim3(N / 64, NG), 256, 0, stream>>>(
            bufA, bufA + bstride, W2, nullptr, bufB, bstride, N);
        agg_csr<64, true, false, true><<<dim3(N / 16, NG), 256, 0, stream>>>(
            bufB, bufB + bstride, offs, esrc, dinv, b2, bufA, bstride, nullptr, 0, nullptr,
            N, E);
        // layer 3: GEMM 64->32, then aggregate +b3 (no relu) + pool + bf16
        tiled_gemm<64, 32, false, false><<<dim3(N / 64, NG), 256, 0, stream>>>(
            bufA, bufA + bstride, W3, nullptr, bufB, bstride, N);
        agg_csr<32, false, true, true><<<dim3(N / 32, NG), 256, 0, stream>>>(
            bufB, bufB + bstride, offs, esrc, dinv, b3, afbase, (size_t)N * 32, afbfbase,
            (size_t)N * 32, gsbase, N, E);
    }

    pool_att<<<dim3(N / 256, 2), 256, 0, stream>>>(af, gsum, Wa, p12, N);

    sim_mfma<false><<<NBLK, 256, 0, stream>>>(afbf, afbf + (size_t)N * 32, N, NBLK, pbmm,
                                              pbhist);
    sim_mfma<true><<<NBLK, 256, 0, stream>>>(afbf, afbf + (size_t)N * 32, N, NBLK, pbmm,
                                             pbhist);

    ntn_final<<<1, 256, 0, stream>>>(p12, Wt, V, bt, pbhist, NBLK, fc1W, fc1b, fc2W, fc2b,
                                     fc3W, fc3b, scW, scb, avg_v, (float*)d_out);
}